// Round 1
// baseline (2104.285 us; speedup 1.0000x reference)
//
#include <hip/hip_runtime.h>

#define U_N 150000
#define I_N 100000
#define D_N 64
#define E_N 1500000
#define N_NODES (U_N + I_N)

// ---------------- degree accumulation ----------------
__global__ void deg_kernel(const int* __restrict__ eu, const int* __restrict__ ei,
                           float* __restrict__ deg) {
    int t = blockIdx.x * blockDim.x + threadIdx.x;
    int stride = gridDim.x * blockDim.x;
    for (int e = t; e < E_N; e += stride) {
        atomicAdd(&deg[eu[e]], 1.0f);
        atomicAdd(&deg[U_N + ei[e]], 1.0f);
    }
}

// ---------------- deg -> d^{-1/2} in place ----------------
__global__ void rsqrt_kernel(float* __restrict__ deg) {
    int t = blockIdx.x * blockDim.x + threadIdx.x;
    if (t < N_NODES) deg[t] = rsqrtf(deg[t] + 1e-7f);
}

// ---------------- out = concat(u_emb, v_emb) (float4) ----------------
__global__ void init_out_kernel(const float* __restrict__ u_emb,
                                const float* __restrict__ v_emb,
                                float* __restrict__ out) {
    size_t t = (size_t)blockIdx.x * blockDim.x + threadIdx.x;
    size_t stride = (size_t)gridDim.x * blockDim.x;
    const size_t nu4 = (size_t)U_N * D_N / 4;
    const size_t ni4 = (size_t)I_N * D_N / 4;
    const float4* us = (const float4*)u_emb;
    const float4* vs = (const float4*)v_emb;
    float4* o = (float4*)out;
    for (size_t i = t; i < nu4; i += stride) o[i] = us[i];
    for (size_t i = t; i < ni4; i += stride) o[nu4 + i] = vs[i];
}

// ---------------- acc += h (float4) ----------------
__global__ void add_kernel(float* __restrict__ acc, const float* __restrict__ h) {
    size_t t = (size_t)blockIdx.x * blockDim.x + threadIdx.x;
    size_t stride = (size_t)gridDim.x * blockDim.x;
    const size_t n4 = (size_t)N_NODES * D_N / 4;
    float4* a = (float4*)acc;
    const float4* b = (const float4*)h;
    for (size_t i = t; i < n4; i += stride) {
        float4 x = a[i];
        float4 y = b[i];
        x.x += y.x; x.y += y.y; x.z += y.z; x.w += y.w;
        a[i] = x;
    }
}

// ---------------- edge propagation: one wave (64 lanes) per edge ----------------
// dst_u[u,d] += w * src_i[i,d];  dst_i[i,d] += w * src_u[u,d]
__global__ void prop_kernel(const float* __restrict__ srcU, const float* __restrict__ srcI,
                            float* __restrict__ dstU, float* __restrict__ dstI,
                            const int* __restrict__ eu, const int* __restrict__ ei,
                            const float* __restrict__ dinv) {
    int wave = (blockIdx.x * blockDim.x + threadIdx.x) >> 6;
    int lane = threadIdx.x & 63;
    int nwaves = (gridDim.x * blockDim.x) >> 6;
    for (int e = wave; e < E_N; e += nwaves) {
        int u = eu[e];
        int i = ei[e];
        float w = dinv[u] * dinv[U_N + i];
        float hu = srcU[(size_t)u * D_N + lane];
        float hi = srcI[(size_t)i * D_N + lane];
        atomicAdd(&dstU[(size_t)u * D_N + lane], w * hi);
        atomicAdd(&dstI[(size_t)i * D_N + lane], w * hu);
    }
}

// ---------------- out = out * 0.25; out[U:] += v_emb ----------------
__global__ void final_kernel(float* __restrict__ out, const float* __restrict__ v_emb) {
    size_t t = (size_t)blockIdx.x * blockDim.x + threadIdx.x;
    size_t stride = (size_t)gridDim.x * blockDim.x;
    const size_t nu4 = (size_t)U_N * D_N / 4;
    const size_t n4 = (size_t)N_NODES * D_N / 4;
    float4* o = (float4*)out;
    const float4* v = (const float4*)v_emb;
    for (size_t i = t; i < n4; i += stride) {
        float4 x = o[i];
        x.x *= 0.25f; x.y *= 0.25f; x.z *= 0.25f; x.w *= 0.25f;
        if (i >= nu4) {
            float4 vv = v[i - nu4];
            x.x += vv.x; x.y += vv.y; x.z += vv.z; x.w += vv.w;
        }
        o[i] = x;
    }
}

extern "C" void kernel_launch(void* const* d_in, const int* in_sizes, int n_in,
                              void* d_out, int out_size, void* d_ws, size_t ws_size,
                              hipStream_t stream) {
    const float* u_emb = (const float*)d_in[0];
    const float* v_emb = (const float*)d_in[1];
    const int* eu = (const int*)d_in[2];
    const int* ei = (const int*)d_in[3];
    float* out = (float*)d_out;

    // ws layout: dinv [N_NODES] (1 MiB aligned slab) | bufA [N*D] | bufB [N*D]
    char* ws = (char*)d_ws;
    float* dinv = (float*)ws;
    float* bufA = (float*)(ws + (1u << 20));
    float* bufB = bufA + (size_t)N_NODES * D_N;
    const size_t hbytes = (size_t)N_NODES * D_N * sizeof(float);

    hipMemsetAsync(dinv, 0, N_NODES * sizeof(float), stream);
    hipMemsetAsync(bufA, 0, hbytes, stream);
    hipMemsetAsync(bufB, 0, hbytes, stream);

    deg_kernel<<<2048, 256, 0, stream>>>(eu, ei, dinv);
    rsqrt_kernel<<<(N_NODES + 255) / 256, 256, 0, stream>>>(dinv);
    init_out_kernel<<<2048, 256, 0, stream>>>(u_emb, v_emb, out);

    float* bufA_i = bufA + (size_t)U_N * D_N;
    float* bufB_i = bufB + (size_t)U_N * D_N;
    float* out_i  = out + (size_t)U_N * D_N;

    // layer 1: src = ego (the raw inputs), dst = bufA
    prop_kernel<<<8192, 256, 0, stream>>>(u_emb, v_emb, bufA, bufA_i, eu, ei, dinv);
    add_kernel<<<2048, 256, 0, stream>>>(out, bufA);

    // layer 2: src = bufA, dst = bufB
    prop_kernel<<<8192, 256, 0, stream>>>(bufA, bufA_i, bufB, bufB_i, eu, ei, dinv);
    add_kernel<<<2048, 256, 0, stream>>>(out, bufB);

    // layer 3: src = bufB, dst = d_out directly (accumulates h3 into acc)
    prop_kernel<<<8192, 256, 0, stream>>>(bufB, bufB_i, out, out_i, eu, ei, dinv);

    final_kernel<<<2048, 256, 0, stream>>>(out, v_emb);
}

// Round 2
// 1469.529 us; speedup vs baseline: 1.4319x; 1.4319x over previous
//
#include <hip/hip_runtime.h>

#define U_N 150000
#define I_N 100000
#define D_N 64
#define E_N 1500000
#define N_NODES (U_N + I_N)

// ============================================================
// CSR build
// ============================================================

__global__ void hist_kernel(const int* __restrict__ eu, const int* __restrict__ ei,
                            int* __restrict__ cnt_u, int* __restrict__ cnt_i) {
    int t = blockIdx.x * blockDim.x + threadIdx.x;
    int stride = gridDim.x * blockDim.x;
    for (int e = t; e < E_N; e += stride) {
        atomicAdd(&cnt_u[eu[e]], 1);
        atomicAdd(&cnt_i[ei[e]], 1);
    }
}

// dinv[n] = rsqrt(deg + 1e-7)
__global__ void dinv_kernel(const int* __restrict__ cnt_u, const int* __restrict__ cnt_i,
                            float* __restrict__ dinv) {
    int t = blockIdx.x * blockDim.x + threadIdx.x;
    if (t >= N_NODES) return;
    int c = (t < U_N) ? cnt_u[t] : cnt_i[t - U_N];
    dinv[t] = rsqrtf((float)c + 1e-7f);
}

// single-block exclusive scan: rowptr[0..n] and cur[0..n-1] = rowptr values
#define SCAN_NT 1024
__global__ void scan_kernel(const int* __restrict__ cnt, int n,
                            int* __restrict__ rowptr, int* __restrict__ cur) {
    __shared__ int lds[SCAN_NT];
    int tid = threadIdx.x;
    int chunk = (n + SCAN_NT - 1) / SCAN_NT;
    int start = tid * chunk;
    int end = start + chunk; if (end > n) end = n;
    int sum = 0;
    for (int i = start; i < end; ++i) sum += cnt[i];
    lds[tid] = sum;
    __syncthreads();
    // inclusive Hillis-Steele scan in LDS
    for (int off = 1; off < SCAN_NT; off <<= 1) {
        int t = (tid >= off) ? lds[tid - off] : 0;
        __syncthreads();
        lds[tid] += t;
        __syncthreads();
    }
    int running = lds[tid] - sum;  // exclusive prefix of this thread's chunk
    for (int i = start; i < end; ++i) {
        rowptr[i] = running;
        cur[i] = running;
        running += cnt[i];
    }
    if (tid == SCAN_NT - 1) rowptr[n] = lds[SCAN_NT - 1];
}

__global__ void fill_kernel(const int* __restrict__ eu, const int* __restrict__ ei,
                            int* __restrict__ cur_u, int* __restrict__ cur_i,
                            int* __restrict__ col_u, int* __restrict__ col_i) {
    int t = blockIdx.x * blockDim.x + threadIdx.x;
    int stride = gridDim.x * blockDim.x;
    for (int e = t; e < E_N; e += stride) {
        int u = eu[e];
        int i = ei[e];
        int pu = atomicAdd(&cur_u[u], 1);
        col_u[pu] = i;         // user's neighbor: item index
        int pi = atomicAdd(&cur_i[i], 1);
        col_i[pi] = u;         // item's neighbor: user index
    }
}

// ============================================================
// elementwise helpers
// ============================================================

__global__ void init_out_kernel(const float* __restrict__ u_emb,
                                const float* __restrict__ v_emb,
                                float* __restrict__ out) {
    size_t t = (size_t)blockIdx.x * blockDim.x + threadIdx.x;
    size_t stride = (size_t)gridDim.x * blockDim.x;
    const size_t nu4 = (size_t)U_N * D_N / 4;
    const size_t ni4 = (size_t)I_N * D_N / 4;
    const float4* us = (const float4*)u_emb;
    const float4* vs = (const float4*)v_emb;
    float4* o = (float4*)out;
    for (size_t i = t; i < nu4; i += stride) o[i] = us[i];
    for (size_t i = t; i < ni4; i += stride) o[nu4 + i] = vs[i];
}

__global__ void final_kernel(float* __restrict__ out, const float* __restrict__ v_emb) {
    size_t t = (size_t)blockIdx.x * blockDim.x + threadIdx.x;
    size_t stride = (size_t)gridDim.x * blockDim.x;
    const size_t nu4 = (size_t)U_N * D_N / 4;
    const size_t n4 = (size_t)N_NODES * D_N / 4;
    float4* o = (float4*)out;
    const float4* v = (const float4*)v_emb;
    for (size_t i = t; i < n4; i += stride) {
        float4 x = o[i];
        x.x *= 0.25f; x.y *= 0.25f; x.z *= 0.25f; x.w *= 0.25f;
        if (i >= nu4) {
            float4 vv = v[i - nu4];
            x.x += vv.x; x.y += vv.y; x.z += vv.z; x.w += vv.w;
        }
        o[i] = x;
    }
}

// ============================================================
// CSR gather: one wave per destination node, lane = dim.
// h[n] = dinv[n] * sum_nbr dinv[nbr] * src[nbr];  acc[n] += h[n]
// ============================================================
__global__ void gather_kernel(const float* __restrict__ srcU, const float* __restrict__ srcI,
                              const int* __restrict__ rowptr_u, const int* __restrict__ col_u,
                              const int* __restrict__ rowptr_i, const int* __restrict__ col_i,
                              const float* __restrict__ dinv,
                              float* __restrict__ h_out, float* __restrict__ acc) {
    int wave = (int)((blockIdx.x * blockDim.x + threadIdx.x) >> 6);
    int lane = threadIdx.x & 63;
    if (wave >= N_NODES) return;
    const int* rp; const int* col; const float* src; const float* dnbr; int row;
    if (wave < U_N) { rp = rowptr_u; col = col_u; src = srcI; dnbr = dinv + U_N; row = wave; }
    else            { rp = rowptr_i; col = col_i; src = srcU; dnbr = dinv;       row = wave - U_N; }
    int beg = rp[row], end = rp[row + 1];
    float a = 0.0f;
    int j = beg;
    for (; j + 3 < end; j += 4) {
        int nb0 = col[j], nb1 = col[j + 1], nb2 = col[j + 2], nb3 = col[j + 3];
        float w0 = dnbr[nb0], w1 = dnbr[nb1], w2 = dnbr[nb2], w3 = dnbr[nb3];
        float s0 = src[(size_t)nb0 * D_N + lane];
        float s1 = src[(size_t)nb1 * D_N + lane];
        float s2 = src[(size_t)nb2 * D_N + lane];
        float s3 = src[(size_t)nb3 * D_N + lane];
        a = fmaf(w0, s0, a);
        a = fmaf(w1, s1, a);
        a = fmaf(w2, s2, a);
        a = fmaf(w3, s3, a);
    }
    for (; j < end; ++j) {
        int nb = col[j];
        a = fmaf(dnbr[nb], src[(size_t)nb * D_N + lane], a);
    }
    a *= dinv[wave];
    size_t o = (size_t)wave * D_N + lane;
    if (h_out) h_out[o] = a;
    acc[o] += a;
}

// ============================================================
// fallback (R1 atomic path) kernels, used only if ws too small
// ============================================================
__global__ void deg_kernel(const int* __restrict__ eu, const int* __restrict__ ei,
                           float* __restrict__ deg) {
    int t = blockIdx.x * blockDim.x + threadIdx.x;
    int stride = gridDim.x * blockDim.x;
    for (int e = t; e < E_N; e += stride) {
        atomicAdd(&deg[eu[e]], 1.0f);
        atomicAdd(&deg[U_N + ei[e]], 1.0f);
    }
}
__global__ void rsqrt_kernel(float* __restrict__ deg) {
    int t = blockIdx.x * blockDim.x + threadIdx.x;
    if (t < N_NODES) deg[t] = rsqrtf(deg[t] + 1e-7f);
}
__global__ void add_kernel(float* __restrict__ acc, const float* __restrict__ h) {
    size_t t = (size_t)blockIdx.x * blockDim.x + threadIdx.x;
    size_t stride = (size_t)gridDim.x * blockDim.x;
    const size_t n4 = (size_t)N_NODES * D_N / 4;
    float4* a = (float4*)acc;
    const float4* b = (const float4*)h;
    for (size_t i = t; i < n4; i += stride) {
        float4 x = a[i]; float4 y = b[i];
        x.x += y.x; x.y += y.y; x.z += y.z; x.w += y.w;
        a[i] = x;
    }
}
__global__ void prop_kernel(const float* __restrict__ srcU, const float* __restrict__ srcI,
                            float* __restrict__ dstU, float* __restrict__ dstI,
                            const int* __restrict__ eu, const int* __restrict__ ei,
                            const float* __restrict__ dinv) {
    int wave = (blockIdx.x * blockDim.x + threadIdx.x) >> 6;
    int lane = threadIdx.x & 63;
    int nwaves = (gridDim.x * blockDim.x) >> 6;
    for (int e = wave; e < E_N; e += nwaves) {
        int u = eu[e];
        int i = ei[e];
        float w = dinv[u] * dinv[U_N + i];
        float hu = srcU[(size_t)u * D_N + lane];
        float hi = srcI[(size_t)i * D_N + lane];
        atomicAdd(&dstU[(size_t)u * D_N + lane], w * hi);
        atomicAdd(&dstI[(size_t)i * D_N + lane], w * hu);
    }
}

// ============================================================
extern "C" void kernel_launch(void* const* d_in, const int* in_sizes, int n_in,
                              void* d_out, int out_size, void* d_ws, size_t ws_size,
                              hipStream_t stream) {
    const float* u_emb = (const float*)d_in[0];
    const float* v_emb = (const float*)d_in[1];
    const int* eu = (const int*)d_in[2];
    const int* ei = (const int*)d_in[3];
    float* out = (float*)d_out;

    const size_t hbytes = (size_t)N_NODES * D_N * sizeof(float);

    // workspace carve-up (256B aligned)
    size_t off = 0;
    auto carve = [&](size_t bytes) {
        size_t p = off;
        off = (off + bytes + 255) & ~(size_t)255;
        return p;
    };
    char* ws = (char*)d_ws;
    size_t o_dinv   = carve((size_t)N_NODES * 4);
    size_t o_cntu   = carve((size_t)U_N * 4);
    size_t o_cnti   = carve((size_t)I_N * 4);
    size_t o_rpu    = carve((size_t)(U_N + 1) * 4);
    size_t o_rpi    = carve((size_t)(I_N + 1) * 4);
    size_t o_curu   = carve((size_t)U_N * 4);
    size_t o_curi   = carve((size_t)I_N * 4);
    size_t o_colu   = carve((size_t)E_N * 4);
    size_t o_coli   = carve((size_t)E_N * 4);
    size_t o_bufA   = carve(hbytes);
    size_t o_bufB   = carve(hbytes);
    size_t needed = off;

    if (ws_size >= needed) {
        float* dinv = (float*)(ws + o_dinv);
        int* cnt_u = (int*)(ws + o_cntu);
        int* cnt_i = (int*)(ws + o_cnti);
        int* rp_u  = (int*)(ws + o_rpu);
        int* rp_i  = (int*)(ws + o_rpi);
        int* cur_u = (int*)(ws + o_curu);
        int* cur_i = (int*)(ws + o_curi);
        int* col_u = (int*)(ws + o_colu);
        int* col_i = (int*)(ws + o_coli);
        float* bufA = (float*)(ws + o_bufA);
        float* bufB = (float*)(ws + o_bufB);

        hipMemsetAsync(cnt_u, 0, (size_t)U_N * 4, stream);
        hipMemsetAsync(cnt_i, 0, (size_t)I_N * 4, stream);

        hist_kernel<<<2048, 256, 0, stream>>>(eu, ei, cnt_u, cnt_i);
        dinv_kernel<<<(N_NODES + 255) / 256, 256, 0, stream>>>(cnt_u, cnt_i, dinv);
        scan_kernel<<<1, SCAN_NT, 0, stream>>>(cnt_u, U_N, rp_u, cur_u);
        scan_kernel<<<1, SCAN_NT, 0, stream>>>(cnt_i, I_N, rp_i, cur_i);
        fill_kernel<<<2048, 256, 0, stream>>>(eu, ei, cur_u, cur_i, col_u, col_i);

        init_out_kernel<<<2048, 256, 0, stream>>>(u_emb, v_emb, out);

        const int gblocks = (N_NODES * 64 + 255) / 256;
        // layer 1: src = ego (raw inputs) -> h1 = bufA, acc += h1
        gather_kernel<<<gblocks, 256, 0, stream>>>(u_emb, v_emb, rp_u, col_u, rp_i, col_i,
                                                   dinv, bufA, out);
        // layer 2: src = bufA -> h2 = bufB, acc += h2
        gather_kernel<<<gblocks, 256, 0, stream>>>(bufA, bufA + (size_t)U_N * D_N,
                                                   rp_u, col_u, rp_i, col_i,
                                                   dinv, bufB, out);
        // layer 3: src = bufB -> acc += h3 (no h write)
        gather_kernel<<<gblocks, 256, 0, stream>>>(bufB, bufB + (size_t)U_N * D_N,
                                                   rp_u, col_u, rp_i, col_i,
                                                   dinv, (float*)nullptr, out);

        final_kernel<<<2048, 256, 0, stream>>>(out, v_emb);
    } else {
        // fallback: R1 atomic-scatter path (needs ~130 MB)
        float* dinv = (float*)ws;
        float* bufA = (float*)(ws + (1u << 20));
        float* bufB = bufA + (size_t)N_NODES * D_N;
        hipMemsetAsync(dinv, 0, N_NODES * sizeof(float), stream);
        hipMemsetAsync(bufA, 0, hbytes, stream);
        hipMemsetAsync(bufB, 0, hbytes, stream);
        deg_kernel<<<2048, 256, 0, stream>>>(eu, ei, dinv);
        rsqrt_kernel<<<(N_NODES + 255) / 256, 256, 0, stream>>>(dinv);
        init_out_kernel<<<2048, 256, 0, stream>>>(u_emb, v_emb, out);
        float* bufA_i = bufA + (size_t)U_N * D_N;
        float* bufB_i = bufB + (size_t)U_N * D_N;
        float* out_i  = out + (size_t)U_N * D_N;
        prop_kernel<<<8192, 256, 0, stream>>>(u_emb, v_emb, bufA, bufA_i, eu, ei, dinv);
        add_kernel<<<2048, 256, 0, stream>>>(out, bufA);
        prop_kernel<<<8192, 256, 0, stream>>>(bufA, bufA_i, bufB, bufB_i, eu, ei, dinv);
        add_kernel<<<2048, 256, 0, stream>>>(out, bufB);
        prop_kernel<<<8192, 256, 0, stream>>>(bufB, bufB_i, out, out_i, eu, ei, dinv);
        final_kernel<<<2048, 256, 0, stream>>>(out, v_emb);
    }
}

// Round 3
// 939.211 us; speedup vs baseline: 2.2405x; 1.5646x over previous
//
#include <hip/hip_runtime.h>

#define U_N 150000
#define I_N 100000
#define D_N 64
#define E_N 1500000
#define N_NODES (U_N + I_N)

// ============================================================
// CSR build
// ============================================================

__global__ void hist_kernel(const int* __restrict__ eu, const int* __restrict__ ei,
                            int* __restrict__ cnt_u, int* __restrict__ cnt_i) {
    int t = blockIdx.x * blockDim.x + threadIdx.x;
    int stride = gridDim.x * blockDim.x;
    for (int e = t; e < E_N; e += stride) {
        atomicAdd(&cnt_u[eu[e]], 1);
        atomicAdd(&cnt_i[ei[e]], 1);
    }
}

// dinv[n] = rsqrt(deg + 1e-7)
__global__ void dinv_kernel(const int* __restrict__ cnt_u, const int* __restrict__ cnt_i,
                            float* __restrict__ dinv) {
    int t = blockIdx.x * blockDim.x + threadIdx.x;
    if (t >= N_NODES) return;
    int c = (t < U_N) ? cnt_u[t] : cnt_i[t - U_N];
    dinv[t] = rsqrtf((float)c + 1e-7f);
}

// ---------- hierarchical exclusive scan ----------
#define SB_NT 256
#define SB_EPT 8
#define SB_CHUNK (SB_NT * SB_EPT)  // 2048 elems per block

// phase 1: per-block sums
__global__ void scan_phase1(const int* __restrict__ cnt, int n, int* __restrict__ bsum) {
    __shared__ int lds[SB_NT];
    int b = blockIdx.x;
    int tid = threadIdx.x;
    int start = b * SB_CHUNK + tid * SB_EPT;
    int s = 0;
#pragma unroll
    for (int k = 0; k < SB_EPT; ++k) {
        int i = start + k;
        if (i < n) s += cnt[i];
    }
    lds[tid] = s;
    __syncthreads();
    for (int off = SB_NT / 2; off > 0; off >>= 1) {
        if (tid < off) lds[tid] += lds[tid + off];
        __syncthreads();
    }
    if (tid == 0) bsum[b] = lds[0];
}

// phase 2: single-block exclusive scan of block sums (nb <= SB_NT)
__global__ void scan_phase2(int* __restrict__ bsum, int nb) {
    __shared__ int lds[SB_NT];
    int tid = threadIdx.x;
    int v = (tid < nb) ? bsum[tid] : 0;
    lds[tid] = v;
    __syncthreads();
    for (int off = 1; off < SB_NT; off <<= 1) {
        int t = (tid >= off) ? lds[tid - off] : 0;
        __syncthreads();
        lds[tid] += t;
        __syncthreads();
    }
    if (tid < nb) bsum[tid] = lds[tid] - v;  // exclusive
}

// phase 3: local scan + block offset -> rowptr, cur; also rowptr[n]
__global__ void scan_phase3(const int* __restrict__ cnt, int n,
                            const int* __restrict__ bsum,
                            int* __restrict__ rowptr, int* __restrict__ cur) {
    __shared__ int lds[SB_NT];
    int b = blockIdx.x;
    int tid = threadIdx.x;
    int start = b * SB_CHUNK + tid * SB_EPT;
    int vals[SB_EPT];
    int s = 0;
#pragma unroll
    for (int k = 0; k < SB_EPT; ++k) {
        int i = start + k;
        vals[k] = (i < n) ? cnt[i] : 0;
        s += vals[k];
    }
    lds[tid] = s;
    __syncthreads();
    for (int off = 1; off < SB_NT; off <<= 1) {
        int t = (tid >= off) ? lds[tid - off] : 0;
        __syncthreads();
        lds[tid] += t;
        __syncthreads();
    }
    int running = bsum[b] + lds[tid] - s;  // exclusive prefix for this thread
#pragma unroll
    for (int k = 0; k < SB_EPT; ++k) {
        int i = start + k;
        if (i < n) {
            rowptr[i] = running;
            cur[i] = running;
            running += vals[k];
            if (i == n - 1) rowptr[n] = running;
        }
    }
}

__global__ void fill_kernel(const int* __restrict__ eu, const int* __restrict__ ei,
                            int* __restrict__ cur_u, int* __restrict__ cur_i,
                            int* __restrict__ col_u, int* __restrict__ col_i) {
    int t = blockIdx.x * blockDim.x + threadIdx.x;
    int stride = gridDim.x * blockDim.x;
    for (int e = t; e < E_N; e += stride) {
        int u = eu[e];
        int i = ei[e];
        int pu = atomicAdd(&cur_u[u], 1);
        col_u[pu] = i;         // user's neighbor: item index
        int pi = atomicAdd(&cur_i[i], 1);
        col_i[pi] = u;         // item's neighbor: user index
    }
}

// ============================================================
// elementwise helpers
// ============================================================

__global__ void init_out_kernel(const float* __restrict__ u_emb,
                                const float* __restrict__ v_emb,
                                float* __restrict__ out) {
    size_t t = (size_t)blockIdx.x * blockDim.x + threadIdx.x;
    size_t stride = (size_t)gridDim.x * blockDim.x;
    const size_t nu4 = (size_t)U_N * D_N / 4;
    const size_t ni4 = (size_t)I_N * D_N / 4;
    const float4* us = (const float4*)u_emb;
    const float4* vs = (const float4*)v_emb;
    float4* o = (float4*)out;
    for (size_t i = t; i < nu4; i += stride) o[i] = us[i];
    for (size_t i = t; i < ni4; i += stride) o[nu4 + i] = vs[i];
}

__global__ void final_kernel(float* __restrict__ out, const float* __restrict__ v_emb) {
    size_t t = (size_t)blockIdx.x * blockDim.x + threadIdx.x;
    size_t stride = (size_t)gridDim.x * blockDim.x;
    const size_t nu4 = (size_t)U_N * D_N / 4;
    const size_t n4 = (size_t)N_NODES * D_N / 4;
    float4* o = (float4*)out;
    const float4* v = (const float4*)v_emb;
    for (size_t i = t; i < n4; i += stride) {
        float4 x = o[i];
        x.x *= 0.25f; x.y *= 0.25f; x.z *= 0.25f; x.w *= 0.25f;
        if (i >= nu4) {
            float4 vv = v[i - nu4];
            x.x += vv.x; x.y += vv.y; x.z += vv.z; x.w += vv.w;
        }
        o[i] = x;
    }
}

// ============================================================
// CSR gather: one wave per destination node, lane = dim.
// h[n] = dinv[n] * sum_nbr dinv[nbr] * src[nbr];  acc[n] += h[n]
// ============================================================
__global__ void gather_kernel(const float* __restrict__ srcU, const float* __restrict__ srcI,
                              const int* __restrict__ rowptr_u, const int* __restrict__ col_u,
                              const int* __restrict__ rowptr_i, const int* __restrict__ col_i,
                              const float* __restrict__ dinv,
                              float* __restrict__ h_out, float* __restrict__ acc) {
    int wave = (int)((blockIdx.x * blockDim.x + threadIdx.x) >> 6);
    int lane = threadIdx.x & 63;
    if (wave >= N_NODES) return;
    const int* rp; const int* col; const float* src; const float* dnbr; int row;
    if (wave < U_N) { rp = rowptr_u; col = col_u; src = srcI; dnbr = dinv + U_N; row = wave; }
    else            { rp = rowptr_i; col = col_i; src = srcU; dnbr = dinv;       row = wave - U_N; }
    int beg = rp[row], end = rp[row + 1];
    float a = 0.0f;
    int j = beg;
    for (; j + 3 < end; j += 4) {
        int nb0 = col[j], nb1 = col[j + 1], nb2 = col[j + 2], nb3 = col[j + 3];
        float w0 = dnbr[nb0], w1 = dnbr[nb1], w2 = dnbr[nb2], w3 = dnbr[nb3];
        float s0 = src[(size_t)nb0 * D_N + lane];
        float s1 = src[(size_t)nb1 * D_N + lane];
        float s2 = src[(size_t)nb2 * D_N + lane];
        float s3 = src[(size_t)nb3 * D_N + lane];
        a = fmaf(w0, s0, a);
        a = fmaf(w1, s1, a);
        a = fmaf(w2, s2, a);
        a = fmaf(w3, s3, a);
    }
    for (; j < end; ++j) {
        int nb = col[j];
        a = fmaf(dnbr[nb], src[(size_t)nb * D_N + lane], a);
    }
    a *= dinv[wave];
    size_t o = (size_t)wave * D_N + lane;
    if (h_out) h_out[o] = a;
    acc[o] += a;
}

// ============================================================
// fallback (R1 atomic path) kernels, used only if ws too small
// ============================================================
__global__ void deg_kernel(const int* __restrict__ eu, const int* __restrict__ ei,
                           float* __restrict__ deg) {
    int t = blockIdx.x * blockDim.x + threadIdx.x;
    int stride = gridDim.x * blockDim.x;
    for (int e = t; e < E_N; e += stride) {
        atomicAdd(&deg[eu[e]], 1.0f);
        atomicAdd(&deg[U_N + ei[e]], 1.0f);
    }
}
__global__ void rsqrt_kernel(float* __restrict__ deg) {
    int t = blockIdx.x * blockDim.x + threadIdx.x;
    if (t < N_NODES) deg[t] = rsqrtf(deg[t] + 1e-7f);
}
__global__ void add_kernel(float* __restrict__ acc, const float* __restrict__ h) {
    size_t t = (size_t)blockIdx.x * blockDim.x + threadIdx.x;
    size_t stride = (size_t)gridDim.x * blockDim.x;
    const size_t n4 = (size_t)N_NODES * D_N / 4;
    float4* a = (float4*)acc;
    const float4* b = (const float4*)h;
    for (size_t i = t; i < n4; i += stride) {
        float4 x = a[i]; float4 y = b[i];
        x.x += y.x; x.y += y.y; x.z += y.z; x.w += y.w;
        a[i] = x;
    }
}
__global__ void prop_kernel(const float* __restrict__ srcU, const float* __restrict__ srcI,
                            float* __restrict__ dstU, float* __restrict__ dstI,
                            const int* __restrict__ eu, const int* __restrict__ ei,
                            const float* __restrict__ dinv) {
    int wave = (blockIdx.x * blockDim.x + threadIdx.x) >> 6;
    int lane = threadIdx.x & 63;
    int nwaves = (gridDim.x * blockDim.x) >> 6;
    for (int e = wave; e < E_N; e += nwaves) {
        int u = eu[e];
        int i = ei[e];
        float w = dinv[u] * dinv[U_N + i];
        float hu = srcU[(size_t)u * D_N + lane];
        float hi = srcI[(size_t)i * D_N + lane];
        atomicAdd(&dstU[(size_t)u * D_N + lane], w * hi);
        atomicAdd(&dstI[(size_t)i * D_N + lane], w * hu);
    }
}

// ============================================================
extern "C" void kernel_launch(void* const* d_in, const int* in_sizes, int n_in,
                              void* d_out, int out_size, void* d_ws, size_t ws_size,
                              hipStream_t stream) {
    const float* u_emb = (const float*)d_in[0];
    const float* v_emb = (const float*)d_in[1];
    const int* eu = (const int*)d_in[2];
    const int* ei = (const int*)d_in[3];
    float* out = (float*)d_out;

    const size_t hbytes = (size_t)N_NODES * D_N * sizeof(float);

    // workspace carve-up (256B aligned)
    size_t off = 0;
    auto carve = [&](size_t bytes) {
        size_t p = off;
        off = (off + bytes + 255) & ~(size_t)255;
        return p;
    };
    char* ws = (char*)d_ws;
    size_t o_dinv   = carve((size_t)N_NODES * 4);
    size_t o_cntu   = carve((size_t)U_N * 4);
    size_t o_cnti   = carve((size_t)I_N * 4);
    size_t o_rpu    = carve((size_t)(U_N + 1) * 4);
    size_t o_rpi    = carve((size_t)(I_N + 1) * 4);
    size_t o_curu   = carve((size_t)U_N * 4);
    size_t o_curi   = carve((size_t)I_N * 4);
    size_t o_colu   = carve((size_t)E_N * 4);
    size_t o_coli   = carve((size_t)E_N * 4);
    size_t o_bsum   = carve((size_t)SB_NT * 4);
    size_t o_bufA   = carve(hbytes);
    size_t o_bufB   = carve(hbytes);
    size_t needed = off;

    if (ws_size >= needed) {
        float* dinv = (float*)(ws + o_dinv);
        int* cnt_u = (int*)(ws + o_cntu);
        int* cnt_i = (int*)(ws + o_cnti);
        int* rp_u  = (int*)(ws + o_rpu);
        int* rp_i  = (int*)(ws + o_rpi);
        int* cur_u = (int*)(ws + o_curu);
        int* cur_i = (int*)(ws + o_curi);
        int* col_u = (int*)(ws + o_colu);
        int* col_i = (int*)(ws + o_coli);
        int* bsum  = (int*)(ws + o_bsum);
        float* bufA = (float*)(ws + o_bufA);
        float* bufB = (float*)(ws + o_bufB);

        hipMemsetAsync(cnt_u, 0, (size_t)U_N * 4, stream);
        hipMemsetAsync(cnt_i, 0, (size_t)I_N * 4, stream);

        hist_kernel<<<2048, 256, 0, stream>>>(eu, ei, cnt_u, cnt_i);
        dinv_kernel<<<(N_NODES + 255) / 256, 256, 0, stream>>>(cnt_u, cnt_i, dinv);

        // hierarchical scans (U then I); nb <= 74 <= SB_NT
        {
            int nb_u = (U_N + SB_CHUNK - 1) / SB_CHUNK;
            scan_phase1<<<nb_u, SB_NT, 0, stream>>>(cnt_u, U_N, bsum);
            scan_phase2<<<1, SB_NT, 0, stream>>>(bsum, nb_u);
            scan_phase3<<<nb_u, SB_NT, 0, stream>>>(cnt_u, U_N, bsum, rp_u, cur_u);
            int nb_i = (I_N + SB_CHUNK - 1) / SB_CHUNK;
            scan_phase1<<<nb_i, SB_NT, 0, stream>>>(cnt_i, I_N, bsum);
            scan_phase2<<<1, SB_NT, 0, stream>>>(bsum, nb_i);
            scan_phase3<<<nb_i, SB_NT, 0, stream>>>(cnt_i, I_N, bsum, rp_i, cur_i);
        }

        fill_kernel<<<2048, 256, 0, stream>>>(eu, ei, cur_u, cur_i, col_u, col_i);

        init_out_kernel<<<2048, 256, 0, stream>>>(u_emb, v_emb, out);

        const int gblocks = (N_NODES * 64 + 255) / 256;
        // layer 1: src = ego (raw inputs) -> h1 = bufA, acc += h1
        gather_kernel<<<gblocks, 256, 0, stream>>>(u_emb, v_emb, rp_u, col_u, rp_i, col_i,
                                                   dinv, bufA, out);
        // layer 2: src = bufA -> h2 = bufB, acc += h2
        gather_kernel<<<gblocks, 256, 0, stream>>>(bufA, bufA + (size_t)U_N * D_N,
                                                   rp_u, col_u, rp_i, col_i,
                                                   dinv, bufB, out);
        // layer 3: src = bufB -> acc += h3 (no h write)
        gather_kernel<<<gblocks, 256, 0, stream>>>(bufB, bufB + (size_t)U_N * D_N,
                                                   rp_u, col_u, rp_i, col_i,
                                                   dinv, (float*)nullptr, out);

        final_kernel<<<2048, 256, 0, stream>>>(out, v_emb);
    } else {
        // fallback: R1 atomic-scatter path (needs ~130 MB)
        float* dinv = (float*)ws;
        float* bufA = (float*)(ws + (1u << 20));
        float* bufB = bufA + (size_t)N_NODES * D_N;
        hipMemsetAsync(dinv, 0, N_NODES * sizeof(float), stream);
        hipMemsetAsync(bufA, 0, hbytes, stream);
        hipMemsetAsync(bufB, 0, hbytes, stream);
        deg_kernel<<<2048, 256, 0, stream>>>(eu, ei, dinv);
        rsqrt_kernel<<<(N_NODES + 255) / 256, 256, 0, stream>>>(dinv);
        init_out_kernel<<<2048, 256, 0, stream>>>(u_emb, v_emb, out);
        float* bufA_i = bufA + (size_t)U_N * D_N;
        float* bufB_i = bufB + (size_t)U_N * D_N;
        float* out_i  = out + (size_t)U_N * D_N;
        prop_kernel<<<8192, 256, 0, stream>>>(u_emb, v_emb, bufA, bufA_i, eu, ei, dinv);
        add_kernel<<<2048, 256, 0, stream>>>(out, bufA);
        prop_kernel<<<8192, 256, 0, stream>>>(bufA, bufA_i, bufB, bufB_i, eu, ei, dinv);
        add_kernel<<<2048, 256, 0, stream>>>(out, bufB);
        prop_kernel<<<8192, 256, 0, stream>>>(bufB, bufB_i, out, out_i, eu, ei, dinv);
        final_kernel<<<2048, 256, 0, stream>>>(out, v_emb);
    }
}

// Round 4
// 779.058 us; speedup vs baseline: 2.7011x; 1.2056x over previous
//
#include <hip/hip_runtime.h>

#define U_N 150000
#define I_N 100000
#define D_N 64
#define E_N 1500000
#define N_NODES (U_N + I_N)

// bucket geometry for the 2-pass CSR fill
#define BSHIFT 11
#define BW (1 << BSHIFT)          // 2048 keys per bucket
#define NB_U ((U_N + BW - 1) / BW)  // 74
#define NB_I ((I_N + BW - 1) / BW)  // 49
#define NBMAX 128
#define CH 8192                   // edges staged per block in pass 1

// ============================================================
// degree histogram + dinv
// ============================================================
__global__ void hist_kernel(const int* __restrict__ eu, const int* __restrict__ ei,
                            int* __restrict__ cnt_u, int* __restrict__ cnt_i) {
    int t = blockIdx.x * blockDim.x + threadIdx.x;
    int stride = gridDim.x * blockDim.x;
    for (int e = t; e < E_N; e += stride) {
        atomicAdd(&cnt_u[eu[e]], 1);
        atomicAdd(&cnt_i[ei[e]], 1);
    }
}

__global__ void dinv_kernel(const int* __restrict__ cnt_u, const int* __restrict__ cnt_i,
                            float* __restrict__ dinv) {
    int t = blockIdx.x * blockDim.x + threadIdx.x;
    if (t >= N_NODES) return;
    int c = (t < U_N) ? cnt_u[t] : cnt_i[t - U_N];
    dinv[t] = rsqrtf((float)c + 1e-7f);
}

// ---------- hierarchical exclusive scan (rowptr) ----------
#define SB_NT 256
#define SB_EPT 8
#define SB_CHUNK (SB_NT * SB_EPT)  // 2048 elems per block

__global__ void scan_phase1(const int* __restrict__ cnt, int n, int* __restrict__ bsum) {
    __shared__ int lds[SB_NT];
    int b = blockIdx.x;
    int tid = threadIdx.x;
    int start = b * SB_CHUNK + tid * SB_EPT;
    int s = 0;
#pragma unroll
    for (int k = 0; k < SB_EPT; ++k) {
        int i = start + k;
        if (i < n) s += cnt[i];
    }
    lds[tid] = s;
    __syncthreads();
    for (int off = SB_NT / 2; off > 0; off >>= 1) {
        if (tid < off) lds[tid] += lds[tid + off];
        __syncthreads();
    }
    if (tid == 0) bsum[b] = lds[0];
}

__global__ void scan_phase2(int* __restrict__ bsum, int nb) {
    __shared__ int lds[SB_NT];
    int tid = threadIdx.x;
    int v = (tid < nb) ? bsum[tid] : 0;
    lds[tid] = v;
    __syncthreads();
    for (int off = 1; off < SB_NT; off <<= 1) {
        int t = (tid >= off) ? lds[tid - off] : 0;
        __syncthreads();
        lds[tid] += t;
        __syncthreads();
    }
    if (tid < nb) bsum[tid] = lds[tid] - v;  // exclusive
}

__global__ void scan_phase3(const int* __restrict__ cnt, int n,
                            const int* __restrict__ bsum,
                            int* __restrict__ rowptr) {
    __shared__ int lds[SB_NT];
    int b = blockIdx.x;
    int tid = threadIdx.x;
    int start = b * SB_CHUNK + tid * SB_EPT;
    int vals[SB_EPT];
    int s = 0;
#pragma unroll
    for (int k = 0; k < SB_EPT; ++k) {
        int i = start + k;
        vals[k] = (i < n) ? cnt[i] : 0;
        s += vals[k];
    }
    lds[tid] = s;
    __syncthreads();
    for (int off = 1; off < SB_NT; off <<= 1) {
        int t = (tid >= off) ? lds[tid - off] : 0;
        __syncthreads();
        lds[tid] += t;
        __syncthreads();
    }
    int running = bsum[b] + lds[tid] - s;
#pragma unroll
    for (int k = 0; k < SB_EPT; ++k) {
        int i = start + k;
        if (i < n) {
            rowptr[i] = running;
            running += vals[k];
            if (i == n - 1) rowptr[n] = running;
        }
    }
}

// ============================================================
// 2-pass bucketed CSR fill
// ============================================================
// bucket cursors init: cursors[b] = rowptr[b<<BSHIFT]
__global__ void init_cursor_kernel(const int* __restrict__ rp_u, int* __restrict__ cur_bu,
                                   const int* __restrict__ rp_i, int* __restrict__ cur_bi) {
    int t = threadIdx.x;
    if (t < NB_U) cur_bu[t] = rp_u[t << BSHIFT];
    if (t < NB_I) cur_bi[t] = rp_i[t << BSHIFT];
}

// pass 1: stage (key,payload) pairs bucket-contiguously, coalesced writes
__global__ void stage_kernel(const int* __restrict__ keys, const int* __restrict__ pays,
                             int* __restrict__ cursors, int2* __restrict__ staging) {
    __shared__ int2 sp[CH];
    __shared__ unsigned short sb[CH];
    __shared__ int hist[NBMAX];
    __shared__ int scanb[NBMAX];
    __shared__ int cur[NBMAX];
    __shared__ int gbase[NBMAX];
    int tid = threadIdx.x;
    int e0 = blockIdx.x * CH;
    int cnt = E_N - e0;
    if (cnt <= 0) return;
    if (cnt > CH) cnt = CH;

    for (int b = tid; b < NBMAX; b += blockDim.x) hist[b] = 0;
    __syncthreads();
    for (int s = tid; s < cnt; s += blockDim.x)
        atomicAdd(&hist[keys[e0 + s] >> BSHIFT], 1);
    __syncthreads();
    // exclusive scan of hist over NBMAX (Hillis-Steele, inclusive then shift)
    if (tid < NBMAX) scanb[tid] = hist[tid];
    __syncthreads();
    for (int off = 1; off < NBMAX; off <<= 1) {
        int v = 0;
        if (tid < NBMAX && tid >= off) v = scanb[tid - off];
        __syncthreads();
        if (tid < NBMAX) scanb[tid] += v;
        __syncthreads();
    }
    if (tid < NBMAX) cur[tid] = scanb[tid] - hist[tid];  // exclusive base
    __syncthreads();
    // compact into LDS, bucket-sorted
    for (int s = tid; s < cnt; s += blockDim.x) {
        int k = keys[e0 + s];
        int p = pays[e0 + s];
        int b = k >> BSHIFT;
        int pos = atomicAdd(&cur[b], 1);
        sp[pos] = make_int2(k, p);
        sb[pos] = (unsigned short)b;
    }
    __syncthreads();
    // reserve global ranges (one atomic per non-empty bucket)
    if (tid < NBMAX) {
        int c = hist[tid];
        gbase[tid] = c ? atomicAdd(&cursors[tid], c) : 0;
    }
    __syncthreads();
    // coalesced write-out
    for (int s = tid; s < cnt; s += blockDim.x) {
        int b = sb[s];
        int ebase = scanb[b] - hist[b];
        staging[gbase[b] + (s - ebase)] = sp[s];
    }
}

// pass 2: one block per bucket; LDS cursors; scatter within ~80KB col region
__global__ void scatter_kernel(const int2* __restrict__ staging,
                               const int* __restrict__ rp, int nkeys,
                               int* __restrict__ col) {
    __shared__ int curlds[BW];
    int b = blockIdx.x;
    int lo = b << BSHIFT;
    int hi = lo + BW;
    if (hi > nkeys) hi = nkeys;
    for (int k = lo + threadIdx.x; k < hi; k += blockDim.x)
        curlds[k - lo] = rp[k];
    __syncthreads();
    int sbeg = rp[lo];
    int send = rp[hi];
    for (int s = sbeg + threadIdx.x; s < send; s += blockDim.x) {
        int2 pr = staging[s];
        int pos = atomicAdd(&curlds[pr.x - lo], 1);
        col[pos] = pr.y;
    }
}

// ============================================================
// CSR gather: one wave per destination node, lane = dim. Pure write.
// ============================================================
__global__ void gather_kernel(const float* __restrict__ srcU, const float* __restrict__ srcI,
                              const int* __restrict__ rowptr_u, const int* __restrict__ col_u,
                              const int* __restrict__ rowptr_i, const int* __restrict__ col_i,
                              const float* __restrict__ dinv,
                              float* __restrict__ h_out) {
    int wave = (int)((blockIdx.x * blockDim.x + threadIdx.x) >> 6);
    int lane = threadIdx.x & 63;
    if (wave >= N_NODES) return;
    const int* rp; const int* col; const float* src; const float* dnbr; int row;
    if (wave < U_N) { rp = rowptr_u; col = col_u; src = srcI; dnbr = dinv + U_N; row = wave; }
    else            { rp = rowptr_i; col = col_i; src = srcU; dnbr = dinv;       row = wave - U_N; }
    int beg = rp[row], end = rp[row + 1];
    float a = 0.0f;
    int j = beg;
    for (; j + 3 < end; j += 4) {
        int nb0 = col[j], nb1 = col[j + 1], nb2 = col[j + 2], nb3 = col[j + 3];
        float w0 = dnbr[nb0], w1 = dnbr[nb1], w2 = dnbr[nb2], w3 = dnbr[nb3];
        float s0 = src[(size_t)nb0 * D_N + lane];
        float s1 = src[(size_t)nb1 * D_N + lane];
        float s2 = src[(size_t)nb2 * D_N + lane];
        float s3 = src[(size_t)nb3 * D_N + lane];
        a = fmaf(w0, s0, a);
        a = fmaf(w1, s1, a);
        a = fmaf(w2, s2, a);
        a = fmaf(w3, s3, a);
    }
    for (; j < end; ++j) {
        int nb = col[j];
        a = fmaf(dnbr[nb], src[(size_t)nb * D_N + lane], a);
    }
    a *= dinv[wave];
    h_out[(size_t)wave * D_N + lane] = a;
}

// ============================================================
// final: out = 0.25*(ego + h1 + h2 + h3) (+ v for item rows); out holds h3
// ============================================================
__global__ void final4_kernel(const float* __restrict__ u_emb, const float* __restrict__ v_emb,
                              const float* __restrict__ h1, const float* __restrict__ h2,
                              float* __restrict__ out) {
    size_t t = (size_t)blockIdx.x * blockDim.x + threadIdx.x;
    size_t stride = (size_t)gridDim.x * blockDim.x;
    const size_t nu4 = (size_t)U_N * D_N / 4;
    const size_t n4 = (size_t)N_NODES * D_N / 4;
    const float4* us = (const float4*)u_emb;
    const float4* vs = (const float4*)v_emb;
    const float4* a = (const float4*)h1;
    const float4* b = (const float4*)h2;
    float4* o = (float4*)out;
    for (size_t i = t; i < n4; i += stride) {
        float4 x = o[i];      // h3
        float4 y = a[i];
        float4 z = b[i];
        float4 e;
        bool item = (i >= nu4);
        e = item ? vs[i - nu4] : us[i];
        x.x = 0.25f * (x.x + y.x + z.x + e.x);
        x.y = 0.25f * (x.y + y.y + z.y + e.y);
        x.z = 0.25f * (x.z + y.z + z.z + e.z);
        x.w = 0.25f * (x.w + y.w + z.w + e.w);
        if (item) { x.x += e.x; x.y += e.y; x.z += e.z; x.w += e.w; }
        o[i] = x;
    }
}

// ============================================================
// fallback (R1 atomic path) kernels, used only if ws too small
// ============================================================
__global__ void deg_kernel(const int* __restrict__ eu, const int* __restrict__ ei,
                           float* __restrict__ deg) {
    int t = blockIdx.x * blockDim.x + threadIdx.x;
    int stride = gridDim.x * blockDim.x;
    for (int e = t; e < E_N; e += stride) {
        atomicAdd(&deg[eu[e]], 1.0f);
        atomicAdd(&deg[U_N + ei[e]], 1.0f);
    }
}
__global__ void rsqrt_kernel(float* __restrict__ deg) {
    int t = blockIdx.x * blockDim.x + threadIdx.x;
    if (t < N_NODES) deg[t] = rsqrtf(deg[t] + 1e-7f);
}
__global__ void init_out_kernel(const float* __restrict__ u_emb,
                                const float* __restrict__ v_emb,
                                float* __restrict__ out) {
    size_t t = (size_t)blockIdx.x * blockDim.x + threadIdx.x;
    size_t stride = (size_t)gridDim.x * blockDim.x;
    const size_t nu4 = (size_t)U_N * D_N / 4;
    const size_t ni4 = (size_t)I_N * D_N / 4;
    const float4* us = (const float4*)u_emb;
    const float4* vs = (const float4*)v_emb;
    float4* o = (float4*)out;
    for (size_t i = t; i < nu4; i += stride) o[i] = us[i];
    for (size_t i = t; i < ni4; i += stride) o[nu4 + i] = vs[i];
}
__global__ void add_kernel(float* __restrict__ acc, const float* __restrict__ h) {
    size_t t = (size_t)blockIdx.x * blockDim.x + threadIdx.x;
    size_t stride = (size_t)gridDim.x * blockDim.x;
    const size_t n4 = (size_t)N_NODES * D_N / 4;
    float4* a = (float4*)acc;
    const float4* b = (const float4*)h;
    for (size_t i = t; i < n4; i += stride) {
        float4 x = a[i]; float4 y = b[i];
        x.x += y.x; x.y += y.y; x.z += y.z; x.w += y.w;
        a[i] = x;
    }
}
__global__ void prop_kernel(const float* __restrict__ srcU, const float* __restrict__ srcI,
                            float* __restrict__ dstU, float* __restrict__ dstI,
                            const int* __restrict__ eu, const int* __restrict__ ei,
                            const float* __restrict__ dinv) {
    int wave = (blockIdx.x * blockDim.x + threadIdx.x) >> 6;
    int lane = threadIdx.x & 63;
    int nwaves = (gridDim.x * blockDim.x) >> 6;
    for (int e = wave; e < E_N; e += nwaves) {
        int u = eu[e];
        int i = ei[e];
        float w = dinv[u] * dinv[U_N + i];
        float hu = srcU[(size_t)u * D_N + lane];
        float hi = srcI[(size_t)i * D_N + lane];
        atomicAdd(&dstU[(size_t)u * D_N + lane], w * hi);
        atomicAdd(&dstI[(size_t)i * D_N + lane], w * hu);
    }
}
__global__ void final_kernel(float* __restrict__ out, const float* __restrict__ v_emb) {
    size_t t = (size_t)blockIdx.x * blockDim.x + threadIdx.x;
    size_t stride = (size_t)gridDim.x * blockDim.x;
    const size_t nu4 = (size_t)U_N * D_N / 4;
    const size_t n4 = (size_t)N_NODES * D_N / 4;
    float4* o = (float4*)out;
    const float4* v = (const float4*)v_emb;
    for (size_t i = t; i < n4; i += stride) {
        float4 x = o[i];
        x.x *= 0.25f; x.y *= 0.25f; x.z *= 0.25f; x.w *= 0.25f;
        if (i >= nu4) {
            float4 vv = v[i - nu4];
            x.x += vv.x; x.y += vv.y; x.z += vv.z; x.w += vv.w;
        }
        o[i] = x;
    }
}

// ============================================================
extern "C" void kernel_launch(void* const* d_in, const int* in_sizes, int n_in,
                              void* d_out, int out_size, void* d_ws, size_t ws_size,
                              hipStream_t stream) {
    const float* u_emb = (const float*)d_in[0];
    const float* v_emb = (const float*)d_in[1];
    const int* eu = (const int*)d_in[2];
    const int* ei = (const int*)d_in[3];
    float* out = (float*)d_out;

    const size_t hbytes = (size_t)N_NODES * D_N * sizeof(float);

    size_t off = 0;
    auto carve = [&](size_t bytes) {
        size_t p = off;
        off = (off + bytes + 255) & ~(size_t)255;
        return p;
    };
    char* ws = (char*)d_ws;
    size_t o_dinv = carve((size_t)N_NODES * 4);
    size_t o_cntu = carve((size_t)U_N * 4);
    size_t o_cnti = carve((size_t)I_N * 4);
    size_t o_rpu  = carve((size_t)(U_N + 1) * 4);
    size_t o_rpi  = carve((size_t)(I_N + 1) * 4);
    size_t o_colu = carve((size_t)E_N * 4);
    size_t o_coli = carve((size_t)E_N * 4);
    size_t o_bsum = carve((size_t)SB_NT * 4);
    size_t o_curbu = carve((size_t)NB_U * 4);
    size_t o_curbi = carve((size_t)NB_I * 4);
    size_t o_bufA = carve(hbytes);
    size_t o_bufB = carve(hbytes);   // also aliased as pair staging during CSR build
    size_t needed = off;

    if (ws_size >= needed) {
        float* dinv = (float*)(ws + o_dinv);
        int* cnt_u = (int*)(ws + o_cntu);
        int* cnt_i = (int*)(ws + o_cnti);
        int* rp_u  = (int*)(ws + o_rpu);
        int* rp_i  = (int*)(ws + o_rpi);
        int* col_u = (int*)(ws + o_colu);
        int* col_i = (int*)(ws + o_coli);
        int* bsum  = (int*)(ws + o_bsum);
        int* cur_bu = (int*)(ws + o_curbu);
        int* cur_bi = (int*)(ws + o_curbi);
        float* bufA = (float*)(ws + o_bufA);
        float* bufB = (float*)(ws + o_bufB);
        int2* staging = (int2*)bufB;   // alias: staging (12MB) used before bufB's h2 role

        hipMemsetAsync(cnt_u, 0, (size_t)U_N * 4, stream);
        hipMemsetAsync(cnt_i, 0, (size_t)I_N * 4, stream);

        hist_kernel<<<2048, 256, 0, stream>>>(eu, ei, cnt_u, cnt_i);
        dinv_kernel<<<(N_NODES + 255) / 256, 256, 0, stream>>>(cnt_u, cnt_i, dinv);

        {
            int nb_u = (U_N + SB_CHUNK - 1) / SB_CHUNK;
            scan_phase1<<<nb_u, SB_NT, 0, stream>>>(cnt_u, U_N, bsum);
            scan_phase2<<<1, SB_NT, 0, stream>>>(bsum, nb_u);
            scan_phase3<<<nb_u, SB_NT, 0, stream>>>(cnt_u, U_N, bsum, rp_u);
            int nb_i = (I_N + SB_CHUNK - 1) / SB_CHUNK;
            scan_phase1<<<nb_i, SB_NT, 0, stream>>>(cnt_i, I_N, bsum);
            scan_phase2<<<1, SB_NT, 0, stream>>>(bsum, nb_i);
            scan_phase3<<<nb_i, SB_NT, 0, stream>>>(cnt_i, I_N, bsum, rp_i);
        }

        init_cursor_kernel<<<1, 128, 0, stream>>>(rp_u, cur_bu, rp_i, cur_bi);

        const int sblocks = (E_N + CH - 1) / CH;
        // user-direction CSR: key = eu, payload = ei
        stage_kernel<<<sblocks, 256, 0, stream>>>(eu, ei, cur_bu, staging);
        scatter_kernel<<<NB_U, 256, 0, stream>>>(staging, rp_u, U_N, col_u);
        // item-direction CSR: key = ei, payload = eu
        stage_kernel<<<sblocks, 256, 0, stream>>>(ei, eu, cur_bi, staging);
        scatter_kernel<<<NB_I, 256, 0, stream>>>(staging, rp_i, I_N, col_i);

        const int gblocks = (N_NODES * 64 + 255) / 256;
        // layer 1: src = ego -> h1 = bufA
        gather_kernel<<<gblocks, 256, 0, stream>>>(u_emb, v_emb, rp_u, col_u, rp_i, col_i,
                                                   dinv, bufA);
        // layer 2: src = bufA -> h2 = bufB (overwrites staging; build is done)
        gather_kernel<<<gblocks, 256, 0, stream>>>(bufA, bufA + (size_t)U_N * D_N,
                                                   rp_u, col_u, rp_i, col_i, dinv, bufB);
        // layer 3: src = bufB -> h3 = out
        gather_kernel<<<gblocks, 256, 0, stream>>>(bufB, bufB + (size_t)U_N * D_N,
                                                   rp_u, col_u, rp_i, col_i, dinv, out);

        final4_kernel<<<2048, 256, 0, stream>>>(u_emb, v_emb, bufA, bufB, out);
    } else {
        // fallback: R1 atomic-scatter path
        float* dinv = (float*)ws;
        float* bufA = (float*)(ws + (1u << 20));
        float* bufB = bufA + (size_t)N_NODES * D_N;
        hipMemsetAsync(dinv, 0, N_NODES * sizeof(float), stream);
        hipMemsetAsync(bufA, 0, hbytes, stream);
        hipMemsetAsync(bufB, 0, hbytes, stream);
        deg_kernel<<<2048, 256, 0, stream>>>(eu, ei, dinv);
        rsqrt_kernel<<<(N_NODES + 255) / 256, 256, 0, stream>>>(dinv);
        init_out_kernel<<<2048, 256, 0, stream>>>(u_emb, v_emb, out);
        float* bufA_i = bufA + (size_t)U_N * D_N;
        float* bufB_i = bufB + (size_t)U_N * D_N;
        float* out_i  = out + (size_t)U_N * D_N;
        prop_kernel<<<8192, 256, 0, stream>>>(u_emb, v_emb, bufA, bufA_i, eu, ei, dinv);
        add_kernel<<<2048, 256, 0, stream>>>(out, bufA);
        prop_kernel<<<8192, 256, 0, stream>>>(bufA, bufA_i, bufB, bufB_i, eu, ei, dinv);
        add_kernel<<<2048, 256, 0, stream>>>(out, bufB);
        prop_kernel<<<8192, 256, 0, stream>>>(bufB, bufB_i, out, out_i, eu, ei, dinv);
        final_kernel<<<2048, 256, 0, stream>>>(out, v_emb);
    }
}

// Round 5
// 704.792 us; speedup vs baseline: 2.9857x; 1.1054x over previous
//
#include <hip/hip_runtime.h>

#define U_N 150000
#define I_N 100000
#define D_N 64
#define E_N 1500000
#define N_NODES (U_N + I_N)

// bucket geometry for the 2-pass CSR fill
#define BSHIFT 11
#define BW (1 << BSHIFT)          // 2048 keys per bucket
#define NB_U ((U_N + BW - 1) / BW)  // 74
#define NB_I ((I_N + BW - 1) / BW)  // 49
#define NBMAX 128
#define CH 8192                   // edges staged per block in pass 1

// ============================================================
// degree histogram + dinv
// ============================================================
__global__ void hist_kernel(const int* __restrict__ eu, const int* __restrict__ ei,
                            int* __restrict__ cnt_u, int* __restrict__ cnt_i) {
    int t = blockIdx.x * blockDim.x + threadIdx.x;
    int stride = gridDim.x * blockDim.x;
    for (int e = t; e < E_N; e += stride) {
        atomicAdd(&cnt_u[eu[e]], 1);
        atomicAdd(&cnt_i[ei[e]], 1);
    }
}

__global__ void dinv_kernel(const int* __restrict__ cnt_u, const int* __restrict__ cnt_i,
                            float* __restrict__ dinv) {
    int t = blockIdx.x * blockDim.x + threadIdx.x;
    if (t >= N_NODES) return;
    int c = (t < U_N) ? cnt_u[t] : cnt_i[t - U_N];
    dinv[t] = rsqrtf((float)c + 1e-7f);
}

// ---------- hierarchical exclusive scan (rowptr) ----------
#define SB_NT 256
#define SB_EPT 8
#define SB_CHUNK (SB_NT * SB_EPT)  // 2048 elems per block

__global__ void scan_phase1(const int* __restrict__ cnt, int n, int* __restrict__ bsum) {
    __shared__ int lds[SB_NT];
    int b = blockIdx.x;
    int tid = threadIdx.x;
    int start = b * SB_CHUNK + tid * SB_EPT;
    int s = 0;
#pragma unroll
    for (int k = 0; k < SB_EPT; ++k) {
        int i = start + k;
        if (i < n) s += cnt[i];
    }
    lds[tid] = s;
    __syncthreads();
    for (int off = SB_NT / 2; off > 0; off >>= 1) {
        if (tid < off) lds[tid] += lds[tid + off];
        __syncthreads();
    }
    if (tid == 0) bsum[b] = lds[0];
}

__global__ void scan_phase2(int* __restrict__ bsum, int nb) {
    __shared__ int lds[SB_NT];
    int tid = threadIdx.x;
    int v = (tid < nb) ? bsum[tid] : 0;
    lds[tid] = v;
    __syncthreads();
    for (int off = 1; off < SB_NT; off <<= 1) {
        int t = (tid >= off) ? lds[tid - off] : 0;
        __syncthreads();
        lds[tid] += t;
        __syncthreads();
    }
    if (tid < nb) bsum[tid] = lds[tid] - v;  // exclusive
}

__global__ void scan_phase3(const int* __restrict__ cnt, int n,
                            const int* __restrict__ bsum,
                            int* __restrict__ rowptr) {
    __shared__ int lds[SB_NT];
    int b = blockIdx.x;
    int tid = threadIdx.x;
    int start = b * SB_CHUNK + tid * SB_EPT;
    int vals[SB_EPT];
    int s = 0;
#pragma unroll
    for (int k = 0; k < SB_EPT; ++k) {
        int i = start + k;
        vals[k] = (i < n) ? cnt[i] : 0;
        s += vals[k];
    }
    lds[tid] = s;
    __syncthreads();
    for (int off = 1; off < SB_NT; off <<= 1) {
        int t = (tid >= off) ? lds[tid - off] : 0;
        __syncthreads();
        lds[tid] += t;
        __syncthreads();
    }
    int running = bsum[b] + lds[tid] - s;
#pragma unroll
    for (int k = 0; k < SB_EPT; ++k) {
        int i = start + k;
        if (i < n) {
            rowptr[i] = running;
            running += vals[k];
            if (i == n - 1) rowptr[n] = running;
        }
    }
}

// ============================================================
// 2-pass bucketed CSR fill
// ============================================================
__global__ void init_cursor_kernel(const int* __restrict__ rp_u, int* __restrict__ cur_bu,
                                   const int* __restrict__ rp_i, int* __restrict__ cur_bi) {
    int t = threadIdx.x;
    if (t < NB_U) cur_bu[t] = rp_u[t << BSHIFT];
    if (t < NB_I) cur_bi[t] = rp_i[t << BSHIFT];
}

__global__ void stage_kernel(const int* __restrict__ keys, const int* __restrict__ pays,
                             int* __restrict__ cursors, int2* __restrict__ staging) {
    __shared__ int2 sp[CH];
    __shared__ unsigned short sb[CH];
    __shared__ int hist[NBMAX];
    __shared__ int scanb[NBMAX];
    __shared__ int cur[NBMAX];
    __shared__ int gbase[NBMAX];
    int tid = threadIdx.x;
    int e0 = blockIdx.x * CH;
    int cnt = E_N - e0;
    if (cnt <= 0) return;
    if (cnt > CH) cnt = CH;

    for (int b = tid; b < NBMAX; b += blockDim.x) hist[b] = 0;
    __syncthreads();
    for (int s = tid; s < cnt; s += blockDim.x)
        atomicAdd(&hist[keys[e0 + s] >> BSHIFT], 1);
    __syncthreads();
    if (tid < NBMAX) scanb[tid] = hist[tid];
    __syncthreads();
    for (int off = 1; off < NBMAX; off <<= 1) {
        int v = 0;
        if (tid < NBMAX && tid >= off) v = scanb[tid - off];
        __syncthreads();
        if (tid < NBMAX) scanb[tid] += v;
        __syncthreads();
    }
    if (tid < NBMAX) cur[tid] = scanb[tid] - hist[tid];
    __syncthreads();
    for (int s = tid; s < cnt; s += blockDim.x) {
        int k = keys[e0 + s];
        int p = pays[e0 + s];
        int b = k >> BSHIFT;
        int pos = atomicAdd(&cur[b], 1);
        sp[pos] = make_int2(k, p);
        sb[pos] = (unsigned short)b;
    }
    __syncthreads();
    if (tid < NBMAX) {
        int c = hist[tid];
        gbase[tid] = c ? atomicAdd(&cursors[tid], c) : 0;
    }
    __syncthreads();
    for (int s = tid; s < cnt; s += blockDim.x) {
        int b = sb[s];
        int ebase = scanb[b] - hist[b];
        staging[gbase[b] + (s - ebase)] = sp[s];
    }
}

__global__ void scatter_kernel(const int2* __restrict__ staging,
                               const int* __restrict__ rp, int nkeys,
                               int* __restrict__ col) {
    __shared__ int curlds[BW];
    int b = blockIdx.x;
    int lo = b << BSHIFT;
    int hi = lo + BW;
    if (hi > nkeys) hi = nkeys;
    for (int k = lo + threadIdx.x; k < hi; k += blockDim.x)
        curlds[k - lo] = rp[k];
    __syncthreads();
    int sbeg = rp[lo];
    int send = rp[hi];
    for (int s = sbeg + threadIdx.x; s < send; s += blockDim.x) {
        int2 pr = staging[s];
        int pos = atomicAdd(&curlds[pr.x - lo], 1);
        col[pos] = pr.y;
    }
}

// ============================================================
// CSR gather v2: one wave per destination node.
// Lane = (group g = lane>>4, dim-quad d4 = lane&15).
// Preload up to 64 (col, dinv[col]) per row into lanes; per iteration
// one float4 load services 4 neighbor rows (one per group).
// ============================================================
__global__ void gather_kernel(const float* __restrict__ srcU, const float* __restrict__ srcI,
                              const int* __restrict__ rowptr_u, const int* __restrict__ col_u,
                              const int* __restrict__ rowptr_i, const int* __restrict__ col_i,
                              const float* __restrict__ dinv,
                              float* __restrict__ h_out) {
    int wave = (int)((blockIdx.x * blockDim.x + threadIdx.x) >> 6);
    int lane = threadIdx.x & 63;
    if (wave >= N_NODES) return;
    const int* rp; const int* col; const float4* src4; const float* dnbr; int row;
    if (wave < U_N) { rp = rowptr_u; col = col_u; src4 = (const float4*)srcI; dnbr = dinv + U_N; row = wave; }
    else            { rp = rowptr_i; col = col_i; src4 = (const float4*)srcU; dnbr = dinv;       row = wave - U_N; }
    int beg = rp[row], end = rp[row + 1];
    int g  = lane >> 4;   // neighbor sub-slot 0..3
    int d4 = lane & 15;   // float4 index within the 64-dim row

    float4 acc = make_float4(0.f, 0.f, 0.f, 0.f);

    for (int base = beg; base < end; base += 64) {
        int li = base + lane;
        bool ok = (li < end);
        int cnb = ok ? col[li] : 0;       // coalesced neighbor-id preload
        float cw = ok ? dnbr[cnb] : 0.f;  // 64-lane gather on hot 1MB table
        int n = end - base; if (n > 64) n = 64;
        int iters = (n + 3) >> 2;
#pragma unroll 4
        for (int k = 0; k < iters; ++k) {
            int kk = (k << 2) + g;
            int nb = __shfl(cnb, kk, 64);   // lanes with kk>=n source cnb=0
            float w = __shfl(cw, kk, 64);   // ... and cw=0 -> contributes 0
            float4 s = src4[(size_t)nb * 16 + d4];
            acc.x = fmaf(w, s.x, acc.x);
            acc.y = fmaf(w, s.y, acc.y);
            acc.z = fmaf(w, s.z, acc.z);
            acc.w = fmaf(w, s.w, acc.w);
        }
    }

    // reduce the 4 neighbor sub-slots (groups) together
    acc.x += __shfl_xor(acc.x, 16, 64);
    acc.y += __shfl_xor(acc.y, 16, 64);
    acc.z += __shfl_xor(acc.z, 16, 64);
    acc.w += __shfl_xor(acc.w, 16, 64);
    acc.x += __shfl_xor(acc.x, 32, 64);
    acc.y += __shfl_xor(acc.y, 32, 64);
    acc.z += __shfl_xor(acc.z, 32, 64);
    acc.w += __shfl_xor(acc.w, 32, 64);

    if (g == 0) {
        float sc = dinv[wave];
        acc.x *= sc; acc.y *= sc; acc.z *= sc; acc.w *= sc;
        float4* h4 = (float4*)h_out;
        h4[(size_t)wave * 16 + d4] = acc;
    }
}

// ============================================================
// final: out = 0.25*(ego + h1 + h2 + h3) (+ v for item rows); out holds h3
// ============================================================
__global__ void final4_kernel(const float* __restrict__ u_emb, const float* __restrict__ v_emb,
                              const float* __restrict__ h1, const float* __restrict__ h2,
                              float* __restrict__ out) {
    size_t t = (size_t)blockIdx.x * blockDim.x + threadIdx.x;
    size_t stride = (size_t)gridDim.x * blockDim.x;
    const size_t nu4 = (size_t)U_N * D_N / 4;
    const size_t n4 = (size_t)N_NODES * D_N / 4;
    const float4* us = (const float4*)u_emb;
    const float4* vs = (const float4*)v_emb;
    const float4* a = (const float4*)h1;
    const float4* b = (const float4*)h2;
    float4* o = (float4*)out;
    for (size_t i = t; i < n4; i += stride) {
        float4 x = o[i];      // h3
        float4 y = a[i];
        float4 z = b[i];
        float4 e;
        bool item = (i >= nu4);
        e = item ? vs[i - nu4] : us[i];
        x.x = 0.25f * (x.x + y.x + z.x + e.x);
        x.y = 0.25f * (x.y + y.y + z.y + e.y);
        x.z = 0.25f * (x.z + y.z + z.z + e.z);
        x.w = 0.25f * (x.w + y.w + z.w + e.w);
        if (item) { x.x += e.x; x.y += e.y; x.z += e.z; x.w += e.w; }
        o[i] = x;
    }
}

// ============================================================
// fallback (R1 atomic path) kernels, used only if ws too small
// ============================================================
__global__ void deg_kernel(const int* __restrict__ eu, const int* __restrict__ ei,
                           float* __restrict__ deg) {
    int t = blockIdx.x * blockDim.x + threadIdx.x;
    int stride = gridDim.x * blockDim.x;
    for (int e = t; e < E_N; e += stride) {
        atomicAdd(&deg[eu[e]], 1.0f);
        atomicAdd(&deg[U_N + ei[e]], 1.0f);
    }
}
__global__ void rsqrt_kernel(float* __restrict__ deg) {
    int t = blockIdx.x * blockDim.x + threadIdx.x;
    if (t < N_NODES) deg[t] = rsqrtf(deg[t] + 1e-7f);
}
__global__ void init_out_kernel(const float* __restrict__ u_emb,
                                const float* __restrict__ v_emb,
                                float* __restrict__ out) {
    size_t t = (size_t)blockIdx.x * blockDim.x + threadIdx.x;
    size_t stride = (size_t)gridDim.x * blockDim.x;
    const size_t nu4 = (size_t)U_N * D_N / 4;
    const size_t ni4 = (size_t)I_N * D_N / 4;
    const float4* us = (const float4*)u_emb;
    const float4* vs = (const float4*)v_emb;
    float4* o = (float4*)out;
    for (size_t i = t; i < nu4; i += stride) o[i] = us[i];
    for (size_t i = t; i < ni4; i += stride) o[nu4 + i] = vs[i];
}
__global__ void add_kernel(float* __restrict__ acc, const float* __restrict__ h) {
    size_t t = (size_t)blockIdx.x * blockDim.x + threadIdx.x;
    size_t stride = (size_t)gridDim.x * blockDim.x;
    const size_t n4 = (size_t)N_NODES * D_N / 4;
    float4* a = (float4*)acc;
    const float4* b = (const float4*)h;
    for (size_t i = t; i < n4; i += stride) {
        float4 x = a[i]; float4 y = b[i];
        x.x += y.x; x.y += y.y; x.z += y.z; x.w += y.w;
        a[i] = x;
    }
}
__global__ void prop_kernel(const float* __restrict__ srcU, const float* __restrict__ srcI,
                            float* __restrict__ dstU, float* __restrict__ dstI,
                            const int* __restrict__ eu, const int* __restrict__ ei,
                            const float* __restrict__ dinv) {
    int wave = (blockIdx.x * blockDim.x + threadIdx.x) >> 6;
    int lane = threadIdx.x & 63;
    int nwaves = (gridDim.x * blockDim.x) >> 6;
    for (int e = wave; e < E_N; e += nwaves) {
        int u = eu[e];
        int i = ei[e];
        float w = dinv[u] * dinv[U_N + i];
        float hu = srcU[(size_t)u * D_N + lane];
        float hi = srcI[(size_t)i * D_N + lane];
        atomicAdd(&dstU[(size_t)u * D_N + lane], w * hi);
        atomicAdd(&dstI[(size_t)i * D_N + lane], w * hu);
    }
}
__global__ void final_kernel(float* __restrict__ out, const float* __restrict__ v_emb) {
    size_t t = (size_t)blockIdx.x * blockDim.x + threadIdx.x;
    size_t stride = (size_t)gridDim.x * blockDim.x;
    const size_t nu4 = (size_t)U_N * D_N / 4;
    const size_t n4 = (size_t)N_NODES * D_N / 4;
    float4* o = (float4*)out;
    const float4* v = (const float4*)v_emb;
    for (size_t i = t; i < n4; i += stride) {
        float4 x = o[i];
        x.x *= 0.25f; x.y *= 0.25f; x.z *= 0.25f; x.w *= 0.25f;
        if (i >= nu4) {
            float4 vv = v[i - nu4];
            x.x += vv.x; x.y += vv.y; x.z += vv.z; x.w += vv.w;
        }
        o[i] = x;
    }
}

// ============================================================
extern "C" void kernel_launch(void* const* d_in, const int* in_sizes, int n_in,
                              void* d_out, int out_size, void* d_ws, size_t ws_size,
                              hipStream_t stream) {
    const float* u_emb = (const float*)d_in[0];
    const float* v_emb = (const float*)d_in[1];
    const int* eu = (const int*)d_in[2];
    const int* ei = (const int*)d_in[3];
    float* out = (float*)d_out;

    const size_t hbytes = (size_t)N_NODES * D_N * sizeof(float);

    size_t off = 0;
    auto carve = [&](size_t bytes) {
        size_t p = off;
        off = (off + bytes + 255) & ~(size_t)255;
        return p;
    };
    char* ws = (char*)d_ws;
    size_t o_dinv = carve((size_t)N_NODES * 4);
    size_t o_cntu = carve((size_t)U_N * 4);
    size_t o_cnti = carve((size_t)I_N * 4);
    size_t o_rpu  = carve((size_t)(U_N + 1) * 4);
    size_t o_rpi  = carve((size_t)(I_N + 1) * 4);
    size_t o_colu = carve((size_t)E_N * 4);
    size_t o_coli = carve((size_t)E_N * 4);
    size_t o_bsum = carve((size_t)SB_NT * 4);
    size_t o_curbu = carve((size_t)NB_U * 4);
    size_t o_curbi = carve((size_t)NB_I * 4);
    size_t o_bufA = carve(hbytes);
    size_t o_bufB = carve(hbytes);   // aliased as pair staging during CSR build
    size_t needed = off;

    if (ws_size >= needed) {
        float* dinv = (float*)(ws + o_dinv);
        int* cnt_u = (int*)(ws + o_cntu);
        int* cnt_i = (int*)(ws + o_cnti);
        int* rp_u  = (int*)(ws + o_rpu);
        int* rp_i  = (int*)(ws + o_rpi);
        int* col_u = (int*)(ws + o_colu);
        int* col_i = (int*)(ws + o_coli);
        int* bsum  = (int*)(ws + o_bsum);
        int* cur_bu = (int*)(ws + o_curbu);
        int* cur_bi = (int*)(ws + o_curbi);
        float* bufA = (float*)(ws + o_bufA);
        float* bufB = (float*)(ws + o_bufB);
        int2* staging = (int2*)bufB;

        hipMemsetAsync(cnt_u, 0, (size_t)U_N * 4, stream);
        hipMemsetAsync(cnt_i, 0, (size_t)I_N * 4, stream);

        hist_kernel<<<2048, 256, 0, stream>>>(eu, ei, cnt_u, cnt_i);
        dinv_kernel<<<(N_NODES + 255) / 256, 256, 0, stream>>>(cnt_u, cnt_i, dinv);

        {
            int nb_u = (U_N + SB_CHUNK - 1) / SB_CHUNK;
            scan_phase1<<<nb_u, SB_NT, 0, stream>>>(cnt_u, U_N, bsum);
            scan_phase2<<<1, SB_NT, 0, stream>>>(bsum, nb_u);
            scan_phase3<<<nb_u, SB_NT, 0, stream>>>(cnt_u, U_N, bsum, rp_u);
            int nb_i = (I_N + SB_CHUNK - 1) / SB_CHUNK;
            scan_phase1<<<nb_i, SB_NT, 0, stream>>>(cnt_i, I_N, bsum);
            scan_phase2<<<1, SB_NT, 0, stream>>>(bsum, nb_i);
            scan_phase3<<<nb_i, SB_NT, 0, stream>>>(cnt_i, I_N, bsum, rp_i);
        }

        init_cursor_kernel<<<1, 128, 0, stream>>>(rp_u, cur_bu, rp_i, cur_bi);

        const int sblocks = (E_N + CH - 1) / CH;
        stage_kernel<<<sblocks, 256, 0, stream>>>(eu, ei, cur_bu, staging);
        scatter_kernel<<<NB_U, 256, 0, stream>>>(staging, rp_u, U_N, col_u);
        stage_kernel<<<sblocks, 256, 0, stream>>>(ei, eu, cur_bi, staging);
        scatter_kernel<<<NB_I, 256, 0, stream>>>(staging, rp_i, I_N, col_i);

        const int gblocks = (N_NODES + 3) / 4;  // 4 waves/block, 1 node/wave
        gather_kernel<<<gblocks, 256, 0, stream>>>(u_emb, v_emb, rp_u, col_u, rp_i, col_i,
                                                   dinv, bufA);
        gather_kernel<<<gblocks, 256, 0, stream>>>(bufA, bufA + (size_t)U_N * D_N,
                                                   rp_u, col_u, rp_i, col_i, dinv, bufB);
        gather_kernel<<<gblocks, 256, 0, stream>>>(bufB, bufB + (size_t)U_N * D_N,
                                                   rp_u, col_u, rp_i, col_i, dinv, out);

        final4_kernel<<<2048, 256, 0, stream>>>(u_emb, v_emb, bufA, bufB, out);
    } else {
        // fallback: R1 atomic-scatter path
        float* dinv = (float*)ws;
        float* bufA = (float*)(ws + (1u << 20));
        float* bufB = bufA + (size_t)N_NODES * D_N;
        hipMemsetAsync(dinv, 0, N_NODES * sizeof(float), stream);
        hipMemsetAsync(bufA, 0, hbytes, stream);
        hipMemsetAsync(bufB, 0, hbytes, stream);
        deg_kernel<<<2048, 256, 0, stream>>>(eu, ei, dinv);
        rsqrt_kernel<<<(N_NODES + 255) / 256, 256, 0, stream>>>(dinv);
        init_out_kernel<<<2048, 256, 0, stream>>>(u_emb, v_emb, out);
        float* bufA_i = bufA + (size_t)U_N * D_N;
        float* bufB_i = bufB + (size_t)U_N * D_N;
        float* out_i  = out + (size_t)U_N * D_N;
        prop_kernel<<<8192, 256, 0, stream>>>(u_emb, v_emb, bufA, bufA_i, eu, ei, dinv);
        add_kernel<<<2048, 256, 0, stream>>>(out, bufA);
        prop_kernel<<<8192, 256, 0, stream>>>(bufA, bufA_i, bufB, bufB_i, eu, ei, dinv);
        add_kernel<<<2048, 256, 0, stream>>>(out, bufB);
        prop_kernel<<<8192, 256, 0, stream>>>(bufB, bufB_i, out, out_i, eu, ei, dinv);
        final_kernel<<<2048, 256, 0, stream>>>(out, v_emb);
    }
}

// Round 6
// 638.888 us; speedup vs baseline: 3.2937x; 1.1032x over previous
//
#include <hip/hip_runtime.h>

#define U_N 150000
#define I_N 100000
#define D_N 64
#define E_N 1500000
#define N_NODES (U_N + I_N)

// bucket geometry for the 2-pass CSR fill
#define BSHIFT 11
#define BW (1 << BSHIFT)
#define NB_U ((U_N + BW - 1) / BW)  // 74
#define NB_I ((I_N + BW - 1) / BW)  // 49
#define NBMAX 128
#define CH 8192

typedef unsigned int uint;
typedef unsigned short ushort_t;

// bf16 helpers
__device__ __forceinline__ float bf_lo(uint x) { return __uint_as_float(x << 16); }
__device__ __forceinline__ float bf_hi(uint x) { return __uint_as_float(x & 0xFFFF0000u); }
__device__ __forceinline__ ushort_t f2b(float f) {
    uint u = __float_as_uint(f);
    uint r = u + 0x7FFFu + ((u >> 16) & 1u);   // round-to-nearest-even
    return (ushort_t)(r >> 16);
}

// ============================================================
// degree histogram + dinv
// ============================================================
__global__ void hist_kernel(const int* __restrict__ eu, const int* __restrict__ ei,
                            int* __restrict__ cnt_u, int* __restrict__ cnt_i) {
    int t = blockIdx.x * blockDim.x + threadIdx.x;
    int stride = gridDim.x * blockDim.x;
    for (int e = t; e < E_N; e += stride) {
        atomicAdd(&cnt_u[eu[e]], 1);
        atomicAdd(&cnt_i[ei[e]], 1);
    }
}

__global__ void dinv_kernel(const int* __restrict__ cnt_u, const int* __restrict__ cnt_i,
                            float* __restrict__ dinv) {
    int t = blockIdx.x * blockDim.x + threadIdx.x;
    if (t >= N_NODES) return;
    int c = (t < U_N) ? cnt_u[t] : cnt_i[t - U_N];
    dinv[t] = rsqrtf((float)c + 1e-7f);
}

// ---------- hierarchical exclusive scan (rowptr) ----------
#define SB_NT 256
#define SB_EPT 8
#define SB_CHUNK (SB_NT * SB_EPT)

__global__ void scan_phase1(const int* __restrict__ cnt, int n, int* __restrict__ bsum) {
    __shared__ int lds[SB_NT];
    int b = blockIdx.x;
    int tid = threadIdx.x;
    int start = b * SB_CHUNK + tid * SB_EPT;
    int s = 0;
#pragma unroll
    for (int k = 0; k < SB_EPT; ++k) {
        int i = start + k;
        if (i < n) s += cnt[i];
    }
    lds[tid] = s;
    __syncthreads();
    for (int off = SB_NT / 2; off > 0; off >>= 1) {
        if (tid < off) lds[tid] += lds[tid + off];
        __syncthreads();
    }
    if (tid == 0) bsum[b] = lds[0];
}

__global__ void scan_phase2(int* __restrict__ bsum, int nb) {
    __shared__ int lds[SB_NT];
    int tid = threadIdx.x;
    int v = (tid < nb) ? bsum[tid] : 0;
    lds[tid] = v;
    __syncthreads();
    for (int off = 1; off < SB_NT; off <<= 1) {
        int t = (tid >= off) ? lds[tid - off] : 0;
        __syncthreads();
        lds[tid] += t;
        __syncthreads();
    }
    if (tid < nb) bsum[tid] = lds[tid] - v;
}

__global__ void scan_phase3(const int* __restrict__ cnt, int n,
                            const int* __restrict__ bsum,
                            int* __restrict__ rowptr) {
    __shared__ int lds[SB_NT];
    int b = blockIdx.x;
    int tid = threadIdx.x;
    int start = b * SB_CHUNK + tid * SB_EPT;
    int vals[SB_EPT];
    int s = 0;
#pragma unroll
    for (int k = 0; k < SB_EPT; ++k) {
        int i = start + k;
        vals[k] = (i < n) ? cnt[i] : 0;
        s += vals[k];
    }
    lds[tid] = s;
    __syncthreads();
    for (int off = 1; off < SB_NT; off <<= 1) {
        int t = (tid >= off) ? lds[tid - off] : 0;
        __syncthreads();
        lds[tid] += t;
        __syncthreads();
    }
    int running = bsum[b] + lds[tid] - s;
#pragma unroll
    for (int k = 0; k < SB_EPT; ++k) {
        int i = start + k;
        if (i < n) {
            rowptr[i] = running;
            running += vals[k];
            if (i == n - 1) rowptr[n] = running;
        }
    }
}

// ============================================================
// 2-pass bucketed CSR fill
// ============================================================
__global__ void init_cursor_kernel(const int* __restrict__ rp_u, int* __restrict__ cur_bu,
                                   const int* __restrict__ rp_i, int* __restrict__ cur_bi) {
    int t = threadIdx.x;
    if (t < NB_U) cur_bu[t] = rp_u[t << BSHIFT];
    if (t < NB_I) cur_bi[t] = rp_i[t << BSHIFT];
}

__global__ void stage_kernel(const int* __restrict__ keys, const int* __restrict__ pays,
                             int* __restrict__ cursors, int2* __restrict__ staging) {
    __shared__ int2 sp[CH];
    __shared__ unsigned short sb[CH];
    __shared__ int hist[NBMAX];
    __shared__ int scanb[NBMAX];
    __shared__ int cur[NBMAX];
    __shared__ int gbase[NBMAX];
    int tid = threadIdx.x;
    int e0 = blockIdx.x * CH;
    int cnt = E_N - e0;
    if (cnt <= 0) return;
    if (cnt > CH) cnt = CH;

    for (int b = tid; b < NBMAX; b += blockDim.x) hist[b] = 0;
    __syncthreads();
    for (int s = tid; s < cnt; s += blockDim.x)
        atomicAdd(&hist[keys[e0 + s] >> BSHIFT], 1);
    __syncthreads();
    if (tid < NBMAX) scanb[tid] = hist[tid];
    __syncthreads();
    for (int off = 1; off < NBMAX; off <<= 1) {
        int v = 0;
        if (tid < NBMAX && tid >= off) v = scanb[tid - off];
        __syncthreads();
        if (tid < NBMAX) scanb[tid] += v;
        __syncthreads();
    }
    if (tid < NBMAX) cur[tid] = scanb[tid] - hist[tid];
    __syncthreads();
    for (int s = tid; s < cnt; s += blockDim.x) {
        int k = keys[e0 + s];
        int p = pays[e0 + s];
        int b = k >> BSHIFT;
        int pos = atomicAdd(&cur[b], 1);
        sp[pos] = make_int2(k, p);
        sb[pos] = (unsigned short)b;
    }
    __syncthreads();
    if (tid < NBMAX) {
        int c = hist[tid];
        gbase[tid] = c ? atomicAdd(&cursors[tid], c) : 0;
    }
    __syncthreads();
    for (int s = tid; s < cnt; s += blockDim.x) {
        int b = sb[s];
        int ebase = scanb[b] - hist[b];
        staging[gbase[b] + (s - ebase)] = sp[s];
    }
}

__global__ void scatter_kernel(const int2* __restrict__ staging,
                               const int* __restrict__ rp, int nkeys,
                               int* __restrict__ col) {
    __shared__ int curlds[BW];
    int b = blockIdx.x;
    int lo = b << BSHIFT;
    int hi = lo + BW;
    if (hi > nkeys) hi = nkeys;
    for (int k = lo + threadIdx.x; k < hi; k += blockDim.x)
        curlds[k - lo] = rp[k];
    __syncthreads();
    int sbeg = rp[lo];
    int send = rp[hi];
    for (int s = sbeg + threadIdx.x; s < send; s += blockDim.x) {
        int2 pr = staging[s];
        int pos = atomicAdd(&curlds[pr.x - lo], 1);
        col[pos] = pr.y;
    }
}

// ============================================================
// cvt: ego (fp32 u_emb|v_emb) -> bf16 [N][64]
// ============================================================
__global__ void cvt16_kernel(const float* __restrict__ u_emb, const float* __restrict__ v_emb,
                             ushort_t* __restrict__ dst) {
    size_t t = (size_t)blockIdx.x * blockDim.x + threadIdx.x;
    size_t stride = (size_t)gridDim.x * blockDim.x;
    const size_t nu4 = (size_t)U_N * 16;
    const size_t n4 = (size_t)N_NODES * 16;
    const float4* us = (const float4*)u_emb;
    const float4* vs = (const float4*)v_emb;
    ushort4* o = (ushort4*)dst;
    for (size_t i = t; i < n4; i += stride) {
        float4 x = (i < nu4) ? us[i] : vs[i - nu4];
        ushort4 y;
        y.x = f2b(x.x); y.y = f2b(x.y); y.z = f2b(x.z); y.w = f2b(x.w);
        o[i] = y;
    }
}

// ============================================================
// CSR gather, bf16 src: one wave per destination node.
// lane = (group g = lane>>4, d4 = lane&15); per iter one uint2 (4 bf16 dims)
// per lane covers 4 neighbor rows (one per group).
// FUSE=0: write h as bf16.  FUSE=1: fused final epilogue -> fp32 out.
// ============================================================
template <int FUSE>
__global__ void gather16_kernel(const ushort_t* __restrict__ src16,   // [N][64] bf16
                                const int* __restrict__ rowptr_u, const int* __restrict__ col_u,
                                const int* __restrict__ rowptr_i, const int* __restrict__ col_i,
                                const float* __restrict__ dinv,
                                ushort_t* __restrict__ h16_out,       // FUSE=0
                                const float* __restrict__ u_emb,      // FUSE=1 ...
                                const float* __restrict__ v_emb,
                                const ushort_t* __restrict__ h1_16,
                                const ushort_t* __restrict__ h2_16,
                                float* __restrict__ out) {
    int wave = (int)((blockIdx.x * blockDim.x + threadIdx.x) >> 6);
    int lane = threadIdx.x & 63;
    if (wave >= N_NODES) return;
    const int* rp; const int* col; const uint2* s8; const float* dnbr; int row;
    if (wave < U_N) {
        rp = rowptr_u; col = col_u; dnbr = dinv + U_N; row = wave;
        s8 = (const uint2*)(src16 + (size_t)U_N * D_N);   // items block
    } else {
        rp = rowptr_i; col = col_i; dnbr = dinv; row = wave - U_N;
        s8 = (const uint2*)src16;                          // users block
    }
    int beg = rp[row], end = rp[row + 1];
    int g  = lane >> 4;
    int d4 = lane & 15;

    float4 acc = make_float4(0.f, 0.f, 0.f, 0.f);

    for (int base = beg; base < end; base += 64) {
        int li = base + lane;
        bool ok = (li < end);
        int cnb = ok ? col[li] : 0;
        float cw = ok ? dnbr[cnb] : 0.f;
        int n = end - base; if (n > 64) n = 64;
        int iters = (n + 3) >> 2;
#pragma unroll 4
        for (int k = 0; k < iters; ++k) {
            int kk = (k << 2) + g;
            int nb = __shfl(cnb, kk, 64);
            float w = __shfl(cw, kk, 64);
            uint2 q = s8[(size_t)nb * 16 + d4];
            acc.x = fmaf(w, bf_lo(q.x), acc.x);
            acc.y = fmaf(w, bf_hi(q.x), acc.y);
            acc.z = fmaf(w, bf_lo(q.y), acc.z);
            acc.w = fmaf(w, bf_hi(q.y), acc.w);
        }
    }

    acc.x += __shfl_xor(acc.x, 16, 64);
    acc.y += __shfl_xor(acc.y, 16, 64);
    acc.z += __shfl_xor(acc.z, 16, 64);
    acc.w += __shfl_xor(acc.w, 16, 64);
    acc.x += __shfl_xor(acc.x, 32, 64);
    acc.y += __shfl_xor(acc.y, 32, 64);
    acc.z += __shfl_xor(acc.z, 32, 64);
    acc.w += __shfl_xor(acc.w, 32, 64);

    if (g == 0) {
        float sc = dinv[wave];
        acc.x *= sc; acc.y *= sc; acc.z *= sc; acc.w *= sc;
        if (FUSE == 0) {
            ushort4 o;
            o.x = f2b(acc.x); o.y = f2b(acc.y); o.z = f2b(acc.z); o.w = f2b(acc.w);
            ((ushort4*)h16_out)[(size_t)wave * 16 + d4] = o;
        } else {
            // final: out = 0.25*(ego + h1 + h2 + h3) (+ ego again for items)
            float4 e;
            bool item = (wave >= U_N);
            if (item) e = ((const float4*)v_emb)[(size_t)(wave - U_N) * 16 + d4];
            else      e = ((const float4*)u_emb)[(size_t)wave * 16 + d4];
            uint2 q1 = ((const uint2*)h1_16)[(size_t)wave * 16 + d4];
            uint2 q2 = ((const uint2*)h2_16)[(size_t)wave * 16 + d4];
            float4 r;
            r.x = 0.25f * (e.x + bf_lo(q1.x) + bf_lo(q2.x) + acc.x);
            r.y = 0.25f * (e.y + bf_hi(q1.x) + bf_hi(q2.x) + acc.y);
            r.z = 0.25f * (e.z + bf_lo(q1.y) + bf_lo(q2.y) + acc.z);
            r.w = 0.25f * (e.w + bf_hi(q1.y) + bf_hi(q2.y) + acc.w);
            if (item) { r.x += e.x; r.y += e.y; r.z += e.z; r.w += e.w; }
            ((float4*)out)[(size_t)wave * 16 + d4] = r;
        }
    }
}

// ============================================================
// fallback (R1 atomic path) kernels, used only if ws too small
// ============================================================
__global__ void deg_kernel(const int* __restrict__ eu, const int* __restrict__ ei,
                           float* __restrict__ deg) {
    int t = blockIdx.x * blockDim.x + threadIdx.x;
    int stride = gridDim.x * blockDim.x;
    for (int e = t; e < E_N; e += stride) {
        atomicAdd(&deg[eu[e]], 1.0f);
        atomicAdd(&deg[U_N + ei[e]], 1.0f);
    }
}
__global__ void rsqrt_kernel(float* __restrict__ deg) {
    int t = blockIdx.x * blockDim.x + threadIdx.x;
    if (t < N_NODES) deg[t] = rsqrtf(deg[t] + 1e-7f);
}
__global__ void init_out_kernel(const float* __restrict__ u_emb,
                                const float* __restrict__ v_emb,
                                float* __restrict__ out) {
    size_t t = (size_t)blockIdx.x * blockDim.x + threadIdx.x;
    size_t stride = (size_t)gridDim.x * blockDim.x;
    const size_t nu4 = (size_t)U_N * D_N / 4;
    const size_t ni4 = (size_t)I_N * D_N / 4;
    const float4* us = (const float4*)u_emb;
    const float4* vs = (const float4*)v_emb;
    float4* o = (float4*)out;
    for (size_t i = t; i < nu4; i += stride) o[i] = us[i];
    for (size_t i = t; i < ni4; i += stride) o[nu4 + i] = vs[i];
}
__global__ void add_kernel(float* __restrict__ acc, const float* __restrict__ h) {
    size_t t = (size_t)blockIdx.x * blockDim.x + threadIdx.x;
    size_t stride = (size_t)gridDim.x * blockDim.x;
    const size_t n4 = (size_t)N_NODES * D_N / 4;
    float4* a = (float4*)acc;
    const float4* b = (const float4*)h;
    for (size_t i = t; i < n4; i += stride) {
        float4 x = a[i]; float4 y = b[i];
        x.x += y.x; x.y += y.y; x.z += y.z; x.w += y.w;
        a[i] = x;
    }
}
__global__ void prop_kernel(const float* __restrict__ srcU, const float* __restrict__ srcI,
                            float* __restrict__ dstU, float* __restrict__ dstI,
                            const int* __restrict__ eu, const int* __restrict__ ei,
                            const float* __restrict__ dinv) {
    int wave = (blockIdx.x * blockDim.x + threadIdx.x) >> 6;
    int lane = threadIdx.x & 63;
    int nwaves = (gridDim.x * blockDim.x) >> 6;
    for (int e = wave; e < E_N; e += nwaves) {
        int u = eu[e];
        int i = ei[e];
        float w = dinv[u] * dinv[U_N + i];
        float hu = srcU[(size_t)u * D_N + lane];
        float hi = srcI[(size_t)i * D_N + lane];
        atomicAdd(&dstU[(size_t)u * D_N + lane], w * hi);
        atomicAdd(&dstI[(size_t)i * D_N + lane], w * hu);
    }
}
__global__ void final_kernel(float* __restrict__ out, const float* __restrict__ v_emb) {
    size_t t = (size_t)blockIdx.x * blockDim.x + threadIdx.x;
    size_t stride = (size_t)gridDim.x * blockDim.x;
    const size_t nu4 = (size_t)U_N * D_N / 4;
    const size_t n4 = (size_t)N_NODES * D_N / 4;
    float4* o = (float4*)out;
    const float4* v = (const float4*)v_emb;
    for (size_t i = t; i < n4; i += stride) {
        float4 x = o[i];
        x.x *= 0.25f; x.y *= 0.25f; x.z *= 0.25f; x.w *= 0.25f;
        if (i >= nu4) {
            float4 vv = v[i - nu4];
            x.x += vv.x; x.y += vv.y; x.z += vv.z; x.w += vv.w;
        }
        o[i] = x;
    }
}

// ============================================================
extern "C" void kernel_launch(void* const* d_in, const int* in_sizes, int n_in,
                              void* d_out, int out_size, void* d_ws, size_t ws_size,
                              hipStream_t stream) {
    const float* u_emb = (const float*)d_in[0];
    const float* v_emb = (const float*)d_in[1];
    const int* eu = (const int*)d_in[2];
    const int* ei = (const int*)d_in[3];
    float* out = (float*)d_out;

    const size_t h16bytes = (size_t)N_NODES * D_N * sizeof(ushort_t);  // 32 MB

    size_t off = 0;
    auto carve = [&](size_t bytes) {
        size_t p = off;
        off = (off + bytes + 255) & ~(size_t)255;
        return p;
    };
    char* ws = (char*)d_ws;
    size_t o_dinv = carve((size_t)N_NODES * 4);
    size_t o_cntu = carve((size_t)U_N * 4);
    size_t o_cnti = carve((size_t)I_N * 4);
    size_t o_rpu  = carve((size_t)(U_N + 1) * 4);
    size_t o_rpi  = carve((size_t)(I_N + 1) * 4);
    size_t o_colu = carve((size_t)E_N * 4);
    size_t o_coli = carve((size_t)E_N * 4);
    size_t o_bsum = carve((size_t)SB_NT * 4);
    size_t o_curbu = carve((size_t)NB_U * 4);
    size_t o_curbi = carve((size_t)NB_I * 4);
    size_t o_ego16 = carve(h16bytes);
    size_t o_h1    = carve(h16bytes);
    size_t o_h2    = carve(h16bytes);   // aliased as int2 staging during CSR build (12MB < 32MB)
    size_t needed = off;

    if (ws_size >= needed) {
        float* dinv = (float*)(ws + o_dinv);
        int* cnt_u = (int*)(ws + o_cntu);
        int* cnt_i = (int*)(ws + o_cnti);
        int* rp_u  = (int*)(ws + o_rpu);
        int* rp_i  = (int*)(ws + o_rpi);
        int* col_u = (int*)(ws + o_colu);
        int* col_i = (int*)(ws + o_coli);
        int* bsum  = (int*)(ws + o_bsum);
        int* cur_bu = (int*)(ws + o_curbu);
        int* cur_bi = (int*)(ws + o_curbi);
        ushort_t* ego16 = (ushort_t*)(ws + o_ego16);
        ushort_t* h1_16 = (ushort_t*)(ws + o_h1);
        ushort_t* h2_16 = (ushort_t*)(ws + o_h2);
        int2* staging = (int2*)(ws + o_h2);

        hipMemsetAsync(cnt_u, 0, (size_t)U_N * 4, stream);
        hipMemsetAsync(cnt_i, 0, (size_t)I_N * 4, stream);

        hist_kernel<<<2048, 256, 0, stream>>>(eu, ei, cnt_u, cnt_i);
        dinv_kernel<<<(N_NODES + 255) / 256, 256, 0, stream>>>(cnt_u, cnt_i, dinv);

        {
            int nb_u = (U_N + SB_CHUNK - 1) / SB_CHUNK;
            scan_phase1<<<nb_u, SB_NT, 0, stream>>>(cnt_u, U_N, bsum);
            scan_phase2<<<1, SB_NT, 0, stream>>>(bsum, nb_u);
            scan_phase3<<<nb_u, SB_NT, 0, stream>>>(cnt_u, U_N, bsum, rp_u);
            int nb_i = (I_N + SB_CHUNK - 1) / SB_CHUNK;
            scan_phase1<<<nb_i, SB_NT, 0, stream>>>(cnt_i, I_N, bsum);
            scan_phase2<<<1, SB_NT, 0, stream>>>(bsum, nb_i);
            scan_phase3<<<nb_i, SB_NT, 0, stream>>>(cnt_i, I_N, bsum, rp_i);
        }

        init_cursor_kernel<<<1, 128, 0, stream>>>(rp_u, cur_bu, rp_i, cur_bi);

        const int sblocks = (E_N + CH - 1) / CH;
        stage_kernel<<<sblocks, 256, 0, stream>>>(eu, ei, cur_bu, staging);
        scatter_kernel<<<NB_U, 256, 0, stream>>>(staging, rp_u, U_N, col_u);
        stage_kernel<<<sblocks, 256, 0, stream>>>(ei, eu, cur_bi, staging);
        scatter_kernel<<<NB_I, 256, 0, stream>>>(staging, rp_i, I_N, col_i);

        // ego -> bf16 (runs while CSR build finishes; independent)
        cvt16_kernel<<<2048, 256, 0, stream>>>(u_emb, v_emb, ego16);

        const int gblocks = (N_NODES + 3) / 4;  // 4 waves/block, 1 node/wave
        // layer 1: src = ego16 -> h1 bf16
        gather16_kernel<0><<<gblocks, 256, 0, stream>>>(ego16, rp_u, col_u, rp_i, col_i,
                                                        dinv, h1_16,
                                                        nullptr, nullptr, nullptr, nullptr, nullptr);
        // layer 2: src = h1 -> h2 bf16 (h2 region: staging no longer needed)
        gather16_kernel<0><<<gblocks, 256, 0, stream>>>(h1_16, rp_u, col_u, rp_i, col_i,
                                                        dinv, h2_16,
                                                        nullptr, nullptr, nullptr, nullptr, nullptr);
        // layer 3: src = h2 -> fused final epilogue -> out (fp32)
        gather16_kernel<1><<<gblocks, 256, 0, stream>>>(h2_16, rp_u, col_u, rp_i, col_i,
                                                        dinv, nullptr,
                                                        u_emb, v_emb, h1_16, h2_16, out);
    } else {
        // fallback: R1 atomic-scatter path
        const size_t hbytes = (size_t)N_NODES * D_N * sizeof(float);
        float* dinv = (float*)ws;
        float* bufA = (float*)(ws + (1u << 20));
        float* bufB = bufA + (size_t)N_NODES * D_N;
        hipMemsetAsync(dinv, 0, N_NODES * sizeof(float), stream);
        hipMemsetAsync(bufA, 0, hbytes, stream);
        hipMemsetAsync(bufB, 0, hbytes, stream);
        deg_kernel<<<2048, 256, 0, stream>>>(eu, ei, dinv);
        rsqrt_kernel<<<(N_NODES + 255) / 256, 256, 0, stream>>>(dinv);
        init_out_kernel<<<2048, 256, 0, stream>>>(u_emb, v_emb, out);
        float* bufA_i = bufA + (size_t)U_N * D_N;
        float* bufB_i = bufB + (size_t)U_N * D_N;
        float* out_i  = out + (size_t)U_N * D_N;
        prop_kernel<<<8192, 256, 0, stream>>>(u_emb, v_emb, bufA, bufA_i, eu, ei, dinv);
        add_kernel<<<2048, 256, 0, stream>>>(out, bufA);
        prop_kernel<<<8192, 256, 0, stream>>>(bufA, bufA_i, bufB, bufB_i, eu, ei, dinv);
        add_kernel<<<2048, 256, 0, stream>>>(out, bufB);
        prop_kernel<<<8192, 256, 0, stream>>>(bufB, bufB_i, out, out_i, eu, ei, dinv);
        final_kernel<<<2048, 256, 0, stream>>>(out, v_emb);
    }
}

// Round 7
// 539.049 us; speedup vs baseline: 3.9037x; 1.1852x over previous
//
#include <hip/hip_runtime.h>

#define U_N 150000
#define I_N 100000
#define D_N 64
#define E_N 1500000
#define N_NODES (U_N + I_N)

// bucket geometry for the 2-pass CSR fill
#define BSHIFT 11
#define BW (1 << BSHIFT)
#define NB_U ((U_N + BW - 1) / BW)  // 74
#define NB_I ((I_N + BW - 1) / BW)  // 49
#define NBMAX 128
#define CH 8192

typedef unsigned int uint;
typedef unsigned short ushort_t;

// bf16 helpers
__device__ __forceinline__ float bf_lo(uint x) { return __uint_as_float(x << 16); }
__device__ __forceinline__ float bf_hi(uint x) { return __uint_as_float(x & 0xFFFF0000u); }
__device__ __forceinline__ ushort_t f2b(float f) {
    uint u = __float_as_uint(f);
    uint r = u + 0x7FFFu + ((u >> 16) & 1u);   // round-to-nearest-even
    return (ushort_t)(r >> 16);
}

// ============================================================
// degree histogram + dinv
// ============================================================
__global__ void hist_kernel(const int* __restrict__ eu, const int* __restrict__ ei,
                            int* __restrict__ cnt_u, int* __restrict__ cnt_i) {
    int t = blockIdx.x * blockDim.x + threadIdx.x;
    int stride = gridDim.x * blockDim.x;
    for (int e = t; e < E_N; e += stride) {
        atomicAdd(&cnt_u[eu[e]], 1);
        atomicAdd(&cnt_i[ei[e]], 1);
    }
}

__global__ void dinv_kernel(const int* __restrict__ cnt_u, const int* __restrict__ cnt_i,
                            float* __restrict__ dinv) {
    int t = blockIdx.x * blockDim.x + threadIdx.x;
    if (t >= N_NODES) return;
    int c = (t < U_N) ? cnt_u[t] : cnt_i[t - U_N];
    dinv[t] = rsqrtf((float)c + 1e-7f);
}

// ---------- hierarchical exclusive scan (rowptr) ----------
#define SB_NT 256
#define SB_EPT 8
#define SB_CHUNK (SB_NT * SB_EPT)

__global__ void scan_phase1(const int* __restrict__ cnt, int n, int* __restrict__ bsum) {
    __shared__ int lds[SB_NT];
    int b = blockIdx.x;
    int tid = threadIdx.x;
    int start = b * SB_CHUNK + tid * SB_EPT;
    int s = 0;
#pragma unroll
    for (int k = 0; k < SB_EPT; ++k) {
        int i = start + k;
        if (i < n) s += cnt[i];
    }
    lds[tid] = s;
    __syncthreads();
    for (int off = SB_NT / 2; off > 0; off >>= 1) {
        if (tid < off) lds[tid] += lds[tid + off];
        __syncthreads();
    }
    if (tid == 0) bsum[b] = lds[0];
}

__global__ void scan_phase2(int* __restrict__ bsum, int nb) {
    __shared__ int lds[SB_NT];
    int tid = threadIdx.x;
    int v = (tid < nb) ? bsum[tid] : 0;
    lds[tid] = v;
    __syncthreads();
    for (int off = 1; off < SB_NT; off <<= 1) {
        int t = (tid >= off) ? lds[tid - off] : 0;
        __syncthreads();
        lds[tid] += t;
        __syncthreads();
    }
    if (tid < nb) bsum[tid] = lds[tid] - v;
}

__global__ void scan_phase3(const int* __restrict__ cnt, int n,
                            const int* __restrict__ bsum,
                            int* __restrict__ rowptr) {
    __shared__ int lds[SB_NT];
    int b = blockIdx.x;
    int tid = threadIdx.x;
    int start = b * SB_CHUNK + tid * SB_EPT;
    int vals[SB_EPT];
    int s = 0;
#pragma unroll
    for (int k = 0; k < SB_EPT; ++k) {
        int i = start + k;
        vals[k] = (i < n) ? cnt[i] : 0;
        s += vals[k];
    }
    lds[tid] = s;
    __syncthreads();
    for (int off = 1; off < SB_NT; off <<= 1) {
        int t = (tid >= off) ? lds[tid - off] : 0;
        __syncthreads();
        lds[tid] += t;
        __syncthreads();
    }
    int running = bsum[b] + lds[tid] - s;
#pragma unroll
    for (int k = 0; k < SB_EPT; ++k) {
        int i = start + k;
        if (i < n) {
            rowptr[i] = running;
            running += vals[k];
            if (i == n - 1) rowptr[n] = running;
        }
    }
}

// ============================================================
// 2-pass bucketed CSR fill (colw = {neighbor, dinv[neighbor]})
// ============================================================
__global__ void init_cursor_kernel(const int* __restrict__ rp_u, int* __restrict__ cur_bu,
                                   const int* __restrict__ rp_i, int* __restrict__ cur_bi) {
    int t = threadIdx.x;
    if (t < NB_U) cur_bu[t] = rp_u[t << BSHIFT];
    if (t < NB_I) cur_bi[t] = rp_i[t << BSHIFT];
}

__global__ void stage_kernel(const int* __restrict__ keys, const int* __restrict__ pays,
                             int* __restrict__ cursors, int2* __restrict__ staging) {
    __shared__ int2 sp[CH];
    __shared__ unsigned short sb[CH];
    __shared__ int hist[NBMAX];
    __shared__ int scanb[NBMAX];
    __shared__ int cur[NBMAX];
    __shared__ int gbase[NBMAX];
    int tid = threadIdx.x;
    int e0 = blockIdx.x * CH;
    int cnt = E_N - e0;
    if (cnt <= 0) return;
    if (cnt > CH) cnt = CH;

    for (int b = tid; b < NBMAX; b += blockDim.x) hist[b] = 0;
    __syncthreads();
    for (int s = tid; s < cnt; s += blockDim.x)
        atomicAdd(&hist[keys[e0 + s] >> BSHIFT], 1);
    __syncthreads();
    if (tid < NBMAX) scanb[tid] = hist[tid];
    __syncthreads();
    for (int off = 1; off < NBMAX; off <<= 1) {
        int v = 0;
        if (tid < NBMAX && tid >= off) v = scanb[tid - off];
        __syncthreads();
        if (tid < NBMAX) scanb[tid] += v;
        __syncthreads();
    }
    if (tid < NBMAX) cur[tid] = scanb[tid] - hist[tid];
    __syncthreads();
    for (int s = tid; s < cnt; s += blockDim.x) {
        int k = keys[e0 + s];
        int p = pays[e0 + s];
        int b = k >> BSHIFT;
        int pos = atomicAdd(&cur[b], 1);
        sp[pos] = make_int2(k, p);
        sb[pos] = (unsigned short)b;
    }
    __syncthreads();
    if (tid < NBMAX) {
        int c = hist[tid];
        gbase[tid] = c ? atomicAdd(&cursors[tid], c) : 0;
    }
    __syncthreads();
    for (int s = tid; s < cnt; s += blockDim.x) {
        int b = sb[s];
        int ebase = scanb[b] - hist[b];
        staging[gbase[b] + (s - ebase)] = sp[s];
    }
}

// writes colw[pos] = {neighbor, dinv_nbr[neighbor]}
__global__ void scatter_kernel(const int2* __restrict__ staging,
                               const int* __restrict__ rp, int nkeys,
                               const float* __restrict__ dinv_nbr,
                               int2* __restrict__ colw) {
    __shared__ int curlds[BW];
    int b = blockIdx.x;
    int lo = b << BSHIFT;
    int hi = lo + BW;
    if (hi > nkeys) hi = nkeys;
    for (int k = lo + threadIdx.x; k < hi; k += blockDim.x)
        curlds[k - lo] = rp[k];
    __syncthreads();
    int sbeg = rp[lo];
    int send = rp[hi];
    for (int s = sbeg + threadIdx.x; s < send; s += blockDim.x) {
        int2 pr = staging[s];
        int pos = atomicAdd(&curlds[pr.x - lo], 1);
        colw[pos] = make_int2(pr.y, __float_as_int(dinv_nbr[pr.y]));
    }
}

// ============================================================
// cvt: ego (fp32 u_emb|v_emb) -> bf16 [N][64]
// ============================================================
__global__ void cvt16_kernel(const float* __restrict__ u_emb, const float* __restrict__ v_emb,
                             ushort_t* __restrict__ dst) {
    size_t t = (size_t)blockIdx.x * blockDim.x + threadIdx.x;
    size_t stride = (size_t)gridDim.x * blockDim.x;
    const size_t nu4 = (size_t)U_N * 16;
    const size_t n4 = (size_t)N_NODES * 16;
    const float4* us = (const float4*)u_emb;
    const float4* vs = (const float4*)v_emb;
    ushort4* o = (ushort4*)dst;
    for (size_t i = t; i < n4; i += stride) {
        float4 x = (i < nu4) ? us[i] : vs[i - nu4];
        ushort4 y;
        y.x = f2b(x.x); y.y = f2b(x.y); y.z = f2b(x.z); y.w = f2b(x.w);
        o[i] = y;
    }
}

// ============================================================
// CSR gather v3: one 16-lane group per node (4 nodes/wave).
// lane d4 = threadIdx.x & 15 owns dims [4*d4, 4*d4+4) via one uint2/row.
// colw supplies (nb, w) -- no dependent dinv gather, no shfl anywhere.
// FUSE=0: write h bf16.  FUSE=1: fused final epilogue -> fp32 out.
// ============================================================
template <int FUSE>
__global__ void gather16_kernel(const ushort_t* __restrict__ src16,
                                const int* __restrict__ rowptr_u, const int2* __restrict__ colw_u,
                                const int* __restrict__ rowptr_i, const int2* __restrict__ colw_i,
                                const float* __restrict__ dinv,
                                ushort_t* __restrict__ h16_out,
                                const float* __restrict__ u_emb,
                                const float* __restrict__ v_emb,
                                const ushort_t* __restrict__ h1_16,
                                const ushort_t* __restrict__ h2_16,
                                float* __restrict__ out) {
    int grp = (int)((blockIdx.x * blockDim.x + threadIdx.x) >> 4);
    int d4 = threadIdx.x & 15;
    if (grp >= N_NODES) return;
    const int* rp; const int2* cw; const uint2* s8; int row;
    if (grp < U_N) {
        rp = rowptr_u; cw = colw_u; row = grp;
        s8 = (const uint2*)(src16 + (size_t)U_N * D_N);   // items block
    } else {
        rp = rowptr_i; cw = colw_i; row = grp - U_N;
        s8 = (const uint2*)src16;                          // users block
    }
    int beg = rp[row], end = rp[row + 1];

    float4 acc = make_float4(0.f, 0.f, 0.f, 0.f);
    int j = beg;
    for (; j + 4 <= end; j += 4) {
        int2 c0 = cw[j], c1 = cw[j + 1], c2 = cw[j + 2], c3 = cw[j + 3];
        uint2 q0 = s8[(size_t)c0.x * 16 + d4];
        uint2 q1 = s8[(size_t)c1.x * 16 + d4];
        uint2 q2 = s8[(size_t)c2.x * 16 + d4];
        uint2 q3 = s8[(size_t)c3.x * 16 + d4];
        float w0 = __int_as_float(c0.y), w1 = __int_as_float(c1.y);
        float w2 = __int_as_float(c2.y), w3 = __int_as_float(c3.y);
        acc.x = fmaf(w0, bf_lo(q0.x), acc.x);
        acc.y = fmaf(w0, bf_hi(q0.x), acc.y);
        acc.z = fmaf(w0, bf_lo(q0.y), acc.z);
        acc.w = fmaf(w0, bf_hi(q0.y), acc.w);
        acc.x = fmaf(w1, bf_lo(q1.x), acc.x);
        acc.y = fmaf(w1, bf_hi(q1.x), acc.y);
        acc.z = fmaf(w1, bf_lo(q1.y), acc.z);
        acc.w = fmaf(w1, bf_hi(q1.y), acc.w);
        acc.x = fmaf(w2, bf_lo(q2.x), acc.x);
        acc.y = fmaf(w2, bf_hi(q2.x), acc.y);
        acc.z = fmaf(w2, bf_lo(q2.y), acc.z);
        acc.w = fmaf(w2, bf_hi(q2.y), acc.w);
        acc.x = fmaf(w3, bf_lo(q3.x), acc.x);
        acc.y = fmaf(w3, bf_hi(q3.x), acc.y);
        acc.z = fmaf(w3, bf_lo(q3.y), acc.z);
        acc.w = fmaf(w3, bf_hi(q3.y), acc.w);
    }
    for (; j < end; ++j) {
        int2 c = cw[j];
        uint2 q = s8[(size_t)c.x * 16 + d4];
        float w = __int_as_float(c.y);
        acc.x = fmaf(w, bf_lo(q.x), acc.x);
        acc.y = fmaf(w, bf_hi(q.x), acc.y);
        acc.z = fmaf(w, bf_lo(q.y), acc.z);
        acc.w = fmaf(w, bf_hi(q.y), acc.w);
    }

    float sc = dinv[grp];
    acc.x *= sc; acc.y *= sc; acc.z *= sc; acc.w *= sc;

    if (FUSE == 0) {
        ushort4 o;
        o.x = f2b(acc.x); o.y = f2b(acc.y); o.z = f2b(acc.z); o.w = f2b(acc.w);
        ((ushort4*)h16_out)[(size_t)grp * 16 + d4] = o;
    } else {
        float4 e;
        bool item = (grp >= U_N);
        if (item) e = ((const float4*)v_emb)[(size_t)(grp - U_N) * 16 + d4];
        else      e = ((const float4*)u_emb)[(size_t)grp * 16 + d4];
        uint2 p1 = ((const uint2*)h1_16)[(size_t)grp * 16 + d4];
        uint2 p2 = ((const uint2*)h2_16)[(size_t)grp * 16 + d4];
        float4 r;
        r.x = 0.25f * (e.x + bf_lo(p1.x) + bf_lo(p2.x) + acc.x);
        r.y = 0.25f * (e.y + bf_hi(p1.x) + bf_hi(p2.x) + acc.y);
        r.z = 0.25f * (e.z + bf_lo(p1.y) + bf_lo(p2.y) + acc.z);
        r.w = 0.25f * (e.w + bf_hi(p1.y) + bf_hi(p2.y) + acc.w);
        if (item) { r.x += e.x; r.y += e.y; r.z += e.z; r.w += e.w; }
        ((float4*)out)[(size_t)grp * 16 + d4] = r;
    }
}

// ============================================================
// fallback (R1 atomic path) kernels, used only if ws too small
// ============================================================
__global__ void deg_kernel(const int* __restrict__ eu, const int* __restrict__ ei,
                           float* __restrict__ deg) {
    int t = blockIdx.x * blockDim.x + threadIdx.x;
    int stride = gridDim.x * blockDim.x;
    for (int e = t; e < E_N; e += stride) {
        atomicAdd(&deg[eu[e]], 1.0f);
        atomicAdd(&deg[U_N + ei[e]], 1.0f);
    }
}
__global__ void rsqrt_kernel(float* __restrict__ deg) {
    int t = blockIdx.x * blockDim.x + threadIdx.x;
    if (t < N_NODES) deg[t] = rsqrtf(deg[t] + 1e-7f);
}
__global__ void init_out_kernel(const float* __restrict__ u_emb,
                                const float* __restrict__ v_emb,
                                float* __restrict__ out) {
    size_t t = (size_t)blockIdx.x * blockDim.x + threadIdx.x;
    size_t stride = (size_t)gridDim.x * blockDim.x;
    const size_t nu4 = (size_t)U_N * D_N / 4;
    const size_t ni4 = (size_t)I_N * D_N / 4;
    const float4* us = (const float4*)u_emb;
    const float4* vs = (const float4*)v_emb;
    float4* o = (float4*)out;
    for (size_t i = t; i < nu4; i += stride) o[i] = us[i];
    for (size_t i = t; i < ni4; i += stride) o[nu4 + i] = vs[i];
}
__global__ void add_kernel(float* __restrict__ acc, const float* __restrict__ h) {
    size_t t = (size_t)blockIdx.x * blockDim.x + threadIdx.x;
    size_t stride = (size_t)gridDim.x * blockDim.x;
    const size_t n4 = (size_t)N_NODES * D_N / 4;
    float4* a = (float4*)acc;
    const float4* b = (const float4*)h;
    for (size_t i = t; i < n4; i += stride) {
        float4 x = a[i]; float4 y = b[i];
        x.x += y.x; x.y += y.y; x.z += y.z; x.w += y.w;
        a[i] = x;
    }
}
__global__ void prop_kernel(const float* __restrict__ srcU, const float* __restrict__ srcI,
                            float* __restrict__ dstU, float* __restrict__ dstI,
                            const int* __restrict__ eu, const int* __restrict__ ei,
                            const float* __restrict__ dinv) {
    int wave = (blockIdx.x * blockDim.x + threadIdx.x) >> 6;
    int lane = threadIdx.x & 63;
    int nwaves = (gridDim.x * blockDim.x) >> 6;
    for (int e = wave; e < E_N; e += nwaves) {
        int u = eu[e];
        int i = ei[e];
        float w = dinv[u] * dinv[U_N + i];
        float hu = srcU[(size_t)u * D_N + lane];
        float hi = srcI[(size_t)i * D_N + lane];
        atomicAdd(&dstU[(size_t)u * D_N + lane], w * hi);
        atomicAdd(&dstI[(size_t)i * D_N + lane], w * hu);
    }
}
__global__ void final_kernel(float* __restrict__ out, const float* __restrict__ v_emb) {
    size_t t = (size_t)blockIdx.x * blockDim.x + threadIdx.x;
    size_t stride = (size_t)gridDim.x * blockDim.x;
    const size_t nu4 = (size_t)U_N * D_N / 4;
    const size_t n4 = (size_t)N_NODES * D_N / 4;
    float4* o = (float4*)out;
    const float4* v = (const float4*)v_emb;
    for (size_t i = t; i < n4; i += stride) {
        float4 x = o[i];
        x.x *= 0.25f; x.y *= 0.25f; x.z *= 0.25f; x.w *= 0.25f;
        if (i >= nu4) {
            float4 vv = v[i - nu4];
            x.x += vv.x; x.y += vv.y; x.z += vv.z; x.w += vv.w;
        }
        o[i] = x;
    }
}

// ============================================================
extern "C" void kernel_launch(void* const* d_in, const int* in_sizes, int n_in,
                              void* d_out, int out_size, void* d_ws, size_t ws_size,
                              hipStream_t stream) {
    const float* u_emb = (const float*)d_in[0];
    const float* v_emb = (const float*)d_in[1];
    const int* eu = (const int*)d_in[2];
    const int* ei = (const int*)d_in[3];
    float* out = (float*)d_out;

    const size_t h16bytes = (size_t)N_NODES * D_N * sizeof(ushort_t);  // 32 MB

    size_t off = 0;
    auto carve = [&](size_t bytes) {
        size_t p = off;
        off = (off + bytes + 255) & ~(size_t)255;
        return p;
    };
    char* ws = (char*)d_ws;
    size_t o_dinv = carve((size_t)N_NODES * 4);
    size_t o_cntu = carve((size_t)U_N * 4);
    size_t o_cnti = carve((size_t)I_N * 4);
    size_t o_rpu  = carve((size_t)(U_N + 1) * 4);
    size_t o_rpi  = carve((size_t)(I_N + 1) * 4);
    size_t o_colu = carve((size_t)E_N * 8);   // int2 {nb, w}
    size_t o_coli = carve((size_t)E_N * 8);
    size_t o_bsum = carve((size_t)SB_NT * 4);
    size_t o_curbu = carve((size_t)NB_U * 4);
    size_t o_curbi = carve((size_t)NB_I * 4);
    size_t o_ego16 = carve(h16bytes);
    size_t o_h1    = carve(h16bytes);
    size_t o_h2    = carve(h16bytes);   // aliased as int2 staging during CSR build (12MB < 32MB)
    size_t needed = off;

    if (ws_size >= needed) {
        float* dinv = (float*)(ws + o_dinv);
        int* cnt_u = (int*)(ws + o_cntu);
        int* cnt_i = (int*)(ws + o_cnti);
        int* rp_u  = (int*)(ws + o_rpu);
        int* rp_i  = (int*)(ws + o_rpi);
        int2* colw_u = (int2*)(ws + o_colu);
        int2* colw_i = (int2*)(ws + o_coli);
        int* bsum  = (int*)(ws + o_bsum);
        int* cur_bu = (int*)(ws + o_curbu);
        int* cur_bi = (int*)(ws + o_curbi);
        ushort_t* ego16 = (ushort_t*)(ws + o_ego16);
        ushort_t* h1_16 = (ushort_t*)(ws + o_h1);
        ushort_t* h2_16 = (ushort_t*)(ws + o_h2);
        int2* staging = (int2*)(ws + o_h2);

        hipMemsetAsync(cnt_u, 0, (size_t)U_N * 4, stream);
        hipMemsetAsync(cnt_i, 0, (size_t)I_N * 4, stream);

        hist_kernel<<<2048, 256, 0, stream>>>(eu, ei, cnt_u, cnt_i);
        dinv_kernel<<<(N_NODES + 255) / 256, 256, 0, stream>>>(cnt_u, cnt_i, dinv);

        {
            int nb_u = (U_N + SB_CHUNK - 1) / SB_CHUNK;
            scan_phase1<<<nb_u, SB_NT, 0, stream>>>(cnt_u, U_N, bsum);
            scan_phase2<<<1, SB_NT, 0, stream>>>(bsum, nb_u);
            scan_phase3<<<nb_u, SB_NT, 0, stream>>>(cnt_u, U_N, bsum, rp_u);
            int nb_i = (I_N + SB_CHUNK - 1) / SB_CHUNK;
            scan_phase1<<<nb_i, SB_NT, 0, stream>>>(cnt_i, I_N, bsum);
            scan_phase2<<<1, SB_NT, 0, stream>>>(bsum, nb_i);
            scan_phase3<<<nb_i, SB_NT, 0, stream>>>(cnt_i, I_N, bsum, rp_i);
        }

        init_cursor_kernel<<<1, 128, 0, stream>>>(rp_u, cur_bu, rp_i, cur_bi);

        const int sblocks = (E_N + CH - 1) / CH;
        // user-direction: neighbors are items -> w = dinv[U_N + item]
        stage_kernel<<<sblocks, 256, 0, stream>>>(eu, ei, cur_bu, staging);
        scatter_kernel<<<NB_U, 256, 0, stream>>>(staging, rp_u, U_N, dinv + U_N, colw_u);
        // item-direction: neighbors are users -> w = dinv[user]
        stage_kernel<<<sblocks, 256, 0, stream>>>(ei, eu, cur_bi, staging);
        scatter_kernel<<<NB_I, 256, 0, stream>>>(staging, rp_i, I_N, dinv, colw_i);

        // ego -> bf16
        cvt16_kernel<<<2048, 256, 0, stream>>>(u_emb, v_emb, ego16);

        const int gblocks = ((size_t)N_NODES * 16 + 255) / 256;
        // layer 1: src = ego16 -> h1 bf16
        gather16_kernel<0><<<gblocks, 256, 0, stream>>>(ego16, rp_u, colw_u, rp_i, colw_i,
                                                        dinv, h1_16,
                                                        nullptr, nullptr, nullptr, nullptr, nullptr);
        // layer 2: src = h1 -> h2 bf16 (staging no longer needed)
        gather16_kernel<0><<<gblocks, 256, 0, stream>>>(h1_16, rp_u, colw_u, rp_i, colw_i,
                                                        dinv, h2_16,
                                                        nullptr, nullptr, nullptr, nullptr, nullptr);
        // layer 3: src = h2 -> fused final epilogue -> out (fp32)
        gather16_kernel<1><<<gblocks, 256, 0, stream>>>(h2_16, rp_u, colw_u, rp_i, colw_i,
                                                        dinv, nullptr,
                                                        u_emb, v_emb, h1_16, h2_16, out);
    } else {
        // fallback: R1 atomic-scatter path
        const size_t hbytes = (size_t)N_NODES * D_N * sizeof(float);
        float* dinv = (float*)ws;
        float* bufA = (float*)(ws + (1u << 20));
        float* bufB = bufA + (size_t)N_NODES * D_N;
        hipMemsetAsync(dinv, 0, N_NODES * sizeof(float), stream);
        hipMemsetAsync(bufA, 0, hbytes, stream);
        hipMemsetAsync(bufB, 0, hbytes, stream);
        deg_kernel<<<2048, 256, 0, stream>>>(eu, ei, dinv);
        rsqrt_kernel<<<(N_NODES + 255) / 256, 256, 0, stream>>>(dinv);
        init_out_kernel<<<2048, 256, 0, stream>>>(u_emb, v_emb, out);
        float* bufA_i = bufA + (size_t)U_N * D_N;
        float* bufB_i = bufB + (size_t)U_N * D_N;
        float* out_i  = out + (size_t)U_N * D_N;
        prop_kernel<<<8192, 256, 0, stream>>>(u_emb, v_emb, bufA, bufA_i, eu, ei, dinv);
        add_kernel<<<2048, 256, 0, stream>>>(out, bufA);
        prop_kernel<<<8192, 256, 0, stream>>>(bufA, bufA_i, bufB, bufB_i, eu, ei, dinv);
        add_kernel<<<2048, 256, 0, stream>>>(out, bufB);
        prop_kernel<<<8192, 256, 0, stream>>>(bufB, bufB_i, out, out_i, eu, ei, dinv);
        final_kernel<<<2048, 256, 0, stream>>>(out, v_emb);
    }
}

// Round 8
// 378.158 us; speedup vs baseline: 5.5646x; 1.4255x over previous
//
#include <hip/hip_runtime.h>

#define U_N 150000
#define I_N 100000
#define D_N 64
#define E_N 1500000
#define N_NODES (U_N + I_N)

// bucket geometry
#define BSHIFT 10
#define BW (1 << BSHIFT)              // 1024 keys per bucket
#define NB_U ((U_N + BW - 1) / BW)    // 147
#define NB_I ((I_N + BW - 1) / BW)    // 98
#define NBMAX 256
#define CAP_U 16384                   // expected ~10240/bucket
#define CAP_I 24576                   // expected ~15360/bucket
#define CH 8192                       // edges per stage block

typedef unsigned int uint;
typedef unsigned short ushort_t;

// bf16 helpers
__device__ __forceinline__ float bf_lo(uint x) { return __uint_as_float(x << 16); }
__device__ __forceinline__ float bf_hi(uint x) { return __uint_as_float(x & 0xFFFF0000u); }
__device__ __forceinline__ ushort_t f2b(float f) {
    uint u = __float_as_uint(f);
    uint r = u + 0x7FFFu + ((u >> 16) & 1u);   // round-to-nearest-even
    return (ushort_t)(r >> 16);
}

// ============================================================
// stage: bin edges into per-bucket staging regions (coalesced)
// ============================================================
__global__ void stage2_kernel(const int* __restrict__ keys, const int* __restrict__ pays,
                              int* __restrict__ bcnt, int2* __restrict__ staging, int cap) {
    __shared__ int2 sp[CH];
    __shared__ int hist[NBMAX];
    __shared__ int scanb[NBMAX];
    __shared__ int cur[NBMAX];
    __shared__ int gbase[NBMAX];
    int tid = threadIdx.x;
    int e0 = blockIdx.x * CH;
    int cnt = E_N - e0;
    if (cnt <= 0) return;
    if (cnt > CH) cnt = CH;

    hist[tid] = 0;
    __syncthreads();
    for (int s = tid; s < cnt; s += blockDim.x)
        atomicAdd(&hist[keys[e0 + s] >> BSHIFT], 1);
    __syncthreads();
    scanb[tid] = hist[tid];
    __syncthreads();
    for (int off = 1; off < NBMAX; off <<= 1) {
        int v = (tid >= off) ? scanb[tid - off] : 0;
        __syncthreads();
        scanb[tid] += v;
        __syncthreads();
    }
    cur[tid] = scanb[tid] - hist[tid];   // exclusive base
    __syncthreads();
    // compact into LDS, bucket-sorted
    for (int s = tid; s < cnt; s += blockDim.x) {
        int k = keys[e0 + s];
        int p = pays[e0 + s];
        int pos = atomicAdd(&cur[k >> BSHIFT], 1);
        sp[pos] = make_int2(k, p);
    }
    __syncthreads();
    // reserve global per-bucket ranges
    {
        int c = hist[tid];
        gbase[tid] = c ? atomicAdd(&bcnt[tid], c) : 0;
    }
    __syncthreads();
    // coalesced write-out into bucket regions
    for (int s = tid; s < cnt; s += blockDim.x) {
        int2 pr = sp[s];
        int b = pr.x >> BSHIFT;
        int dst = gbase[b] + (s - (scanb[b] - hist[b]));
        if (dst < cap) staging[(size_t)b * cap + dst] = pr;
    }
}

// ============================================================
// scan bucket totals -> bucket bases; seal rowptr[n]
// ============================================================
__global__ void bscan_kernel(const int* __restrict__ bcnt_u, int* __restrict__ bbase_u,
                             const int* __restrict__ bcnt_i, int* __restrict__ bbase_i,
                             int* __restrict__ rp_u, int* __restrict__ rp_i) {
    __shared__ int lds[NBMAX];
    int tid = threadIdx.x;
    int v = (tid < NB_U) ? bcnt_u[tid] : 0;
    lds[tid] = v;
    __syncthreads();
    for (int off = 1; off < NBMAX; off <<= 1) {
        int t = (tid >= off) ? lds[tid - off] : 0;
        __syncthreads();
        lds[tid] += t;
        __syncthreads();
    }
    if (tid < NB_U) bbase_u[tid] = lds[tid] - v;
    __syncthreads();
    int w = (tid < NB_I) ? bcnt_i[tid] : 0;
    lds[tid] = w;
    __syncthreads();
    for (int off = 1; off < NBMAX; off <<= 1) {
        int t = (tid >= off) ? lds[tid - off] : 0;
        __syncthreads();
        lds[tid] += t;
        __syncthreads();
    }
    if (tid < NB_I) bbase_i[tid] = lds[tid] - w;
    if (tid == 0) { rp_u[U_N] = E_N; rp_i[I_N] = E_N; }
}

// ============================================================
// count: per-bucket LDS histogram -> dinv + rowptr (no global atomics)
// ============================================================
__global__ void count_kernel(const int2* __restrict__ staging, int cap,
                             const int* __restrict__ bcnt, const int* __restrict__ bbase,
                             int nkeys, float* __restrict__ dinv_side,
                             int* __restrict__ rowptr) {
    __shared__ int cnt[BW];
    __shared__ int part[256];
    int b = blockIdx.x;
    int lo = b << BSHIFT;
    int hi = lo + BW; if (hi > nkeys) hi = nkeys;
    int nk = hi - lo;
    int tid = threadIdx.x;
    for (int k = tid; k < BW; k += 256) cnt[k] = 0;
    __syncthreads();
    int ns = bcnt[b]; if (ns > cap) ns = cap;
    const int2* stg = staging + (size_t)b * cap;
    for (int s = tid; s < ns; s += 256)
        atomicAdd(&cnt[stg[s].x - lo], 1);
    __syncthreads();
    for (int k = tid; k < nk; k += 256)
        dinv_side[lo + k] = rsqrtf((float)cnt[k] + 1e-7f);
    // exclusive scan of cnt[0..BW): 4 elems/thread
    int b4 = tid * 4;
    int v0 = cnt[b4], v1 = cnt[b4 + 1], v2 = cnt[b4 + 2], v3 = cnt[b4 + 3];
    int s = v0 + v1 + v2 + v3;
    part[tid] = s;
    __syncthreads();
    for (int off = 1; off < 256; off <<= 1) {
        int t = (tid >= off) ? part[tid - off] : 0;
        __syncthreads();
        part[tid] += t;
        __syncthreads();
    }
    int run = bbase[b] + part[tid] - s;
    if (b4 < nk)     rowptr[lo + b4] = run;
    run += v0;
    if (b4 + 1 < nk) rowptr[lo + b4 + 1] = run;
    run += v1;
    if (b4 + 2 < nk) rowptr[lo + b4 + 2] = run;
    run += v2;
    if (b4 + 3 < nk) rowptr[lo + b4 + 3] = run;
}

// ============================================================
// fill: per-bucket LDS cursors -> colw = {nb, dinv[nb]}
// ============================================================
__global__ void fill2_kernel(const int2* __restrict__ staging, int cap,
                             const int* __restrict__ bcnt,
                             const int* __restrict__ rowptr, int nkeys,
                             const float* __restrict__ dinv_other,
                             int2* __restrict__ colw) {
    __shared__ int cur[BW];
    int b = blockIdx.x;
    int lo = b << BSHIFT;
    int hi = lo + BW; if (hi > nkeys) hi = nkeys;
    int tid = threadIdx.x;
    for (int k = lo + tid; k < hi; k += 256) cur[k - lo] = rowptr[k];
    __syncthreads();
    int ns = bcnt[b]; if (ns > cap) ns = cap;
    const int2* stg = staging + (size_t)b * cap;
    for (int s = tid; s < ns; s += 256) {
        int2 pr = stg[s];
        int pos = atomicAdd(&cur[pr.x - lo], 1);
        colw[pos] = make_int2(pr.y, __float_as_int(dinv_other[pr.y]));
    }
}

// ============================================================
// cvt: ego (fp32 u_emb|v_emb) -> bf16 [N][64]
// ============================================================
__global__ void cvt16_kernel(const float* __restrict__ u_emb, const float* __restrict__ v_emb,
                             ushort_t* __restrict__ dst) {
    size_t t = (size_t)blockIdx.x * blockDim.x + threadIdx.x;
    size_t stride = (size_t)gridDim.x * blockDim.x;
    const size_t nu4 = (size_t)U_N * 16;
    const size_t n4 = (size_t)N_NODES * 16;
    const float4* us = (const float4*)u_emb;
    const float4* vs = (const float4*)v_emb;
    ushort4* o = (ushort4*)dst;
    for (size_t i = t; i < n4; i += stride) {
        float4 x = (i < nu4) ? us[i] : vs[i - nu4];
        ushort4 y;
        y.x = f2b(x.x); y.y = f2b(x.y); y.z = f2b(x.z); y.w = f2b(x.w);
        o[i] = y;
    }
}

// ============================================================
// CSR gather v3: one 16-lane group per node (4 nodes/wave).
// ============================================================
template <int FUSE>
__global__ void gather16_kernel(const ushort_t* __restrict__ src16,
                                const int* __restrict__ rowptr_u, const int2* __restrict__ colw_u,
                                const int* __restrict__ rowptr_i, const int2* __restrict__ colw_i,
                                const float* __restrict__ dinv,
                                ushort_t* __restrict__ h16_out,
                                const float* __restrict__ u_emb,
                                const float* __restrict__ v_emb,
                                const ushort_t* __restrict__ h1_16,
                                const ushort_t* __restrict__ h2_16,
                                float* __restrict__ out) {
    int grp = (int)((blockIdx.x * blockDim.x + threadIdx.x) >> 4);
    int d4 = threadIdx.x & 15;
    if (grp >= N_NODES) return;
    const int* rp; const int2* cw; const uint2* s8; int row;
    if (grp < U_N) {
        rp = rowptr_u; cw = colw_u; row = grp;
        s8 = (const uint2*)(src16 + (size_t)U_N * D_N);   // items block
    } else {
        rp = rowptr_i; cw = colw_i; row = grp - U_N;
        s8 = (const uint2*)src16;                          // users block
    }
    int beg = rp[row], end = rp[row + 1];

    float4 acc = make_float4(0.f, 0.f, 0.f, 0.f);
    int j = beg;
    for (; j + 4 <= end; j += 4) {
        int2 c0 = cw[j], c1 = cw[j + 1], c2 = cw[j + 2], c3 = cw[j + 3];
        uint2 q0 = s8[(size_t)c0.x * 16 + d4];
        uint2 q1 = s8[(size_t)c1.x * 16 + d4];
        uint2 q2 = s8[(size_t)c2.x * 16 + d4];
        uint2 q3 = s8[(size_t)c3.x * 16 + d4];
        float w0 = __int_as_float(c0.y), w1 = __int_as_float(c1.y);
        float w2 = __int_as_float(c2.y), w3 = __int_as_float(c3.y);
        acc.x = fmaf(w0, bf_lo(q0.x), acc.x);
        acc.y = fmaf(w0, bf_hi(q0.x), acc.y);
        acc.z = fmaf(w0, bf_lo(q0.y), acc.z);
        acc.w = fmaf(w0, bf_hi(q0.y), acc.w);
        acc.x = fmaf(w1, bf_lo(q1.x), acc.x);
        acc.y = fmaf(w1, bf_hi(q1.x), acc.y);
        acc.z = fmaf(w1, bf_lo(q1.y), acc.z);
        acc.w = fmaf(w1, bf_hi(q1.y), acc.w);
        acc.x = fmaf(w2, bf_lo(q2.x), acc.x);
        acc.y = fmaf(w2, bf_hi(q2.x), acc.y);
        acc.z = fmaf(w2, bf_lo(q2.y), acc.z);
        acc.w = fmaf(w2, bf_hi(q2.y), acc.w);
        acc.x = fmaf(w3, bf_lo(q3.x), acc.x);
        acc.y = fmaf(w3, bf_hi(q3.x), acc.y);
        acc.z = fmaf(w3, bf_lo(q3.y), acc.z);
        acc.w = fmaf(w3, bf_hi(q3.y), acc.w);
    }
    for (; j < end; ++j) {
        int2 c = cw[j];
        uint2 q = s8[(size_t)c.x * 16 + d4];
        float w = __int_as_float(c.y);
        acc.x = fmaf(w, bf_lo(q.x), acc.x);
        acc.y = fmaf(w, bf_hi(q.x), acc.y);
        acc.z = fmaf(w, bf_lo(q.y), acc.z);
        acc.w = fmaf(w, bf_hi(q.y), acc.w);
    }

    float sc = dinv[grp];
    acc.x *= sc; acc.y *= sc; acc.z *= sc; acc.w *= sc;

    if (FUSE == 0) {
        ushort4 o;
        o.x = f2b(acc.x); o.y = f2b(acc.y); o.z = f2b(acc.z); o.w = f2b(acc.w);
        ((ushort4*)h16_out)[(size_t)grp * 16 + d4] = o;
    } else {
        float4 e;
        bool item = (grp >= U_N);
        if (item) e = ((const float4*)v_emb)[(size_t)(grp - U_N) * 16 + d4];
        else      e = ((const float4*)u_emb)[(size_t)grp * 16 + d4];
        uint2 p1 = ((const uint2*)h1_16)[(size_t)grp * 16 + d4];
        uint2 p2 = ((const uint2*)h2_16)[(size_t)grp * 16 + d4];
        float4 r;
        r.x = 0.25f * (e.x + bf_lo(p1.x) + bf_lo(p2.x) + acc.x);
        r.y = 0.25f * (e.y + bf_hi(p1.x) + bf_hi(p2.x) + acc.y);
        r.z = 0.25f * (e.z + bf_lo(p1.y) + bf_lo(p2.y) + acc.z);
        r.w = 0.25f * (e.w + bf_hi(p1.y) + bf_hi(p2.y) + acc.w);
        if (item) { r.x += e.x; r.y += e.y; r.z += e.z; r.w += e.w; }
        ((float4*)out)[(size_t)grp * 16 + d4] = r;
    }
}

// ============================================================
// fallback (R1 atomic path) kernels, used only if ws too small
// ============================================================
__global__ void deg_kernel(const int* __restrict__ eu, const int* __restrict__ ei,
                           float* __restrict__ deg) {
    int t = blockIdx.x * blockDim.x + threadIdx.x;
    int stride = gridDim.x * blockDim.x;
    for (int e = t; e < E_N; e += stride) {
        atomicAdd(&deg[eu[e]], 1.0f);
        atomicAdd(&deg[U_N + ei[e]], 1.0f);
    }
}
__global__ void rsqrt_kernel(float* __restrict__ deg) {
    int t = blockIdx.x * blockDim.x + threadIdx.x;
    if (t < N_NODES) deg[t] = rsqrtf(deg[t] + 1e-7f);
}
__global__ void init_out_kernel(const float* __restrict__ u_emb,
                                const float* __restrict__ v_emb,
                                float* __restrict__ out) {
    size_t t = (size_t)blockIdx.x * blockDim.x + threadIdx.x;
    size_t stride = (size_t)gridDim.x * blockDim.x;
    const size_t nu4 = (size_t)U_N * D_N / 4;
    const size_t ni4 = (size_t)I_N * D_N / 4;
    const float4* us = (const float4*)u_emb;
    const float4* vs = (const float4*)v_emb;
    float4* o = (float4*)out;
    for (size_t i = t; i < nu4; i += stride) o[i] = us[i];
    for (size_t i = t; i < ni4; i += stride) o[nu4 + i] = vs[i];
}
__global__ void add_kernel(float* __restrict__ acc, const float* __restrict__ h) {
    size_t t = (size_t)blockIdx.x * blockDim.x + threadIdx.x;
    size_t stride = (size_t)gridDim.x * blockDim.x;
    const size_t n4 = (size_t)N_NODES * D_N / 4;
    float4* a = (float4*)acc;
    const float4* b = (const float4*)h;
    for (size_t i = t; i < n4; i += stride) {
        float4 x = a[i]; float4 y = b[i];
        x.x += y.x; x.y += y.y; x.z += y.z; x.w += y.w;
        a[i] = x;
    }
}
__global__ void prop_kernel(const float* __restrict__ srcU, const float* __restrict__ srcI,
                            float* __restrict__ dstU, float* __restrict__ dstI,
                            const int* __restrict__ eu, const int* __restrict__ ei,
                            const float* __restrict__ dinv) {
    int wave = (blockIdx.x * blockDim.x + threadIdx.x) >> 6;
    int lane = threadIdx.x & 63;
    int nwaves = (gridDim.x * blockDim.x) >> 6;
    for (int e = wave; e < E_N; e += nwaves) {
        int u = eu[e];
        int i = ei[e];
        float w = dinv[u] * dinv[U_N + i];
        float hu = srcU[(size_t)u * D_N + lane];
        float hi = srcI[(size_t)i * D_N + lane];
        atomicAdd(&dstU[(size_t)u * D_N + lane], w * hi);
        atomicAdd(&dstI[(size_t)i * D_N + lane], w * hu);
    }
}
__global__ void final_kernel(float* __restrict__ out, const float* __restrict__ v_emb) {
    size_t t = (size_t)blockIdx.x * blockDim.x + threadIdx.x;
    size_t stride = (size_t)gridDim.x * blockDim.x;
    const size_t nu4 = (size_t)U_N * D_N / 4;
    const size_t n4 = (size_t)N_NODES * D_N / 4;
    float4* o = (float4*)out;
    const float4* v = (const float4*)v_emb;
    for (size_t i = t; i < n4; i += stride) {
        float4 x = o[i];
        x.x *= 0.25f; x.y *= 0.25f; x.z *= 0.25f; x.w *= 0.25f;
        if (i >= nu4) {
            float4 vv = v[i - nu4];
            x.x += vv.x; x.y += vv.y; x.z += vv.z; x.w += vv.w;
        }
        o[i] = x;
    }
}

// ============================================================
extern "C" void kernel_launch(void* const* d_in, const int* in_sizes, int n_in,
                              void* d_out, int out_size, void* d_ws, size_t ws_size,
                              hipStream_t stream) {
    const float* u_emb = (const float*)d_in[0];
    const float* v_emb = (const float*)d_in[1];
    const int* eu = (const int*)d_in[2];
    const int* ei = (const int*)d_in[3];
    float* out = (float*)d_out;

    const size_t h16bytes = (size_t)N_NODES * D_N * sizeof(ushort_t);  // 32 MB
    const size_t stg_u_bytes = (size_t)NB_U * CAP_U * sizeof(int2);    // 19.3 MB
    const size_t stg_i_bytes = (size_t)NB_I * CAP_I * sizeof(int2);    // 19.3 MB

    size_t off = 0;
    auto carve = [&](size_t bytes) {
        size_t p = off;
        off = (off + bytes + 255) & ~(size_t)255;
        return p;
    };
    char* ws = (char*)d_ws;
    size_t o_dinv  = carve((size_t)N_NODES * 4);
    size_t o_rpu   = carve((size_t)(U_N + 1) * 4);
    size_t o_rpi   = carve((size_t)(I_N + 1) * 4);
    size_t o_bcntu = carve((size_t)NB_U * 4);
    size_t o_bcnti = carve((size_t)NB_I * 4);
    size_t o_bbasu = carve((size_t)NB_U * 4);
    size_t o_bbasi = carve((size_t)NB_I * 4);
    size_t o_colu  = carve((size_t)E_N * 8);   // int2 {nb, w}
    size_t o_coli  = carve((size_t)E_N * 8);
    size_t o_ego16 = carve(h16bytes);
    size_t o_h1    = carve(h16bytes);          // aliased: staging_u during build
    size_t o_h2    = carve(h16bytes);          // aliased: staging_i during build
    size_t needed = off;

    if (ws_size >= needed) {
        float* dinv = (float*)(ws + o_dinv);
        int* rp_u  = (int*)(ws + o_rpu);
        int* rp_i  = (int*)(ws + o_rpi);
        int* bcnt_u = (int*)(ws + o_bcntu);
        int* bcnt_i = (int*)(ws + o_bcnti);
        int* bbase_u = (int*)(ws + o_bbasu);
        int* bbase_i = (int*)(ws + o_bbasi);
        int2* colw_u = (int2*)(ws + o_colu);
        int2* colw_i = (int2*)(ws + o_coli);
        ushort_t* ego16 = (ushort_t*)(ws + o_ego16);
        ushort_t* h1_16 = (ushort_t*)(ws + o_h1);
        ushort_t* h2_16 = (ushort_t*)(ws + o_h2);
        int2* stg_u = (int2*)(ws + o_h1);
        int2* stg_i = (int2*)(ws + o_h2);

        hipMemsetAsync(bcnt_u, 0, (size_t)NB_U * 4, stream);
        hipMemsetAsync(bcnt_i, 0, (size_t)NB_I * 4, stream);

        // ego -> bf16 (independent; launch first)
        cvt16_kernel<<<2048, 256, 0, stream>>>(u_emb, v_emb, ego16);

        const int sblocks = (E_N + CH - 1) / CH;
        stage2_kernel<<<sblocks, NBMAX, 0, stream>>>(eu, ei, bcnt_u, stg_u, CAP_U);
        stage2_kernel<<<sblocks, NBMAX, 0, stream>>>(ei, eu, bcnt_i, stg_i, CAP_I);
        bscan_kernel<<<1, NBMAX, 0, stream>>>(bcnt_u, bbase_u, bcnt_i, bbase_i, rp_u, rp_i);
        count_kernel<<<NB_U, 256, 0, stream>>>(stg_u, CAP_U, bcnt_u, bbase_u, U_N,
                                               dinv, rp_u);
        count_kernel<<<NB_I, 256, 0, stream>>>(stg_i, CAP_I, bcnt_i, bbase_i, I_N,
                                               dinv + U_N, rp_i);
        // user neighbors are items -> w = dinv[U_N + item]; item nbrs are users
        fill2_kernel<<<NB_U, 256, 0, stream>>>(stg_u, CAP_U, bcnt_u, rp_u, U_N,
                                               dinv + U_N, colw_u);
        fill2_kernel<<<NB_I, 256, 0, stream>>>(stg_i, CAP_I, bcnt_i, rp_i, I_N,
                                               dinv, colw_i);

        const int gblocks = ((size_t)N_NODES * 16 + 255) / 256;
        // layer 1: src = ego16 -> h1 bf16 (staging_u dead after fillU)
        gather16_kernel<0><<<gblocks, 256, 0, stream>>>(ego16, rp_u, colw_u, rp_i, colw_i,
                                                        dinv, h1_16,
                                                        nullptr, nullptr, nullptr, nullptr, nullptr);
        // layer 2: src = h1 -> h2 bf16 (staging_i dead after fillI)
        gather16_kernel<0><<<gblocks, 256, 0, stream>>>(h1_16, rp_u, colw_u, rp_i, colw_i,
                                                        dinv, h2_16,
                                                        nullptr, nullptr, nullptr, nullptr, nullptr);
        // layer 3: src = h2 -> fused final epilogue -> out (fp32)
        gather16_kernel<1><<<gblocks, 256, 0, stream>>>(h2_16, rp_u, colw_u, rp_i, colw_i,
                                                        dinv, nullptr,
                                                        u_emb, v_emb, h1_16, h2_16, out);
    } else {
        // fallback: R1 atomic-scatter path
        const size_t hbytes = (size_t)N_NODES * D_N * sizeof(float);
        float* dinv = (float*)ws;
        float* bufA = (float*)(ws + (1u << 20));
        float* bufB = bufA + (size_t)N_NODES * D_N;
        hipMemsetAsync(dinv, 0, N_NODES * sizeof(float), stream);
        hipMemsetAsync(bufA, 0, hbytes, stream);
        hipMemsetAsync(bufB, 0, hbytes, stream);
        deg_kernel<<<2048, 256, 0, stream>>>(eu, ei, dinv);
        rsqrt_kernel<<<(N_NODES + 255) / 256, 256, 0, stream>>>(dinv);
        init_out_kernel<<<2048, 256, 0, stream>>>(u_emb, v_emb, out);
        float* bufA_i = bufA + (size_t)U_N * D_N;
        float* bufB_i = bufB + (size_t)U_N * D_N;
        float* out_i  = out + (size_t)U_N * D_N;
        prop_kernel<<<8192, 256, 0, stream>>>(u_emb, v_emb, bufA, bufA_i, eu, ei, dinv);
        add_kernel<<<2048, 256, 0, stream>>>(out, bufA);
        prop_kernel<<<8192, 256, 0, stream>>>(bufA, bufA_i, bufB, bufB_i, eu, ei, dinv);
        add_kernel<<<2048, 256, 0, stream>>>(out, bufB);
        prop_kernel<<<8192, 256, 0, stream>>>(bufB, bufB_i, out, out_i, eu, ei, dinv);
        final_kernel<<<2048, 256, 0, stream>>>(out, v_emb);
    }
}

// Round 9
// 328.879 us; speedup vs baseline: 6.3984x; 1.1498x over previous
//
#include <hip/hip_runtime.h>

#define U_N 150000
#define I_N 100000
#define D_N 64
#define E_N 1500000
#define N_NODES (U_N + I_N)

// bucket geometry
#define BSHIFT 10
#define BW (1 << BSHIFT)              // 1024 keys per bucket
#define NB_U ((U_N + BW - 1) / BW)    // 147
#define NB_I ((I_N + BW - 1) / BW)    // 98
#define NBMAX 256
#define CAP_U 16384                   // expected ~10240/bucket
#define CAP_I 24576                   // expected ~15360/bucket
#define CH2 4096                      // edges per stage block

typedef unsigned int uint;
typedef unsigned short ushort_t;

// bf16 helpers
__device__ __forceinline__ float bf_lo(uint x) { return __uint_as_float(x << 16); }
__device__ __forceinline__ float bf_hi(uint x) { return __uint_as_float(x & 0xFFFF0000u); }
__device__ __forceinline__ ushort_t f2b(float f) {
    uint u = __float_as_uint(f);
    uint r = u + 0x7FFFu + ((u >> 16) & 1u);   // round-to-nearest-even
    return (ushort_t)(r >> 16);
}

// ============================================================
// stage both directions in ONE pass over the edge list.
// staged word = (payload << 10) | (key & 1023)
// ============================================================
__global__ __launch_bounds__(256) void stage_both_kernel(
    const int* __restrict__ eu, const int* __restrict__ ei,
    int* __restrict__ bcnt, uint* __restrict__ stg_u, uint* __restrict__ stg_i) {
    __shared__ uint spu[CH2], spi[CH2];
    __shared__ unsigned char sbu[CH2], sbi[CH2];
    __shared__ int histu[NBMAX], scanu[NBMAX], curu[NBMAX], gbu[NBMAX];
    __shared__ int histi[NBMAX], scani[NBMAX], curi[NBMAX], gbi[NBMAX];
    int tid = threadIdx.x;
    int e0 = blockIdx.x * CH2;
    int cnt = E_N - e0;
    if (cnt <= 0) return;
    if (cnt > CH2) cnt = CH2;

    histu[tid] = 0; histi[tid] = 0;
    __syncthreads();
    for (int s = tid; s < cnt; s += 256) {
        atomicAdd(&histu[eu[e0 + s] >> BSHIFT], 1);
        atomicAdd(&histi[ei[e0 + s] >> BSHIFT], 1);
    }
    __syncthreads();
    scanu[tid] = histu[tid]; scani[tid] = histi[tid];
    __syncthreads();
    for (int off = 1; off < NBMAX; off <<= 1) {
        int vu = (tid >= off) ? scanu[tid - off] : 0;
        int vi = (tid >= off) ? scani[tid - off] : 0;
        __syncthreads();
        scanu[tid] += vu; scani[tid] += vi;
        __syncthreads();
    }
    curu[tid] = scanu[tid] - histu[tid];
    curi[tid] = scani[tid] - histi[tid];
    __syncthreads();
    for (int s = tid; s < cnt; s += 256) {
        int ku = eu[e0 + s], ki = ei[e0 + s];
        int bu = ku >> BSHIFT, bi = ki >> BSHIFT;
        int pu = atomicAdd(&curu[bu], 1);
        spu[pu] = ((uint)ki << BSHIFT) | (uint)(ku & (BW - 1));
        sbu[pu] = (unsigned char)bu;
        int pi = atomicAdd(&curi[bi], 1);
        spi[pi] = ((uint)ku << BSHIFT) | (uint)(ki & (BW - 1));
        sbi[pi] = (unsigned char)bi;
    }
    __syncthreads();
    {
        int cu = histu[tid];
        gbu[tid] = cu ? atomicAdd(&bcnt[tid], cu) : 0;
        int ci = histi[tid];
        gbi[tid] = ci ? atomicAdd(&bcnt[NB_U + tid], ci) : 0;
    }
    __syncthreads();
    for (int s = tid; s < cnt; s += 256) {
        int b = sbu[s];
        int dst = gbu[b] + (s - (scanu[b] - histu[b]));
        if (dst < CAP_U) stg_u[(size_t)b * CAP_U + dst] = spu[s];
    }
    for (int s = tid; s < cnt; s += 256) {
        int b = sbi[s];
        int dst = gbi[b] + (s - (scani[b] - histi[b]));
        if (dst < CAP_I) stg_i[(size_t)b * CAP_I + dst] = spi[s];
    }
}

// ============================================================
// scan bucket totals -> bucket bases; seal rowptr ends
// ============================================================
__global__ void bscan_kernel(const int* __restrict__ bcnt, int* __restrict__ bbase,
                             int* __restrict__ rp_u, int* __restrict__ rp_i) {
    __shared__ int lds[NBMAX];
    int tid = threadIdx.x;
    int v = (tid < NB_U) ? bcnt[tid] : 0;
    lds[tid] = v;
    __syncthreads();
    for (int off = 1; off < NBMAX; off <<= 1) {
        int t = (tid >= off) ? lds[tid - off] : 0;
        __syncthreads();
        lds[tid] += t;
        __syncthreads();
    }
    if (tid < NB_U) bbase[tid] = lds[tid] - v;
    __syncthreads();
    int w = (tid < NB_I) ? bcnt[NB_U + tid] : 0;
    lds[tid] = w;
    __syncthreads();
    for (int off = 1; off < NBMAX; off <<= 1) {
        int t = (tid >= off) ? lds[tid - off] : 0;
        __syncthreads();
        lds[tid] += t;
        __syncthreads();
    }
    if (tid < NB_I) bbase[NB_U + tid] = lds[tid] - w;
    if (tid == 0) { rp_u[U_N] = E_N; rp_i[I_N] = E_N; }
}

// ============================================================
// count: per-bucket LDS histogram -> dinv + rowptr (both sides, one launch)
// ============================================================
__global__ __launch_bounds__(256) void count_both_kernel(
    const uint* __restrict__ stg_u, const uint* __restrict__ stg_i,
    const int* __restrict__ bcnt, const int* __restrict__ bbase,
    float* __restrict__ dinv, int* __restrict__ rp_u, int* __restrict__ rp_i) {
    __shared__ int cnt[BW];
    __shared__ int part[256];
    int b = blockIdx.x;
    const uint* stg; int cap, lo, nkeys; float* dside; int* rowptr;
    if (b < NB_U) {
        stg = stg_u + (size_t)b * CAP_U; cap = CAP_U; lo = b << BSHIFT;
        nkeys = U_N; dside = dinv; rowptr = rp_u;
    } else {
        int bb = b - NB_U;
        stg = stg_i + (size_t)bb * CAP_I; cap = CAP_I; lo = bb << BSHIFT;
        nkeys = I_N; dside = dinv + U_N; rowptr = rp_i;
    }
    int ns = bcnt[b]; if (ns > cap) ns = cap;
    int base = bbase[b];
    int hi = lo + BW; if (hi > nkeys) hi = nkeys;
    int nk = hi - lo;
    int tid = threadIdx.x;
    for (int k = tid; k < BW; k += 256) cnt[k] = 0;
    __syncthreads();
    for (int s = tid; s < ns; s += 256)
        atomicAdd(&cnt[stg[s] & (BW - 1)], 1);
    __syncthreads();
    for (int k = tid; k < nk; k += 256)
        dside[lo + k] = rsqrtf((float)cnt[k] + 1e-7f);
    int b4 = tid * 4;
    int v0 = cnt[b4], v1 = cnt[b4 + 1], v2 = cnt[b4 + 2], v3 = cnt[b4 + 3];
    int s = v0 + v1 + v2 + v3;
    part[tid] = s;
    __syncthreads();
    for (int off = 1; off < 256; off <<= 1) {
        int t = (tid >= off) ? part[tid - off] : 0;
        __syncthreads();
        part[tid] += t;
        __syncthreads();
    }
    int run = base + part[tid] - s;
    if (b4 < nk)     rowptr[lo + b4] = run;
    run += v0;
    if (b4 + 1 < nk) rowptr[lo + b4 + 1] = run;
    run += v1;
    if (b4 + 2 < nk) rowptr[lo + b4 + 2] = run;
    run += v2;
    if (b4 + 3 < nk) rowptr[lo + b4 + 3] = run;
}

// ============================================================
// fill: per-bucket LDS cursors -> colw = {nb, dinv[nb]} (both sides)
// ============================================================
__global__ __launch_bounds__(256) void fill_both_kernel(
    const uint* __restrict__ stg_u, const uint* __restrict__ stg_i,
    const int* __restrict__ bcnt,
    const int* __restrict__ rp_u, const int* __restrict__ rp_i,
    const float* __restrict__ dinv,
    int2* __restrict__ colw_u, int2* __restrict__ colw_i) {
    __shared__ int cur[BW];
    int b = blockIdx.x;
    const uint* stg; int cap, lo, nkeys; const int* rowptr; const float* dother; int2* colw;
    if (b < NB_U) {
        stg = stg_u + (size_t)b * CAP_U; cap = CAP_U; lo = b << BSHIFT;
        nkeys = U_N; rowptr = rp_u; dother = dinv + U_N; colw = colw_u;
    } else {
        int bb = b - NB_U;
        stg = stg_i + (size_t)bb * CAP_I; cap = CAP_I; lo = bb << BSHIFT;
        nkeys = I_N; rowptr = rp_i; dother = dinv; colw = colw_i;
    }
    int ns = bcnt[b]; if (ns > cap) ns = cap;
    int hi = lo + BW; if (hi > nkeys) hi = nkeys;
    int tid = threadIdx.x;
    for (int k = lo + tid; k < hi; k += 256) cur[k - lo] = rowptr[k];
    __syncthreads();
    for (int s = tid; s < ns; s += 256) {
        uint pr = stg[s];
        int pos = atomicAdd(&cur[pr & (BW - 1)], 1);
        int pay = (int)(pr >> BSHIFT);
        colw[pos] = make_int2(pay, __float_as_int(dother[pay]));
    }
}

// ============================================================
// cvt: ego (fp32 u_emb|v_emb) -> bf16 [N][64]
// ============================================================
__global__ void cvt16_kernel(const float* __restrict__ u_emb, const float* __restrict__ v_emb,
                             ushort_t* __restrict__ dst) {
    size_t t = (size_t)blockIdx.x * blockDim.x + threadIdx.x;
    size_t stride = (size_t)gridDim.x * blockDim.x;
    const size_t nu4 = (size_t)U_N * 16;
    const size_t n4 = (size_t)N_NODES * 16;
    const float4* us = (const float4*)u_emb;
    const float4* vs = (const float4*)v_emb;
    ushort4* o = (ushort4*)dst;
    for (size_t i = t; i < n4; i += stride) {
        float4 x = (i < nu4) ? us[i] : vs[i - nu4];
        ushort4 y;
        y.x = f2b(x.x); y.y = f2b(x.y); y.z = f2b(x.z); y.w = f2b(x.w);
        o[i] = y;
    }
}

// ============================================================
// CSR gather: one 16-lane group per node (4 nodes/wave).
// sc recomputed from rowptr (deg) -- no dinv read in hot loop.
// ============================================================
#define ACC4(w, q)                                 \
    acc.x = fmaf(w, bf_lo((q).x), acc.x);          \
    acc.y = fmaf(w, bf_hi((q).x), acc.y);          \
    acc.z = fmaf(w, bf_lo((q).y), acc.z);          \
    acc.w = fmaf(w, bf_hi((q).y), acc.w);

template <int FUSE>
__global__ void gather16_kernel(const ushort_t* __restrict__ src16,
                                const int* __restrict__ rowptr_u, const int2* __restrict__ colw_u,
                                const int* __restrict__ rowptr_i, const int2* __restrict__ colw_i,
                                ushort_t* __restrict__ h16_out,
                                const float* __restrict__ u_emb,
                                const float* __restrict__ v_emb,
                                const ushort_t* __restrict__ h1_16,
                                const ushort_t* __restrict__ h2_16,
                                float* __restrict__ out) {
    int grp = (int)((blockIdx.x * blockDim.x + threadIdx.x) >> 4);
    int d4 = threadIdx.x & 15;
    if (grp >= N_NODES) return;
    const int* rp; const int2* cw; const uint2* s8; int row;
    if (grp < U_N) {
        rp = rowptr_u; cw = colw_u; row = grp;
        s8 = (const uint2*)(src16 + (size_t)U_N * D_N);   // items block
    } else {
        rp = rowptr_i; cw = colw_i; row = grp - U_N;
        s8 = (const uint2*)src16;                          // users block
    }
    int beg = rp[row], end = rp[row + 1];

    float4 acc = make_float4(0.f, 0.f, 0.f, 0.f);
    int j = beg;
    while (j + 8 <= end) {
        int2 c[8]; uint2 q[8];
#pragma unroll
        for (int t = 0; t < 8; ++t) c[t] = cw[j + t];
#pragma unroll
        for (int t = 0; t < 8; ++t) q[t] = s8[(size_t)c[t].x * 16 + d4];
#pragma unroll
        for (int t = 0; t < 8; ++t) { float w = __int_as_float(c[t].y); ACC4(w, q[t]); }
        j += 8;
    }
    if (j + 4 <= end) {
        int2 c[4]; uint2 q[4];
#pragma unroll
        for (int t = 0; t < 4; ++t) c[t] = cw[j + t];
#pragma unroll
        for (int t = 0; t < 4; ++t) q[t] = s8[(size_t)c[t].x * 16 + d4];
#pragma unroll
        for (int t = 0; t < 4; ++t) { float w = __int_as_float(c[t].y); ACC4(w, q[t]); }
        j += 4;
    }
    for (; j < end; ++j) {
        int2 c = cw[j];
        uint2 q = s8[(size_t)c.x * 16 + d4];
        float w = __int_as_float(c.y);
        ACC4(w, q);
    }

    float sc = rsqrtf((float)(end - beg) + 1e-7f);
    acc.x *= sc; acc.y *= sc; acc.z *= sc; acc.w *= sc;

    if (FUSE == 0) {
        ushort4 o;
        o.x = f2b(acc.x); o.y = f2b(acc.y); o.z = f2b(acc.z); o.w = f2b(acc.w);
        ((ushort4*)h16_out)[(size_t)grp * 16 + d4] = o;
    } else {
        float4 e;
        bool item = (grp >= U_N);
        if (item) e = ((const float4*)v_emb)[(size_t)(grp - U_N) * 16 + d4];
        else      e = ((const float4*)u_emb)[(size_t)grp * 16 + d4];
        uint2 p1 = ((const uint2*)h1_16)[(size_t)grp * 16 + d4];
        uint2 p2 = ((const uint2*)h2_16)[(size_t)grp * 16 + d4];
        float4 r;
        r.x = 0.25f * (e.x + bf_lo(p1.x) + bf_lo(p2.x) + acc.x);
        r.y = 0.25f * (e.y + bf_hi(p1.x) + bf_hi(p2.x) + acc.y);
        r.z = 0.25f * (e.z + bf_lo(p1.y) + bf_lo(p2.y) + acc.z);
        r.w = 0.25f * (e.w + bf_hi(p1.y) + bf_hi(p2.y) + acc.w);
        if (item) { r.x += e.x; r.y += e.y; r.z += e.z; r.w += e.w; }
        ((float4*)out)[(size_t)grp * 16 + d4] = r;
    }
}

// ============================================================
// fallback (R1 atomic path) kernels, used only if ws too small
// ============================================================
__global__ void deg_kernel(const int* __restrict__ eu, const int* __restrict__ ei,
                           float* __restrict__ deg) {
    int t = blockIdx.x * blockDim.x + threadIdx.x;
    int stride = gridDim.x * blockDim.x;
    for (int e = t; e < E_N; e += stride) {
        atomicAdd(&deg[eu[e]], 1.0f);
        atomicAdd(&deg[U_N + ei[e]], 1.0f);
    }
}
__global__ void rsqrt_kernel(float* __restrict__ deg) {
    int t = blockIdx.x * blockDim.x + threadIdx.x;
    if (t < N_NODES) deg[t] = rsqrtf(deg[t] + 1e-7f);
}
__global__ void init_out_kernel(const float* __restrict__ u_emb,
                                const float* __restrict__ v_emb,
                                float* __restrict__ out) {
    size_t t = (size_t)blockIdx.x * blockDim.x + threadIdx.x;
    size_t stride = (size_t)gridDim.x * blockDim.x;
    const size_t nu4 = (size_t)U_N * D_N / 4;
    const size_t ni4 = (size_t)I_N * D_N / 4;
    const float4* us = (const float4*)u_emb;
    const float4* vs = (const float4*)v_emb;
    float4* o = (float4*)out;
    for (size_t i = t; i < nu4; i += stride) o[i] = us[i];
    for (size_t i = t; i < ni4; i += stride) o[nu4 + i] = vs[i];
}
__global__ void add_kernel(float* __restrict__ acc, const float* __restrict__ h) {
    size_t t = (size_t)blockIdx.x * blockDim.x + threadIdx.x;
    size_t stride = (size_t)gridDim.x * blockDim.x;
    const size_t n4 = (size_t)N_NODES * D_N / 4;
    float4* a = (float4*)acc;
    const float4* b = (const float4*)h;
    for (size_t i = t; i < n4; i += stride) {
        float4 x = a[i]; float4 y = b[i];
        x.x += y.x; x.y += y.y; x.z += y.z; x.w += y.w;
        a[i] = x;
    }
}
__global__ void prop_kernel(const float* __restrict__ srcU, const float* __restrict__ srcI,
                            float* __restrict__ dstU, float* __restrict__ dstI,
                            const int* __restrict__ eu, const int* __restrict__ ei,
                            const float* __restrict__ dinv) {
    int wave = (blockIdx.x * blockDim.x + threadIdx.x) >> 6;
    int lane = threadIdx.x & 63;
    int nwaves = (gridDim.x * blockDim.x) >> 6;
    for (int e = wave; e < E_N; e += nwaves) {
        int u = eu[e];
        int i = ei[e];
        float w = dinv[u] * dinv[U_N + i];
        float hu = srcU[(size_t)u * D_N + lane];
        float hi = srcI[(size_t)i * D_N + lane];
        atomicAdd(&dstU[(size_t)u * D_N + lane], w * hi);
        atomicAdd(&dstI[(size_t)i * D_N + lane], w * hu);
    }
}
__global__ void final_kernel(float* __restrict__ out, const float* __restrict__ v_emb) {
    size_t t = (size_t)blockIdx.x * blockDim.x + threadIdx.x;
    size_t stride = (size_t)gridDim.x * blockDim.x;
    const size_t nu4 = (size_t)U_N * D_N / 4;
    const size_t n4 = (size_t)N_NODES * D_N / 4;
    float4* o = (float4*)out;
    const float4* v = (const float4*)v_emb;
    for (size_t i = t; i < n4; i += stride) {
        float4 x = o[i];
        x.x *= 0.25f; x.y *= 0.25f; x.z *= 0.25f; x.w *= 0.25f;
        if (i >= nu4) {
            float4 vv = v[i - nu4];
            x.x += vv.x; x.y += vv.y; x.z += vv.z; x.w += vv.w;
        }
        o[i] = x;
    }
}

// ============================================================
extern "C" void kernel_launch(void* const* d_in, const int* in_sizes, int n_in,
                              void* d_out, int out_size, void* d_ws, size_t ws_size,
                              hipStream_t stream) {
    const float* u_emb = (const float*)d_in[0];
    const float* v_emb = (const float*)d_in[1];
    const int* eu = (const int*)d_in[2];
    const int* ei = (const int*)d_in[3];
    float* out = (float*)d_out;

    const size_t h16bytes = (size_t)N_NODES * D_N * sizeof(ushort_t);  // 32 MB

    size_t off = 0;
    auto carve = [&](size_t bytes) {
        size_t p = off;
        off = (off + bytes + 255) & ~(size_t)255;
        return p;
    };
    char* ws = (char*)d_ws;
    size_t o_dinv  = carve((size_t)N_NODES * 4);
    size_t o_rpu   = carve((size_t)(U_N + 1) * 4);
    size_t o_rpi   = carve((size_t)(I_N + 1) * 4);
    size_t o_bcnt  = carve((size_t)(NB_U + NBMAX) * 4);
    size_t o_bbase = carve((size_t)(NB_U + NBMAX) * 4);
    size_t o_colu  = carve((size_t)E_N * 8);   // int2 {nb, w}
    size_t o_coli  = carve((size_t)E_N * 8);
    size_t o_ego16 = carve(h16bytes);
    size_t o_h1    = carve(h16bytes);          // aliased: stg_u during build (9.6 MB)
    size_t o_h2    = carve(h16bytes);          // aliased: stg_i during build (9.6 MB)
    size_t needed = off;

    if (ws_size >= needed) {
        float* dinv = (float*)(ws + o_dinv);
        int* rp_u  = (int*)(ws + o_rpu);
        int* rp_i  = (int*)(ws + o_rpi);
        int* bcnt  = (int*)(ws + o_bcnt);
        int* bbase = (int*)(ws + o_bbase);
        int2* colw_u = (int2*)(ws + o_colu);
        int2* colw_i = (int2*)(ws + o_coli);
        ushort_t* ego16 = (ushort_t*)(ws + o_ego16);
        ushort_t* h1_16 = (ushort_t*)(ws + o_h1);
        ushort_t* h2_16 = (ushort_t*)(ws + o_h2);
        uint* stg_u = (uint*)(ws + o_h1);
        uint* stg_i = (uint*)(ws + o_h2);

        hipMemsetAsync(bcnt, 0, (size_t)(NB_U + NBMAX) * 4, stream);

        // ego -> bf16 (independent; launch first)
        cvt16_kernel<<<2048, 256, 0, stream>>>(u_emb, v_emb, ego16);

        const int sblocks = (E_N + CH2 - 1) / CH2;
        stage_both_kernel<<<sblocks, NBMAX, 0, stream>>>(eu, ei, bcnt, stg_u, stg_i);
        bscan_kernel<<<1, NBMAX, 0, stream>>>(bcnt, bbase, rp_u, rp_i);
        count_both_kernel<<<NB_U + NB_I, 256, 0, stream>>>(stg_u, stg_i, bcnt, bbase,
                                                           dinv, rp_u, rp_i);
        fill_both_kernel<<<NB_U + NB_I, 256, 0, stream>>>(stg_u, stg_i, bcnt,
                                                          rp_u, rp_i, dinv, colw_u, colw_i);

        const int gblocks = ((size_t)N_NODES * 16 + 255) / 256;
        // layer 1: src = ego16 -> h1 bf16 (stg_u dead after fill)
        gather16_kernel<0><<<gblocks, 256, 0, stream>>>(ego16, rp_u, colw_u, rp_i, colw_i,
                                                        h1_16,
                                                        nullptr, nullptr, nullptr, nullptr, nullptr);
        // layer 2: src = h1 -> h2 bf16 (stg_i dead after fill)
        gather16_kernel<0><<<gblocks, 256, 0, stream>>>(h1_16, rp_u, colw_u, rp_i, colw_i,
                                                        h2_16,
                                                        nullptr, nullptr, nullptr, nullptr, nullptr);
        // layer 3: src = h2 -> fused final epilogue -> out (fp32)
        gather16_kernel<1><<<gblocks, 256, 0, stream>>>(h2_16, rp_u, colw_u, rp_i, colw_i,
                                                        nullptr,
                                                        u_emb, v_emb, h1_16, h2_16, out);
    } else {
        // fallback: R1 atomic-scatter path
        const size_t hbytes = (size_t)N_NODES * D_N * sizeof(float);
        float* dinv = (float*)ws;
        float* bufA = (float*)(ws + (1u << 20));
        float* bufB = bufA + (size_t)N_NODES * D_N;
        hipMemsetAsync(dinv, 0, N_NODES * sizeof(float), stream);
        hipMemsetAsync(bufA, 0, hbytes, stream);
        hipMemsetAsync(bufB, 0, hbytes, stream);
        deg_kernel<<<2048, 256, 0, stream>>>(eu, ei, dinv);
        rsqrt_kernel<<<(N_NODES + 255) / 256, 256, 0, stream>>>(dinv);
        init_out_kernel<<<2048, 256, 0, stream>>>(u_emb, v_emb, out);
        float* bufA_i = bufA + (size_t)U_N * D_N;
        float* bufB_i = bufB + (size_t)U_N * D_N;
        float* out_i  = out + (size_t)U_N * D_N;
        prop_kernel<<<8192, 256, 0, stream>>>(u_emb, v_emb, bufA, bufA_i, eu, ei, dinv);
        add_kernel<<<2048, 256, 0, stream>>>(out, bufA);
        prop_kernel<<<8192, 256, 0, stream>>>(bufA, bufA_i, bufB, bufB_i, eu, ei, dinv);
        add_kernel<<<2048, 256, 0, stream>>>(out, bufB);
        prop_kernel<<<8192, 256, 0, stream>>>(bufB, bufB_i, out, out_i, eu, ei, dinv);
        final_kernel<<<2048, 256, 0, stream>>>(out, v_emb);
    }
}

// Round 11
// 314.958 us; speedup vs baseline: 6.6812x; 1.0442x over previous
//
#include <hip/hip_runtime.h>

#define U_N 150000
#define I_N 100000
#define D_N 64
#define E_N 1500000
#define N_NODES (U_N + I_N)

// bucket geometry
#define BSHIFT 10
#define BW (1 << BSHIFT)              // 1024 keys per bucket
#define NB_U ((U_N + BW - 1) / BW)    // 147
#define NB_I ((I_N + BW - 1) / BW)    // 98
#define NBMAX 256
#define CAP_U 16384
#define CAP_I 24576
#define CH2 4096

typedef unsigned int uint;
typedef unsigned short ushort_t;

// bf16 helpers
__device__ __forceinline__ float bf_lo(uint x) { return __uint_as_float(x << 16); }
__device__ __forceinline__ float bf_hi(uint x) { return __uint_as_float(x & 0xFFFF0000u); }
__device__ __forceinline__ ushort_t f2b(float f) {
    uint u = __float_as_uint(f);
    uint r = u + 0x7FFFu + ((u >> 16) & 1u);   // round-to-nearest-even
    return (ushort_t)(r >> 16);
}
__device__ __forceinline__ void acc4(float4& acc, float wgt, uint2 q) {
    acc.x = fmaf(wgt, bf_lo(q.x), acc.x);
    acc.y = fmaf(wgt, bf_hi(q.x), acc.y);
    acc.z = fmaf(wgt, bf_lo(q.y), acc.z);
    acc.w = fmaf(wgt, bf_hi(q.y), acc.w);
}

// ============================================================
// stage both directions in ONE pass over the edge list.
// staged word = (payload << 10) | (key & 1023)
// ============================================================
__global__ __launch_bounds__(256) void stage_both_kernel(
    const int* __restrict__ eu, const int* __restrict__ ei,
    int* __restrict__ bcnt, uint* __restrict__ stg_u, uint* __restrict__ stg_i) {
    __shared__ uint spu[CH2], spi[CH2];
    __shared__ unsigned char sbu[CH2], sbi[CH2];
    __shared__ int histu[NBMAX], scanu[NBMAX], curu[NBMAX], gbu[NBMAX];
    __shared__ int histi[NBMAX], scani[NBMAX], curi[NBMAX], gbi[NBMAX];
    int tid = threadIdx.x;
    int e0 = blockIdx.x * CH2;
    int cnt = E_N - e0;
    if (cnt <= 0) return;
    if (cnt > CH2) cnt = CH2;

    histu[tid] = 0; histi[tid] = 0;
    __syncthreads();
    for (int s = tid; s < cnt; s += 256) {
        atomicAdd(&histu[eu[e0 + s] >> BSHIFT], 1);
        atomicAdd(&histi[ei[e0 + s] >> BSHIFT], 1);
    }
    __syncthreads();
    scanu[tid] = histu[tid]; scani[tid] = histi[tid];
    __syncthreads();
    for (int off = 1; off < NBMAX; off <<= 1) {
        int vu = (tid >= off) ? scanu[tid - off] : 0;
        int vi = (tid >= off) ? scani[tid - off] : 0;
        __syncthreads();
        scanu[tid] += vu; scani[tid] += vi;
        __syncthreads();
    }
    curu[tid] = scanu[tid] - histu[tid];
    curi[tid] = scani[tid] - histi[tid];
    __syncthreads();
    for (int s = tid; s < cnt; s += 256) {
        int ku = eu[e0 + s], ki = ei[e0 + s];
        int bu = ku >> BSHIFT, bi = ki >> BSHIFT;
        int pu = atomicAdd(&curu[bu], 1);
        spu[pu] = ((uint)ki << BSHIFT) | (uint)(ku & (BW - 1));
        sbu[pu] = (unsigned char)bu;
        int pi = atomicAdd(&curi[bi], 1);
        spi[pi] = ((uint)ku << BSHIFT) | (uint)(ki & (BW - 1));
        sbi[pi] = (unsigned char)bi;
    }
    __syncthreads();
    {
        int cu = histu[tid];
        gbu[tid] = cu ? atomicAdd(&bcnt[tid], cu) : 0;
        int ci = histi[tid];
        gbi[tid] = ci ? atomicAdd(&bcnt[NB_U + tid], ci) : 0;
    }
    __syncthreads();
    for (int s = tid; s < cnt; s += 256) {
        int b = sbu[s];
        int dst = gbu[b] + (s - (scanu[b] - histu[b]));
        if (dst < CAP_U) stg_u[(size_t)b * CAP_U + dst] = spu[s];
    }
    for (int s = tid; s < cnt; s += 256) {
        int b = sbi[s];
        int dst = gbi[b] + (s - (scani[b] - histi[b]));
        if (dst < CAP_I) stg_i[(size_t)b * CAP_I + dst] = spi[s];
    }
}

// ============================================================
// scan bucket totals -> bucket bases; seal rowptr ends
// ============================================================
__global__ void bscan_kernel(const int* __restrict__ bcnt, int* __restrict__ bbase,
                             int* __restrict__ rp_u, int* __restrict__ rp_i) {
    __shared__ int lds[NBMAX];
    int tid = threadIdx.x;
    int v = (tid < NB_U) ? bcnt[tid] : 0;
    lds[tid] = v;
    __syncthreads();
    for (int off = 1; off < NBMAX; off <<= 1) {
        int t = (tid >= off) ? lds[tid - off] : 0;
        __syncthreads();
        lds[tid] += t;
        __syncthreads();
    }
    if (tid < NB_U) bbase[tid] = lds[tid] - v;
    __syncthreads();
    int w = (tid < NB_I) ? bcnt[NB_U + tid] : 0;
    lds[tid] = w;
    __syncthreads();
    for (int off = 1; off < NBMAX; off <<= 1) {
        int t = (tid >= off) ? lds[tid - off] : 0;
        __syncthreads();
        lds[tid] += t;
        __syncthreads();
    }
    if (tid < NB_I) bbase[NB_U + tid] = lds[tid] - w;
    if (tid == 0) { rp_u[U_N] = E_N; rp_i[I_N] = E_N; }
}

// ============================================================
// csr_finish: per-bucket histogram -> dinv + rowptr, then scatter
// colw = payload (4B) using in-LDS cursors. One kernel, both sides.
// ============================================================
__global__ __launch_bounds__(256) void csr_finish_kernel(
    const uint* __restrict__ stg_u, const uint* __restrict__ stg_i,
    const int* __restrict__ bcnt, const int* __restrict__ bbase,
    float* __restrict__ dinv, int* __restrict__ rp_u, int* __restrict__ rp_i,
    int* __restrict__ colw_u, int* __restrict__ colw_i) {
    __shared__ int cnt[BW];
    __shared__ int cur[BW];
    __shared__ int part[256];
    int b = blockIdx.x;
    const uint* stg; int cap, lo, nkeys; float* dside; int* rowptr; int* colw;
    if (b < NB_U) {
        stg = stg_u + (size_t)b * CAP_U; cap = CAP_U; lo = b << BSHIFT;
        nkeys = U_N; dside = dinv; rowptr = rp_u; colw = colw_u;
    } else {
        int bb = b - NB_U;
        stg = stg_i + (size_t)bb * CAP_I; cap = CAP_I; lo = bb << BSHIFT;
        nkeys = I_N; dside = dinv + U_N; rowptr = rp_i; colw = colw_i;
    }
    int ns = bcnt[b]; if (ns > cap) ns = cap;
    int base = bbase[b];
    int hi = lo + BW; if (hi > nkeys) hi = nkeys;
    int nk = hi - lo;
    int tid = threadIdx.x;
    for (int k = tid; k < BW; k += 256) cnt[k] = 0;
    __syncthreads();
    for (int s = tid; s < ns; s += 256)
        atomicAdd(&cnt[stg[s] & (BW - 1)], 1);
    __syncthreads();
    for (int k = tid; k < nk; k += 256)
        dside[lo + k] = rsqrtf((float)cnt[k] + 1e-7f);
    // exclusive scan of cnt -> rowptr + LDS cursors
    int b4 = tid * 4;
    int v0 = cnt[b4], v1 = cnt[b4 + 1], v2 = cnt[b4 + 2], v3 = cnt[b4 + 3];
    int s = v0 + v1 + v2 + v3;
    part[tid] = s;
    __syncthreads();
    for (int off = 1; off < 256; off <<= 1) {
        int t = (tid >= off) ? part[tid - off] : 0;
        __syncthreads();
        part[tid] += t;
        __syncthreads();
    }
    int run = base + part[tid] - s;
    cur[b4] = run;
    if (b4 < nk) rowptr[lo + b4] = run;
    run += v0;
    cur[b4 + 1] = run;
    if (b4 + 1 < nk) rowptr[lo + b4 + 1] = run;
    run += v1;
    cur[b4 + 2] = run;
    if (b4 + 2 < nk) rowptr[lo + b4 + 2] = run;
    run += v2;
    cur[b4 + 3] = run;
    if (b4 + 3 < nk) rowptr[lo + b4 + 3] = run;
    __syncthreads();
    // scatter payloads into row-contiguous colw
    for (int s2 = tid; s2 < ns; s2 += 256) {
        uint pr = stg[s2];
        int pos = atomicAdd(&cur[pr & (BW - 1)], 1);
        colw[pos] = (int)(pr >> BSHIFT);
    }
}

// ============================================================
// cvt: ego (fp32 u_emb|v_emb) -> bf16 [N][64]
// ============================================================
__global__ void cvt16_kernel(const float* __restrict__ u_emb, const float* __restrict__ v_emb,
                             ushort_t* __restrict__ dst) {
    size_t t = (size_t)blockIdx.x * blockDim.x + threadIdx.x;
    size_t stride = (size_t)gridDim.x * blockDim.x;
    const size_t nu4 = (size_t)U_N * 16;
    const size_t n4 = (size_t)N_NODES * 16;
    const float4* us = (const float4*)u_emb;
    const float4* vs = (const float4*)v_emb;
    ushort4* o = (ushort4*)dst;
    for (size_t i = t; i < n4; i += stride) {
        float4 x = (i < nu4) ? us[i] : vs[i - nu4];
        ushort4 y;
        y.x = f2b(x.x); y.y = f2b(x.y); y.z = f2b(x.z); y.w = f2b(x.w);
        o[i] = y;
    }
}

// ============================================================
// CSR gather: one 16-lane group per node (4 nodes/wave).
// colw = payload only; w = dnbr[nb] (1MB L2-hot broadcast, independent).
// ============================================================
template <int FUSE>
__global__ void gather16_kernel(const ushort_t* __restrict__ src16,
                                const int* __restrict__ rowptr_u, const int* __restrict__ colw_u,
                                const int* __restrict__ rowptr_i, const int* __restrict__ colw_i,
                                const float* __restrict__ dinv,
                                ushort_t* __restrict__ h16_out,
                                const ushort_t* __restrict__ ego16,
                                const ushort_t* __restrict__ h1_16,
                                float* __restrict__ out) {
    int grp = (int)((blockIdx.x * blockDim.x + threadIdx.x) >> 4);
    int d4 = threadIdx.x & 15;
    if (grp >= N_NODES) return;
    const int* rp; const int* cw; const uint2* s8; const float* dnbr; int row;
    if (grp < U_N) {
        rp = rowptr_u; cw = colw_u; row = grp; dnbr = dinv + U_N;
        s8 = (const uint2*)(src16 + (size_t)U_N * D_N);   // items block
    } else {
        rp = rowptr_i; cw = colw_i; row = grp - U_N; dnbr = dinv;
        s8 = (const uint2*)src16;                          // users block
    }
    int beg = rp[row], end = rp[row + 1];

    float4 acc = make_float4(0.f, 0.f, 0.f, 0.f);
    int j = beg;
    while (j + 8 <= end) {
        int c[8]; float wv[8]; uint2 q[8];
#pragma unroll
        for (int t = 0; t < 8; ++t) c[t] = cw[j + t];
#pragma unroll
        for (int t = 0; t < 8; ++t) wv[t] = dnbr[c[t]];
#pragma unroll
        for (int t = 0; t < 8; ++t) q[t] = s8[(size_t)c[t] * 16 + d4];
#pragma unroll
        for (int t = 0; t < 8; ++t) acc4(acc, wv[t], q[t]);
        j += 8;
    }
    if (j + 4 <= end) {
        int c[4]; float wv[4]; uint2 q[4];
#pragma unroll
        for (int t = 0; t < 4; ++t) c[t] = cw[j + t];
#pragma unroll
        for (int t = 0; t < 4; ++t) wv[t] = dnbr[c[t]];
#pragma unroll
        for (int t = 0; t < 4; ++t) q[t] = s8[(size_t)c[t] * 16 + d4];
#pragma unroll
        for (int t = 0; t < 4; ++t) acc4(acc, wv[t], q[t]);
        j += 4;
    }
    for (; j < end; ++j) {
        int c = cw[j];
        float wgt = dnbr[c];
        uint2 q = s8[(size_t)c * 16 + d4];
        acc4(acc, wgt, q);
    }

    float sc = rsqrtf((float)(end - beg) + 1e-7f);
    acc.x *= sc; acc.y *= sc; acc.z *= sc; acc.w *= sc;

    if (FUSE == 0) {
        ushort4 o;
        o.x = f2b(acc.x); o.y = f2b(acc.y); o.z = f2b(acc.z); o.w = f2b(acc.w);
        ((ushort4*)h16_out)[(size_t)grp * 16 + d4] = o;
    } else {
        // out = 0.25*(ego + h1 + h2 + h3) (+ ego again for items); bf16 ego/h1/h2
        uint2 e  = ((const uint2*)ego16)[(size_t)grp * 16 + d4];
        uint2 p1 = ((const uint2*)h1_16)[(size_t)grp * 16 + d4];
        uint2 p2 = ((const uint2*)src16)[(size_t)grp * 16 + d4];  // src16 == h2
        float ex = bf_lo(e.x), ey = bf_hi(e.x), ez = bf_lo(e.y), ew = bf_hi(e.y);
        float4 r;
        r.x = 0.25f * (ex + bf_lo(p1.x) + bf_lo(p2.x) + acc.x);
        r.y = 0.25f * (ey + bf_hi(p1.x) + bf_hi(p2.x) + acc.y);
        r.z = 0.25f * (ez + bf_lo(p1.y) + bf_lo(p2.y) + acc.z);
        r.w = 0.25f * (ew + bf_hi(p1.y) + bf_hi(p2.y) + acc.w);
        if (grp >= U_N) { r.x += ex; r.y += ey; r.z += ez; r.w += ew; }
        ((float4*)out)[(size_t)grp * 16 + d4] = r;
    }
}

// ============================================================
// fallback (R1 atomic path) kernels, used only if ws too small
// ============================================================
__global__ void deg_kernel(const int* __restrict__ eu, const int* __restrict__ ei,
                           float* __restrict__ deg) {
    int t = blockIdx.x * blockDim.x + threadIdx.x;
    int stride = gridDim.x * blockDim.x;
    for (int e = t; e < E_N; e += stride) {
        atomicAdd(&deg[eu[e]], 1.0f);
        atomicAdd(&deg[U_N + ei[e]], 1.0f);
    }
}
__global__ void rsqrt_kernel(float* __restrict__ deg) {
    int t = blockIdx.x * blockDim.x + threadIdx.x;
    if (t < N_NODES) deg[t] = rsqrtf(deg[t] + 1e-7f);
}
__global__ void init_out_kernel(const float* __restrict__ u_emb,
                                const float* __restrict__ v_emb,
                                float* __restrict__ out) {
    size_t t = (size_t)blockIdx.x * blockDim.x + threadIdx.x;
    size_t stride = (size_t)gridDim.x * blockDim.x;
    const size_t nu4 = (size_t)U_N * D_N / 4;
    const size_t ni4 = (size_t)I_N * D_N / 4;
    const float4* us = (const float4*)u_emb;
    const float4* vs = (const float4*)v_emb;
    float4* o = (float4*)out;
    for (size_t i = t; i < nu4; i += stride) o[i] = us[i];
    for (size_t i = t; i < ni4; i += stride) o[nu4 + i] = vs[i];
}
__global__ void add_kernel(float* __restrict__ acc, const float* __restrict__ h) {
    size_t t = (size_t)blockIdx.x * blockDim.x + threadIdx.x;
    size_t stride = (size_t)gridDim.x * blockDim.x;
    const size_t n4 = (size_t)N_NODES * D_N / 4;
    float4* a = (float4*)acc;
    const float4* b = (const float4*)h;
    for (size_t i = t; i < n4; i += stride) {
        float4 x = a[i]; float4 y = b[i];
        x.x += y.x; x.y += y.y; x.z += y.z; x.w += y.w;
        a[i] = x;
    }
}
__global__ void prop_kernel(const float* __restrict__ srcU, const float* __restrict__ srcI,
                            float* __restrict__ dstU, float* __restrict__ dstI,
                            const int* __restrict__ eu, const int* __restrict__ ei,
                            const float* __restrict__ dinv) {
    int wave = (blockIdx.x * blockDim.x + threadIdx.x) >> 6;
    int lane = threadIdx.x & 63;
    int nwaves = (gridDim.x * blockDim.x) >> 6;
    for (int e = wave; e < E_N; e += nwaves) {
        int u = eu[e];
        int i = ei[e];
        float w = dinv[u] * dinv[U_N + i];
        float hu = srcU[(size_t)u * D_N + lane];
        float hi = srcI[(size_t)i * D_N + lane];
        atomicAdd(&dstU[(size_t)u * D_N + lane], w * hi);
        atomicAdd(&dstI[(size_t)i * D_N + lane], w * hu);
    }
}
__global__ void final_kernel(float* __restrict__ out, const float* __restrict__ v_emb) {
    size_t t = (size_t)blockIdx.x * blockDim.x + threadIdx.x;
    size_t stride = (size_t)gridDim.x * blockDim.x;
    const size_t nu4 = (size_t)U_N * D_N / 4;
    const size_t n4 = (size_t)N_NODES * D_N / 4;
    float4* o = (float4*)out;
    const float4* v = (const float4*)v_emb;
    for (size_t i = t; i < n4; i += stride) {
        float4 x = o[i];
        x.x *= 0.25f; x.y *= 0.25f; x.z *= 0.25f; x.w *= 0.25f;
        if (i >= nu4) {
            float4 vv = v[i - nu4];
            x.x += vv.x; x.y += vv.y; x.z += vv.z; x.w += vv.w;
        }
        o[i] = x;
    }
}

// ============================================================
extern "C" void kernel_launch(void* const* d_in, const int* in_sizes, int n_in,
                              void* d_out, int out_size, void* d_ws, size_t ws_size,
                              hipStream_t stream) {
    const float* u_emb = (const float*)d_in[0];
    const float* v_emb = (const float*)d_in[1];
    const int* eu = (const int*)d_in[2];
    const int* ei = (const int*)d_in[3];
    float* out = (float*)d_out;

    const size_t h16bytes = (size_t)N_NODES * D_N * sizeof(ushort_t);  // 32 MB

    size_t off = 0;
    auto carve = [&](size_t bytes) {
        size_t p = off;
        off = (off + bytes + 255) & ~(size_t)255;
        return p;
    };
    char* ws = (char*)d_ws;
    size_t o_dinv  = carve((size_t)N_NODES * 4);
    size_t o_rpu   = carve((size_t)(U_N + 1) * 4);
    size_t o_rpi   = carve((size_t)(I_N + 1) * 4);
    size_t o_bcnt  = carve((size_t)(NB_U + NBMAX) * 4);
    size_t o_bbase = carve((size_t)(NB_U + NBMAX) * 4);
    size_t o_colu  = carve((size_t)E_N * 4);   // payload only
    size_t o_coli  = carve((size_t)E_N * 4);
    size_t o_ego16 = carve(h16bytes);
    size_t o_h1    = carve(h16bytes);          // aliased: stg_u during build (9.6 MB)
    size_t o_h2    = carve(h16bytes);          // aliased: stg_i during build (9.6 MB)
    size_t needed = off;

    if (ws_size >= needed) {
        float* dinv = (float*)(ws + o_dinv);
        int* rp_u  = (int*)(ws + o_rpu);
        int* rp_i  = (int*)(ws + o_rpi);
        int* bcnt  = (int*)(ws + o_bcnt);
        int* bbase = (int*)(ws + o_bbase);
        int* colw_u = (int*)(ws + o_colu);
        int* colw_i = (int*)(ws + o_coli);
        ushort_t* ego16 = (ushort_t*)(ws + o_ego16);
        ushort_t* h1_16 = (ushort_t*)(ws + o_h1);
        ushort_t* h2_16 = (ushort_t*)(ws + o_h2);
        uint* stg_u = (uint*)(ws + o_h1);
        uint* stg_i = (uint*)(ws + o_h2);

        hipMemsetAsync(bcnt, 0, (size_t)(NB_U + NBMAX) * 4, stream);

        cvt16_kernel<<<2048, 256, 0, stream>>>(u_emb, v_emb, ego16);

        const int sblocks = (E_N + CH2 - 1) / CH2;
        stage_both_kernel<<<sblocks, NBMAX, 0, stream>>>(eu, ei, bcnt, stg_u, stg_i);
        bscan_kernel<<<1, NBMAX, 0, stream>>>(bcnt, bbase, rp_u, rp_i);
        csr_finish_kernel<<<NB_U + NB_I, 256, 0, stream>>>(stg_u, stg_i, bcnt, bbase,
                                                           dinv, rp_u, rp_i, colw_u, colw_i);

        const int gblocks = ((size_t)N_NODES * 16 + 255) / 256;
        // layer 1: src = ego16 -> h1 bf16 (stg_u dead after csr_finish)
        gather16_kernel<0><<<gblocks, 256, 0, stream>>>(ego16, rp_u, colw_u, rp_i, colw_i,
                                                        dinv, h1_16, nullptr, nullptr, nullptr);
        // layer 2: src = h1 -> h2 bf16 (stg_i dead after csr_finish)
        gather16_kernel<0><<<gblocks, 256, 0, stream>>>(h1_16, rp_u, colw_u, rp_i, colw_i,
                                                        dinv, h2_16, nullptr, nullptr, nullptr);
        // layer 3: src = h2 -> fused final epilogue (all-bf16 reads) -> out fp32
        gather16_kernel<1><<<gblocks, 256, 0, stream>>>(h2_16, rp_u, colw_u, rp_i, colw_i,
                                                        dinv, nullptr, ego16, h1_16, out);
    } else {
        // fallback: R1 atomic-scatter path
        const size_t hbytes = (size_t)N_NODES * D_N * sizeof(float);
        float* dinv = (float*)ws;
        float* bufA = (float*)(ws + (1u << 20));
        float* bufB = bufA + (size_t)N_NODES * D_N;
        hipMemsetAsync(dinv, 0, N_NODES * sizeof(float), stream);
        hipMemsetAsync(bufA, 0, hbytes, stream);
        hipMemsetAsync(bufB, 0, hbytes, stream);
        deg_kernel<<<2048, 256, 0, stream>>>(eu, ei, dinv);
        rsqrt_kernel<<<(N_NODES + 255) / 256, 256, 0, stream>>>(dinv);
        init_out_kernel<<<2048, 256, 0, stream>>>(u_emb, v_emb, out);
        float* bufA_i = bufA + (size_t)U_N * D_N;
        float* bufB_i = bufB + (size_t)U_N * D_N;
        float* out_i  = out + (size_t)U_N * D_N;
        prop_kernel<<<8192, 256, 0, stream>>>(u_emb, v_emb, bufA, bufA_i, eu, ei, dinv);
        add_kernel<<<2048, 256, 0, stream>>>(out, bufA);
        prop_kernel<<<8192, 256, 0, stream>>>(bufA, bufA_i, bufB, bufB_i, eu, ei, dinv);
        add_kernel<<<2048, 256, 0, stream>>>(out, bufB);
        prop_kernel<<<8192, 256, 0, stream>>>(bufB, bufB_i, out, out_i, eu, ei, dinv);
        final_kernel<<<2048, 256, 0, stream>>>(out, v_emb);
    }
}